// Round 1
// baseline (4082.834 us; speedup 1.0000x reference)
//
#include <hip/hip_runtime.h>
#include <hip/hip_bf16.h>

// Problem constants (match reference setup_inputs / hyperparams)
constexpr int B  = 4;
constexpr int H  = 544;
constexpr int W  = 960;
constexpr int H2 = 272;   // half-res
constexpr int W2 = 480;
constexpr int NH = B * H2 * W2;     // 522240
constexpr int NF = B * H * W;       // 2088960
constexpr int MD = 24;              // MAX_DISP/DS

// Accumulator slots in workspace (after 4 half-res arrays)
// 0: gt_num  1: gt_den  2: ph_num  3: ph_den  4: s_dx  5: s_dy
// 6: s_sign  7: s_mag   8: s_act

__device__ inline void waveReduceAtomic(float v, float* dst) {
  #pragma unroll
  for (int off = 32; off > 0; off >>= 1) v += __shfl_down(v, off, 64);
  if ((threadIdx.x & 63) == 0) atomicAdd(dst, v);
}

// ---------------- downsample to half-res grayscale ----------------
__global__ __launch_bounds__(256) void k_down(const float* __restrict__ left,
                                              const float* __restrict__ right,
                                              float* __restrict__ lg,
                                              float* __restrict__ rg) {
  int tid = blockIdx.x * 256 + threadIdx.x;
  if (tid >= NH) return;
  int b = tid / (H2 * W2);
  int rem = tid % (H2 * W2);
  int y = rem / W2, x = rem % W2;
  const float* lb = left  + (size_t)b * 3 * H * W;
  const float* rb = right + (size_t)b * 3 * H * W;
  int y2 = 2 * y, x2 = 2 * x;
  float sl = 0.f, sr = 0.f;
  #pragma unroll
  for (int c = 0; c < 3; c++) {
    const float* lp = lb + (size_t)(c * H + y2) * W + x2;
    const float* rp = rb + (size_t)(c * H + y2) * W + x2;
    sl += lp[0] + lp[1] + lp[W] + lp[W + 1];
    sr += rp[0] + rp[1] + rp[W] + rp[W + 1];
  }
  lg[tid] = sl * (1.f / 12.f);
  rg[tid] = sr * (1.f / 12.f);
}

// ---------------- fused NCC disparity search ----------------
#define NTH 16
#define NTW 64
__global__ __launch_bounds__(256) void k_ncc(const float* __restrict__ lg,
                                             const float* __restrict__ rg,
                                             float* __restrict__ best_c,
                                             float* __restrict__ best_d) {
  const int b  = blockIdx.z;
  const int x0 = blockIdx.x * NTW;
  const int y0 = blockIdx.y * NTH;

  __shared__ float LG[NTH + 10][NTW + 10];   // lg tile, halo +-5
  __shared__ float RG[NTH + 10][NTW + 58];   // rg tile, halo +-(5+24)
  __shared__ float cH[NTH + 10][NTW];        // horizontal cross sums
  __shared__ float rH[NTH + 10][NTW];        // horizontal rs sums (masked)
  __shared__ float r2H[NTH + 10][NTW];       // horizontal rs^2 sums (masked)

  const float* lgb = lg + (size_t)b * H2 * W2;
  const float* rgb = rg + (size_t)b * H2 * W2;
  const int tid = threadIdx.x;

  for (int e = tid; e < (NTH + 10) * (NTW + 10); e += 256) {
    int r = e / (NTW + 10), i = e % (NTW + 10);
    int yg = y0 - 5 + r, xg = x0 - 5 + i;
    LG[r][i] = (yg >= 0 && yg < H2 && xg >= 0 && xg < W2) ? lgb[yg * W2 + xg] : 0.f;
  }
  for (int e = tid; e < (NTH + 10) * (NTW + 58); e += 256) {
    int r = e / (NTW + 58), i = e % (NTW + 58);
    int yg = y0 - 5 + r, xg = x0 - 29 + i;
    RG[r][i] = (yg >= 0 && yg < H2 && xg >= 0 && xg < W2) ? rgb[yg * W2 + xg] : 0.f;
  }
  __syncthreads();

  // lm / ls (left mean & std) once per tile
  for (int e = tid; e < (NTH + 10) * NTW; e += 256) {
    int r = e / NTW, x = e % NTW;
    float s = 0.f, s2 = 0.f;
    #pragma unroll
    for (int m = 0; m < 11; m++) { float l = LG[r][x + m]; s += l; s2 += l * l; }
    cH[r][x] = s; rH[r][x] = s2;
  }
  __syncthreads();

  float lmv[4], lsv[4], bcv[4], bdv[4];
  #pragma unroll
  for (int k = 0; k < 4; k++) {
    int p = tid + k * 256;
    int y = p / NTW, x = p % NTW;
    float s = 0.f, s2 = 0.f;
    #pragma unroll
    for (int dy = 0; dy < 11; dy++) { s += cH[y + dy][x]; s2 += rH[y + dy][x]; }
    float m = s * (1.f / 121.f);
    lmv[k] = m;
    lsv[k] = sqrtf(fmaxf(s2 * (1.f / 121.f) - m * m, 1e-8f));
    bcv[k] = -1.f; bdv[k] = 0.f;
  }
  __syncthreads();

  for (int d = -MD; d <= MD; ++d) {
    if (d == 0) continue;
    // horizontal pass (masked by unshifted support for rs/rs^2)
    for (int e = tid; e < (NTH + 10) * NTW; e += 256) {
      int r = e / NTW, x = e % NTW;
      float c = 0.f, s = 0.f, s2 = 0.f;
      int base = x + d + 24;
      #pragma unroll
      for (int m = 0; m < 11; m++) {
        float l  = LG[r][x + m];
        float rv = RG[r][base + m];
        int xg = x0 - 5 + x + m;                 // unshifted tap position
        float rvm = (xg >= 0 && xg < W2) ? rv : 0.f;
        c += l * rv; s += rvm; s2 += rvm * rv;
      }
      cH[r][x] = c; rH[r][x] = s; r2H[r][x] = s2;
    }
    __syncthreads();
    // vertical pass + argmax update
    #pragma unroll
    for (int k = 0; k < 4; k++) {
      int p = tid + k * 256;
      int y = p / NTW, x = p % NTW;
      float cs = 0.f, rs = 0.f, r2s = 0.f;
      #pragma unroll
      for (int dy = 0; dy < 11; dy++) {
        cs += cH[y + dy][x]; rs += rH[y + dy][x]; r2s += r2H[y + dy][x];
      }
      float cross = cs * (1.f / 121.f);
      float rm = rs * (1.f / 121.f);
      float r2 = r2s * (1.f / 121.f);
      float rstd = sqrtf(fmaxf(r2 - rm * rm, 1e-8f));
      float ncc = (cross - lmv[k] * rm) / (lsv[k] * rstd + 1e-8f);
      if (ncc > bcv[k]) { bcv[k] = ncc; bdv[k] = (float)d; }
    }
    __syncthreads();
  }

  #pragma unroll
  for (int k = 0; k < 4; k++) {
    int p = tid + k * 256;
    int y = p / NTW, x = p % NTW;
    int yg = y0 + y, xg = x0 + x;
    if (yg < H2 && xg < W2) {
      size_t o = (size_t)b * H2 * W2 + yg * W2 + xg;
      best_c[o] = bcv[k];
      best_d[o] = bdv[k];
    }
  }
}

// ---------------- photometric (warp + SSIM + L1), on the fly ----------------
__global__ __launch_bounds__(256) void k_photo(const float* __restrict__ pred,
                                               const float* __restrict__ left,
                                               const float* __restrict__ right,
                                               float* __restrict__ acc) {
  int tid = blockIdx.x * 256 + threadIdx.x;
  float num = 0.f, den = 0.f;
  if (tid < NF) {
    int b = tid / (H * W);
    int rem = tid % (H * W);
    int y = rem / W, x = rem % W;
    const float* dispb = pred + (size_t)b * H * W;
    const float* lb = left  + (size_t)b * 3 * H * W;
    const float* rb = right + (size_t)b * 3 * H * W;

    float ds = dispb[y * W + x];
    float xs = (float)x - ds;
    bool valid = (xs > 0.f) && (xs < (float)(W - 1));

    float sl[3] = {0,0,0}, sw[3] = {0,0,0}, sl2[3] = {0,0,0}, sw2[3] = {0,0,0}, slw[3] = {0,0,0};
    float cl[3] = {0,0,0}, cw[3] = {0,0,0};
    for (int ky = -1; ky <= 1; ky++) {
      int yy = y + ky; if (yy < 0 || yy >= H) continue;
      for (int kx = -1; kx <= 1; kx++) {
        int xx = x + kx; if (xx < 0 || xx >= W) continue;
        float dv = dispb[yy * W + xx];
        float xsv = (float)xx - dv;
        float xc = fminf(fmaxf(xsv, 0.f), (float)(W - 1));
        float x0f = floorf(xc);
        float w = xc - x0f;
        int x0i = (int)x0f;
        int x1i = min(x0i + 1, W - 1);
        #pragma unroll
        for (int c = 0; c < 3; c++) {
          float lv = lb[(size_t)(c * H + yy) * W + xx];
          const float* rc = rb + (size_t)(c * H + yy) * W;
          float wv = rc[x0i] * (1.f - w) + rc[x1i] * w;
          sl[c] += lv; sw[c] += wv;
          sl2[c] += lv * lv; sw2[c] += wv * wv; slw[c] += lv * wv;
          if (ky == 0 && kx == 0) { cl[c] = lv; cw[c] = wv; }
        }
      }
    }
    float ssm = 0.f, l1m = 0.f;
    #pragma unroll
    for (int c = 0; c < 3; c++) {
      float mx = sl[c] * (1.f / 9.f), my = sw[c] * (1.f / 9.f);
      float sx = fmaxf(sl2[c] * (1.f / 9.f) - mx * mx, 0.f);
      float sy = fmaxf(sw2[c] * (1.f / 9.f) - my * my, 0.f);
      float sxy = slw[c] * (1.f / 9.f) - mx * my;
      float n  = (2.f * mx * my + 1e-4f) * (2.f * sxy + 9e-4f);
      float dd = (mx * mx + my * my + 1e-4f) * (sx + sy + 9e-4f);
      float ss = (1.f - n / dd) * 0.5f;
      ss = fminf(fmaxf(ss, 0.f), 1.f);
      ssm += ss;
      l1m += fabsf(cl[c] - cw[c]);
    }
    ssm *= (1.f / 3.f); l1m *= (1.f / 3.f);
    float err = 0.85f * ssm + 0.15f * l1m;
    if (valid) { num = err; den = 1.f; }
  }
  waveReduceAtomic(num, acc + 2);
  waveReduceAtomic(den, acc + 3);
}

// ---------------- gt anchor ----------------
__global__ __launch_bounds__(256) void k_gt(const float* __restrict__ pred,
                                            const float* __restrict__ gt,
                                            const float* __restrict__ conf,
                                            const float* __restrict__ occ,
                                            float* __restrict__ acc) {
  int tid = blockIdx.x * 256 + threadIdx.x;
  float num = 0.f, den = 0.f;
  if (tid < NF) {
    float g = gt[tid];
    float trust = (g > 2.0f) ? conf[tid] * occ[tid] : 0.f;
    num = trust * fabsf(pred[tid] - g);
    den = trust;
  }
  waveReduceAtomic(num, acc + 0);
  waveReduceAtomic(den, acc + 1);
}

// ---------------- smoothness ----------------
__global__ __launch_bounds__(256) void k_smooth(const float* __restrict__ pred,
                                                const float* __restrict__ left,
                                                float* __restrict__ acc) {
  int tid = blockIdx.x * 256 + threadIdx.x;
  float sdx = 0.f, sdy = 0.f;
  if (tid < NF) {
    int b = tid / (H * W);
    int rem = tid % (H * W);
    int y = rem / W, x = rem % W;
    const float* pb = pred + (size_t)b * H * W;
    const float* lb = left + (size_t)b * 3 * H * W;
    float p0 = pb[y * W + x];
    if (x < W - 1) {
      float ddx = fabsf(pb[y * W + x + 1] - p0);
      float idx = 0.f;
      #pragma unroll
      for (int c = 0; c < 3; c++) {
        const float* lc = lb + (size_t)(c * H + y) * W;
        idx += fabsf(lc[x + 1] - lc[x]);
      }
      sdx = ddx * __expf(-idx * (1.f / 3.f));
    }
    if (y < H - 1) {
      float ddy = fabsf(pb[(y + 1) * W + x] - p0);
      float idy = 0.f;
      #pragma unroll
      for (int c = 0; c < 3; c++) {
        const float* lc = lb + (size_t)(c * H) * W;
        idy += fabsf(lc[(y + 1) * W + x] - lc[y * W + x]);
      }
      sdy = ddy * __expf(-idy * (1.f / 3.f));
    }
  }
  waveReduceAtomic(sdx, acc + 4);
  waveReduceAtomic(sdy, acc + 5);
}

// ---------------- sign / magnitude vs NCC pseudo-disparity ----------------
__global__ __launch_bounds__(256) void k_signmag(const float* __restrict__ pred,
                                                 const float* __restrict__ best_c,
                                                 const float* __restrict__ best_d,
                                                 float* __restrict__ acc) {
  int tid = blockIdx.x * 256 + threadIdx.x;
  float ssg = 0.f, smg = 0.f, sac = 0.f;
  if (tid < NF) {
    int b = tid / (H * W);
    int rem = tid % (H * W);
    int y = rem / W, x = rem % W;
    size_t hidx = (size_t)b * H2 * W2 + (size_t)(y >> 1) * W2 + (x >> 1);
    float bc = best_c[hidx];
    if (bc > 0.3f) {                       // nc = max(bc,0); nc *= (nc > 0.3)
      float nd = best_d[hidx] * 2.f;
      float p = pred[tid];
      float sgn = (nd > 0.f) ? 1.f : ((nd < 0.f) ? -1.f : 0.f);
      ssg = fmaxf(-p * sgn, 0.f);
      smg = bc * fabsf(p - nd);
      sac = 1.f;
    }
  }
  waveReduceAtomic(ssg, acc + 6);
  waveReduceAtomic(smg, acc + 7);
  waveReduceAtomic(sac, acc + 8);
}

// ---------------- final scalar composition ----------------
__global__ void k_final(const float* __restrict__ acc, float* __restrict__ out) {
  float gt = acc[0] / fmaxf(acc[1], 1.f);
  float ph = acc[2] / fmaxf(acc[3], 1.f);
  float n  = fmaxf(acc[8], 1.f);
  float sm = 0.3f * (acc[6] / n) + 0.7f * (acc[7] / n);
  float smo = acc[4] * (1.f / ((float)B * H * (W - 1)))
            + acc[5] * (1.f / ((float)B * (H - 1) * W));
  out[0] = gt + ph + 0.5f * sm + 0.1f * smo;
}

extern "C" void kernel_launch(void* const* d_in, const int* in_sizes, int n_in,
                              void* d_out, int out_size, void* d_ws, size_t ws_size,
                              hipStream_t stream) {
  const float* pred  = (const float*)d_in[0];
  const float* gt    = (const float*)d_in[1];
  const float* conf  = (const float*)d_in[2];
  const float* occ   = (const float*)d_in[3];
  const float* left  = (const float*)d_in[4];
  const float* right = (const float*)d_in[5];
  float* out = (float*)d_out;

  float* ws = (float*)d_ws;
  float* lg = ws;
  float* rg = ws + NH;
  float* bc = ws + 2 * (size_t)NH;
  float* bd = ws + 3 * (size_t)NH;
  float* acc = ws + 4 * (size_t)NH;

  hipMemsetAsync(acc, 0, 16 * sizeof(float), stream);

  k_down<<<(NH + 255) / 256, 256, 0, stream>>>(left, right, lg, rg);

  dim3 nccGrid((W2 + NTW - 1) / NTW, (H2 + NTH - 1) / NTH, B);
  k_ncc<<<nccGrid, 256, 0, stream>>>(lg, rg, bc, bd);

  int fullBlocks = (NF + 255) / 256;
  k_photo<<<fullBlocks, 256, 0, stream>>>(pred, left, right, acc);
  k_gt<<<fullBlocks, 256, 0, stream>>>(pred, gt, conf, occ, acc);
  k_smooth<<<fullBlocks, 256, 0, stream>>>(pred, left, acc);
  k_signmag<<<fullBlocks, 256, 0, stream>>>(pred, bc, bd, acc);

  k_final<<<1, 1, 0, stream>>>(acc, out);
}

// Round 2
// 471.919 us; speedup vs baseline: 8.6516x; 8.6516x over previous
//
#include <hip/hip_runtime.h>
#include <hip/hip_bf16.h>

// Problem constants (match reference setup_inputs / hyperparams)
constexpr int B  = 4;
constexpr int H  = 544;
constexpr int W  = 960;
constexpr int H2 = 272;   // half-res
constexpr int W2 = 480;
constexpr int NH = B * H2 * W2;     // 522240
constexpr int NF = B * H * W;       // 2088960
constexpr int MD = 24;              // MAX_DISP/DS
constexpr int NBLK = (NF + 255) / 256;  // 8160 pixel-kernel blocks

// Partial-sum slots (per block): 0 gt_num, 1 gt_den, 2 ph_num, 3 ph_den,
// 4 s_dx, 5 s_dy, 6 s_sign, 7 s_mag, 8 s_act
constexpr int NSLOT = 9;

__device__ inline float waveSum(float v) {
  #pragma unroll
  for (int off = 32; off > 0; off >>= 1) v += __shfl_down(v, off, 64);
  return v;
}

// ---------------- downsample to half-res grayscale ----------------
__global__ __launch_bounds__(256) void k_down(const float* __restrict__ left,
                                              const float* __restrict__ right,
                                              float* __restrict__ lg,
                                              float* __restrict__ rg) {
  int tid = blockIdx.x * 256 + threadIdx.x;
  if (tid >= NH) return;
  int b = tid / (H2 * W2);
  int rem = tid % (H2 * W2);
  int y = rem / W2, x = rem % W2;
  const float* lb = left  + (size_t)b * 3 * H * W;
  const float* rb = right + (size_t)b * 3 * H * W;
  int y2 = 2 * y, x2 = 2 * x;
  float sl = 0.f, sr = 0.f;
  #pragma unroll
  for (int c = 0; c < 3; c++) {
    const float* lp = lb + (size_t)(c * H + y2) * W + x2;
    const float* rp = rb + (size_t)(c * H + y2) * W + x2;
    sl += lp[0] + lp[1] + lp[W] + lp[W + 1];
    sr += rp[0] + rp[1] + rp[W] + rp[W + 1];
  }
  lg[tid] = sl * (1.f / 12.f);
  rg[tid] = sr * (1.f / 12.f);
}

// ---------------- fused NCC disparity search ----------------
#define NTH 16
#define NTW 64
__global__ __launch_bounds__(256) void k_ncc(const float* __restrict__ lg,
                                             const float* __restrict__ rg,
                                             float* __restrict__ best_c,
                                             float* __restrict__ best_d) {
  const int b  = blockIdx.z;
  const int x0 = blockIdx.x * NTW;
  const int y0 = blockIdx.y * NTH;

  __shared__ float LG[NTH + 10][NTW + 10];   // lg tile, halo +-5
  __shared__ float RG[NTH + 10][NTW + 58];   // rg tile, halo +-(5+24)
  __shared__ float cH[NTH + 10][NTW];        // horizontal cross sums
  __shared__ float rH[NTH + 10][NTW];        // horizontal rs sums (masked)
  __shared__ float r2H[NTH + 10][NTW];       // horizontal rs^2 sums (masked)

  const float* lgb = lg + (size_t)b * H2 * W2;
  const float* rgb = rg + (size_t)b * H2 * W2;
  const int tid = threadIdx.x;

  for (int e = tid; e < (NTH + 10) * (NTW + 10); e += 256) {
    int r = e / (NTW + 10), i = e % (NTW + 10);
    int yg = y0 - 5 + r, xg = x0 - 5 + i;
    LG[r][i] = (yg >= 0 && yg < H2 && xg >= 0 && xg < W2) ? lgb[yg * W2 + xg] : 0.f;
  }
  for (int e = tid; e < (NTH + 10) * (NTW + 58); e += 256) {
    int r = e / (NTW + 58), i = e % (NTW + 58);
    int yg = y0 - 5 + r, xg = x0 - 29 + i;
    RG[r][i] = (yg >= 0 && yg < H2 && xg >= 0 && xg < W2) ? rgb[yg * W2 + xg] : 0.f;
  }
  __syncthreads();

  // lm / ls (left mean & std) once per tile
  for (int e = tid; e < (NTH + 10) * NTW; e += 256) {
    int r = e / NTW, x = e % NTW;
    float s = 0.f, s2 = 0.f;
    #pragma unroll
    for (int m = 0; m < 11; m++) { float l = LG[r][x + m]; s += l; s2 += l * l; }
    cH[r][x] = s; rH[r][x] = s2;
  }
  __syncthreads();

  float lmv[4], lsv[4], bcv[4], bdv[4];
  #pragma unroll
  for (int k = 0; k < 4; k++) {
    int p = tid + k * 256;
    int y = p / NTW, x = p % NTW;
    float s = 0.f, s2 = 0.f;
    #pragma unroll
    for (int dy = 0; dy < 11; dy++) { s += cH[y + dy][x]; s2 += rH[y + dy][x]; }
    float m = s * (1.f / 121.f);
    lmv[k] = m;
    lsv[k] = sqrtf(fmaxf(s2 * (1.f / 121.f) - m * m, 1e-8f));
    bcv[k] = -1.f; bdv[k] = 0.f;
  }
  __syncthreads();

  for (int d = -MD; d <= MD; ++d) {
    if (d == 0) continue;
    // horizontal pass (masked by unshifted support for rs/rs^2)
    for (int e = tid; e < (NTH + 10) * NTW; e += 256) {
      int r = e / NTW, x = e % NTW;
      float c = 0.f, s = 0.f, s2 = 0.f;
      int base = x + d + 24;
      #pragma unroll
      for (int m = 0; m < 11; m++) {
        float l  = LG[r][x + m];
        float rv = RG[r][base + m];
        int xg = x0 - 5 + x + m;                 // unshifted tap position
        float rvm = (xg >= 0 && xg < W2) ? rv : 0.f;
        c += l * rv; s += rvm; s2 += rvm * rv;
      }
      cH[r][x] = c; rH[r][x] = s; r2H[r][x] = s2;
    }
    __syncthreads();
    // vertical pass + argmax update
    #pragma unroll
    for (int k = 0; k < 4; k++) {
      int p = tid + k * 256;
      int y = p / NTW, x = p % NTW;
      float cs = 0.f, rs = 0.f, r2s = 0.f;
      #pragma unroll
      for (int dy = 0; dy < 11; dy++) {
        cs += cH[y + dy][x]; rs += rH[y + dy][x]; r2s += r2H[y + dy][x];
      }
      float cross = cs * (1.f / 121.f);
      float rm = rs * (1.f / 121.f);
      float r2 = r2s * (1.f / 121.f);
      float rstd = sqrtf(fmaxf(r2 - rm * rm, 1e-8f));
      float ncc = (cross - lmv[k] * rm) / (lsv[k] * rstd + 1e-8f);
      if (ncc > bcv[k]) { bcv[k] = ncc; bdv[k] = (float)d; }
    }
    __syncthreads();
  }

  #pragma unroll
  for (int k = 0; k < 4; k++) {
    int p = tid + k * 256;
    int y = p / NTW, x = p % NTW;
    int yg = y0 + y, xg = x0 + x;
    if (yg < H2 && xg < W2) {
      size_t o = (size_t)b * H2 * W2 + yg * W2 + xg;
      best_c[o] = bcv[k];
      best_d[o] = bdv[k];
    }
  }
}

// ------- fused per-pixel kernel: gt anchor + photometric + smoothness +
// ------- sign/magnitude, two-stage reduction (no atomics) -------
__global__ __launch_bounds__(256) void k_pixel(const float* __restrict__ pred,
                                               const float* __restrict__ gt,
                                               const float* __restrict__ conf,
                                               const float* __restrict__ occ,
                                               const float* __restrict__ left,
                                               const float* __restrict__ right,
                                               const float* __restrict__ best_c,
                                               const float* __restrict__ best_d,
                                               float* __restrict__ partials) {
  int tid = blockIdx.x * 256 + threadIdx.x;
  float v[NSLOT];
  #pragma unroll
  for (int s = 0; s < NSLOT; s++) v[s] = 0.f;

  if (tid < NF) {
    int b = tid / (H * W);
    int rem = tid % (H * W);
    int y = rem / W, x = rem % W;
    const float* dispb = pred + (size_t)b * H * W;
    const float* lb = left  + (size_t)b * 3 * H * W;
    const float* rb = right + (size_t)b * 3 * H * W;

    // ---- gt anchor ----
    {
      float g = gt[tid];
      float trust = (g > 2.0f) ? conf[tid] * occ[tid] : 0.f;
      v[0] = trust * fabsf(dispb[y * W + x] - g);
      v[1] = trust;
    }

    // ---- photometric: 3x3 window, warp on the fly ----
    float ds = dispb[y * W + x];
    {
      float xs = (float)x - ds;
      bool valid = (xs > 0.f) && (xs < (float)(W - 1));

      float sl[3] = {0,0,0}, sw[3] = {0,0,0}, sl2[3] = {0,0,0},
            sw2[3] = {0,0,0}, slw[3] = {0,0,0};
      float cl[3] = {0,0,0}, cw[3] = {0,0,0};
      for (int ky = -1; ky <= 1; ky++) {
        int yy = y + ky; if (yy < 0 || yy >= H) continue;
        for (int kx = -1; kx <= 1; kx++) {
          int xx = x + kx; if (xx < 0 || xx >= W) continue;
          float dv = dispb[yy * W + xx];
          float xsv = (float)xx - dv;
          float xc = fminf(fmaxf(xsv, 0.f), (float)(W - 1));
          float x0f = floorf(xc);
          float w = xc - x0f;
          int x0i = (int)x0f;
          int x1i = min(x0i + 1, W - 1);
          #pragma unroll
          for (int c = 0; c < 3; c++) {
            float lv = lb[(size_t)(c * H + yy) * W + xx];
            const float* rc = rb + (size_t)(c * H + yy) * W;
            float wv = rc[x0i] * (1.f - w) + rc[x1i] * w;
            sl[c] += lv; sw[c] += wv;
            sl2[c] += lv * lv; sw2[c] += wv * wv; slw[c] += lv * wv;
            if (ky == 0 && kx == 0) { cl[c] = lv; cw[c] = wv; }
          }
        }
      }
      float ssm = 0.f, l1m = 0.f;
      #pragma unroll
      for (int c = 0; c < 3; c++) {
        float mx = sl[c] * (1.f / 9.f), my = sw[c] * (1.f / 9.f);
        float sx = fmaxf(sl2[c] * (1.f / 9.f) - mx * mx, 0.f);
        float sy = fmaxf(sw2[c] * (1.f / 9.f) - my * my, 0.f);
        float sxy = slw[c] * (1.f / 9.f) - mx * my;
        float n  = (2.f * mx * my + 1e-4f) * (2.f * sxy + 9e-4f);
        float dd = (mx * mx + my * my + 1e-4f) * (sx + sy + 9e-4f);
        float ss = (1.f - n / dd) * 0.5f;
        ss = fminf(fmaxf(ss, 0.f), 1.f);
        ssm += ss;
        l1m += fabsf(cl[c] - cw[c]);
      }
      ssm *= (1.f / 3.f); l1m *= (1.f / 3.f);
      float err = 0.85f * ssm + 0.15f * l1m;
      if (valid) { v[2] = err; v[3] = 1.f; }
    }

    // ---- smoothness ----
    {
      float p0 = ds;
      if (x < W - 1) {
        float ddx = fabsf(dispb[y * W + x + 1] - p0);
        float idx = 0.f;
        #pragma unroll
        for (int c = 0; c < 3; c++) {
          const float* lc = lb + (size_t)(c * H + y) * W;
          idx += fabsf(lc[x + 1] - lc[x]);
        }
        v[4] = ddx * __expf(-idx * (1.f / 3.f));
      }
      if (y < H - 1) {
        float ddy = fabsf(dispb[(y + 1) * W + x] - p0);
        float idy = 0.f;
        #pragma unroll
        for (int c = 0; c < 3; c++) {
          const float* lc = lb + (size_t)(c * H) * W;
          idy += fabsf(lc[(y + 1) * W + x] - lc[y * W + x]);
        }
        v[5] = ddy * __expf(-idy * (1.f / 3.f));
      }
    }

    // ---- sign / magnitude vs NCC pseudo-disparity ----
    {
      size_t hidx = (size_t)b * H2 * W2 + (size_t)(y >> 1) * W2 + (x >> 1);
      float bc = best_c[hidx];
      if (bc > 0.3f) {                     // nc = max(bc,0); nc *= (nc > 0.3)
        float nd = best_d[hidx] * 2.f;
        float p = ds;
        float sgn = (nd > 0.f) ? 1.f : ((nd < 0.f) ? -1.f : 0.f);
        v[6] = fmaxf(-p * sgn, 0.f);
        v[7] = bc * fabsf(p - nd);
        v[8] = 1.f;
      }
    }
  }

  // ---- block reduction: wave shuffle + LDS, one partial per block per slot
  __shared__ float sm[4][NSLOT];
  int wave = threadIdx.x >> 6, lane = threadIdx.x & 63;
  #pragma unroll
  for (int s = 0; s < NSLOT; s++) {
    float r = waveSum(v[s]);
    if (lane == 0) sm[wave][s] = r;
  }
  __syncthreads();
  if (threadIdx.x < NSLOT) {
    float t = sm[0][threadIdx.x] + sm[1][threadIdx.x] +
              sm[2][threadIdx.x] + sm[3][threadIdx.x];
    partials[(size_t)threadIdx.x * NBLK + blockIdx.x] = t;
  }
}

// ---------------- final reduction + scalar composition ----------------
__global__ __launch_bounds__(256) void k_final(const float* __restrict__ P,
                                               float* __restrict__ out) {
  __shared__ float red[NSLOT][4];
  int lane = threadIdx.x & 63, wave = threadIdx.x >> 6;
  #pragma unroll
  for (int s = 0; s < NSLOT; s++) {
    float l = 0.f;
    for (int i = threadIdx.x; i < NBLK; i += 256) l += P[(size_t)s * NBLK + i];
    l = waveSum(l);
    if (lane == 0) red[s][wave] = l;
  }
  __syncthreads();
  if (threadIdx.x == 0) {
    float a[NSLOT];
    #pragma unroll
    for (int s = 0; s < NSLOT; s++) a[s] = red[s][0] + red[s][1] + red[s][2] + red[s][3];
    float gtl = a[0] / fmaxf(a[1], 1.f);
    float ph  = a[2] / fmaxf(a[3], 1.f);
    float n   = fmaxf(a[8], 1.f);
    float smv = 0.3f * (a[6] / n) + 0.7f * (a[7] / n);
    float smo = a[4] * (1.f / ((float)B * H * (W - 1)))
              + a[5] * (1.f / ((float)B * (H - 1) * W));
    out[0] = gtl + ph + 0.5f * smv + 0.1f * smo;
  }
}

extern "C" void kernel_launch(void* const* d_in, const int* in_sizes, int n_in,
                              void* d_out, int out_size, void* d_ws, size_t ws_size,
                              hipStream_t stream) {
  const float* pred  = (const float*)d_in[0];
  const float* gt    = (const float*)d_in[1];
  const float* conf  = (const float*)d_in[2];
  const float* occ   = (const float*)d_in[3];
  const float* left  = (const float*)d_in[4];
  const float* right = (const float*)d_in[5];
  float* out = (float*)d_out;

  float* ws = (float*)d_ws;
  float* lg = ws;
  float* rg = ws + NH;
  float* bc = ws + 2 * (size_t)NH;
  float* bd = ws + 3 * (size_t)NH;
  float* partials = ws + 4 * (size_t)NH;   // NSLOT * NBLK floats

  k_down<<<(NH + 255) / 256, 256, 0, stream>>>(left, right, lg, rg);

  dim3 nccGrid((W2 + NTW - 1) / NTW, (H2 + NTH - 1) / NTH, B);
  k_ncc<<<nccGrid, 256, 0, stream>>>(lg, rg, bc, bd);

  k_pixel<<<NBLK, 256, 0, stream>>>(pred, gt, conf, occ, left, right, bc, bd, partials);

  k_final<<<1, 256, 0, stream>>>(partials, out);
}

// Round 3
// 338.744 us; speedup vs baseline: 12.0529x; 1.3931x over previous
//
#include <hip/hip_runtime.h>
#include <hip/hip_bf16.h>

// Problem constants (match reference setup_inputs / hyperparams)
constexpr int B  = 4;
constexpr int H  = 544;
constexpr int W  = 960;
constexpr int H2 = 272;   // half-res
constexpr int W2 = 480;
constexpr int NH = B * H2 * W2;     // 522240
constexpr int NF = B * H * W;       // 2088960
constexpr int NBLK = (NF + 255) / 256;  // 8160 pixel-kernel blocks
constexpr int NSLOT = 9;

__device__ inline float waveSum(float v) {
  #pragma unroll
  for (int off = 32; off > 0; off >>= 1) v += __shfl_down(v, off, 64);
  return v;
}

// ---------------- downsample to half-res grayscale ----------------
__global__ __launch_bounds__(256) void k_down(const float* __restrict__ left,
                                              const float* __restrict__ right,
                                              float* __restrict__ lg,
                                              float* __restrict__ rg) {
  int tid = blockIdx.x * 256 + threadIdx.x;
  if (tid >= NH) return;
  int b = tid / (H2 * W2);
  int rem = tid % (H2 * W2);
  int y = rem / W2, x = rem % W2;
  const float* lb = left  + (size_t)b * 3 * H * W;
  const float* rb = right + (size_t)b * 3 * H * W;
  int y2 = 2 * y, x2 = 2 * x;
  float sl = 0.f, sr = 0.f;
  #pragma unroll
  for (int c = 0; c < 3; c++) {
    const float* lp = lb + (size_t)(c * H + y2) * W + x2;
    const float* rp = rb + (size_t)(c * H + y2) * W + x2;
    sl += lp[0] + lp[1] + lp[W] + lp[W + 1];
    sr += rp[0] + rp[1] + rp[W] + rp[W + 1];
  }
  lg[tid] = sl * (1.f / 12.f);
  rg[tid] = sr * (1.f / 12.f);
}

// ---------------- fused NCC disparity search (restructured) ----------------
// Tile 64x16. d split in 2 groups: grp0 = [-24..-1], grp1 = [1..24].
// LDS layout (floats), total 13462 (53848 B -> 3 blocks/CU):
//   LGs  @0      26 x 74
//   RV1  @1924   16 x 112   (11x11 box sums of rg at x+d, raw 121-sums)
//   RV2  @3716   16 x 112   (same for rg^2)
//   POOL @5508   3904  (LH1/LH2 | VR1/VR2 | CH0/CH1)
//   P1   @9412   16 x 25    (border prefix sums, rg)
//   P2   @9812   16 x 25    (border prefix sums, rg^2)
//   RGs  @10212  26 x 125   (122 cols used, stride 125 kills bank conflicts)
__global__ __launch_bounds__(256) void k_ncc(const float* __restrict__ lg,
                                             const float* __restrict__ rg,
                                             float* __restrict__ bc0,
                                             float* __restrict__ bd0,
                                             float* __restrict__ bc1,
                                             float* __restrict__ bd1) {
  const int z = blockIdx.z;
  const int b = z >> 1, grp = z & 1;
  const int x0 = blockIdx.x * 64;
  const int y0 = blockIdx.y * 16;
  const int tid = threadIdx.x;

  __shared__ float SM[13462];
  float* LGs = SM;            // 26 x 74
  float* RV1 = SM + 1924;     // 16 x 112
  float* RV2 = SM + 3716;
  float* POOL= SM + 5508;     // 3904
  float* P1  = SM + 9412;     // 16 x 25
  float* P2  = SM + 9812;
  float* RGs = SM + 10212;    // 26 x 125

  const float* lgb = lg + (size_t)b * (H2 * W2);
  const float* rgb = rg + (size_t)b * (H2 * W2);

  // ---- load LG, RG tiles (zero-filled halos = reference zero padding) ----
  for (int e = tid; e < 26 * 74; e += 256) {
    int r = e / 74, c = e % 74;
    int gy = y0 - 5 + r, gxx = x0 - 5 + c;
    LGs[r * 74 + c] = (gy >= 0 && gy < H2 && gxx >= 0 && gxx < W2) ? lgb[gy * W2 + gxx] : 0.f;
  }
  for (int e = tid; e < 26 * 122; e += 256) {
    int r = e / 122, c = e % 122;
    int gy = y0 - 5 + r, gxx = x0 - 29 + c;
    RGs[r * 125 + c] = (gy >= 0 && gy < H2 && gxx >= 0 && gxx < W2) ? rgb[gy * W2 + gxx] : 0.f;
  }
  __syncthreads();

  // ---- LH pass (horizontal 11-sums of lg, lg^2) + lgc register cache ----
  const int hg = tid & 7, hr = tid >> 3;   // col-group (8 cols), row
  float lgc[18];
  float* LH1 = POOL;          // 26 x 64
  float* LH2 = POOL + 1664;
  if (hr < 26) {
    #pragma unroll
    for (int k = 0; k < 18; k++) lgc[k] = LGs[hr * 74 + 8 * hg + k];
    float w1[8], w2[8];
    float s1 = 0.f, s2 = 0.f;
    #pragma unroll
    for (int k = 0; k < 11; k++) { s1 += lgc[k]; s2 += lgc[k] * lgc[k]; }
    w1[0] = s1; w2[0] = s2;
    #pragma unroll
    for (int j = 1; j < 8; j++) {
      s1 += lgc[j + 10] - lgc[j - 1];
      s2 += lgc[j + 10] * lgc[j + 10] - lgc[j - 1] * lgc[j - 1];
      w1[j] = s1; w2[j] = s2;
    }
    *(float4*)&LH1[hr * 64 + 8 * hg]     = make_float4(w1[0], w1[1], w1[2], w1[3]);
    *(float4*)&LH1[hr * 64 + 8 * hg + 4] = make_float4(w1[4], w1[5], w1[6], w1[7]);
    *(float4*)&LH2[hr * 64 + 8 * hg]     = make_float4(w2[0], w2[1], w2[2], w2[3]);
    *(float4*)&LH2[hr * 64 + 8 * hg + 4] = make_float4(w2[4], w2[5], w2[6], w2[7]);
  }
  // border VB fill -> P[y][i+1] (head: global cols 0..23; tail: 456..479)
  const bool headTile = (x0 == 0), tailTile = (x0 == 448);
  if (headTile || tailTile) {
    int cl0 = headTile ? 29 : 37;     // RG local col of buffer col 0
    for (int e = tid; e < 16 * 24; e += 256) {
      int y = e / 24, i = e % 24;
      float v1 = 0.f, v2 = 0.f;
      #pragma unroll
      for (int dy = 0; dy < 11; dy++) {
        float v = RGs[(y + dy) * 125 + cl0 + i];
        v1 += v; v2 += v * v;
      }
      P1[y * 25 + i + 1] = v1;
      P2[y * 25 + i + 1] = v2;
    }
  }
  __syncthreads();

  // ---- prefix P (border tiles) + lm/ls extraction ----
  if ((headTile || tailTile) && tid < 16) {
    int y = tid;
    float s1 = 0.f, s2 = 0.f;
    P1[y * 25] = 0.f; P2[y * 25] = 0.f;
    for (int k = 0; k < 24; k++) {
      s1 += P1[y * 25 + k + 1]; P1[y * 25 + k + 1] = s1;
      s2 += P2[y * 25 + k + 1]; P2[y * 25 + k + 1] = s2;
    }
  }
  const int vx = tid & 63;
  const int vys = (tid >> 6) * 4;     // 4 output rows per thread
  float lmv[4], lsv[4];
  {
    float s1 = 0.f, s2 = 0.f;
    #pragma unroll
    for (int dy = 0; dy < 11; dy++) { s1 += LH1[(vys + dy) * 64 + vx]; s2 += LH2[(vys + dy) * 64 + vx]; }
    #pragma unroll
    for (int k = 0; k < 4; k++) {
      if (k) {
        s1 += LH1[(vys + k + 10) * 64 + vx] - LH1[(vys + k - 1) * 64 + vx];
        s2 += LH2[(vys + k + 10) * 64 + vx] - LH2[(vys + k - 1) * 64 + vx];
      }
      float m = s1 * (1.f / 121.f);
      lmv[k] = m;
      lsv[k] = sqrtf(fmaxf(s2 * (1.f / 121.f) - m * m, 1e-8f));
    }
  }
  __syncthreads();

  // ---- VR pass: vertical 11-sums of rg, rg^2 (overwrites LH) ----
  float* VR1 = POOL;          // 16 x 122
  float* VR2 = POOL + 1952;
  if (tid < 244) {
    int c = tid % 122;
    int r0 = (tid / 122) * 8;
    float s1 = 0.f, s2 = 0.f;
    #pragma unroll
    for (int dy = 0; dy < 11; dy++) {
      float v = RGs[(r0 + dy) * 125 + c];
      s1 += v; s2 += v * v;
    }
    VR1[r0 * 122 + c] = s1; VR2[r0 * 122 + c] = s2;
    #pragma unroll
    for (int k = 1; k < 8; k++) {
      float vin  = RGs[(r0 + k + 10) * 125 + c];
      float vout = RGs[(r0 + k - 1) * 125 + c];
      s1 += vin - vout;
      s2 += vin * vin - vout * vout;
      VR1[(r0 + k) * 122 + c] = s1; VR2[(r0 + k) * 122 + c] = s2;
    }
  }
  __syncthreads();

  // ---- RV pass: horizontal 11-sums of VR -> raw 121-sums at x+d ----
  {
    int r = tid >> 4, seg = tid & 15;
    int c0 = seg * 7;
    float s1 = 0.f, s2 = 0.f;
    #pragma unroll
    for (int m = 0; m < 11; m++) { s1 += VR1[r * 122 + c0 + m]; s2 += VR2[r * 122 + c0 + m]; }
    RV1[r * 112 + c0] = s1; RV2[r * 112 + c0] = s2;
    #pragma unroll
    for (int j = 1; j < 7; j++) {
      s1 += VR1[r * 122 + c0 + j + 10] - VR1[r * 122 + c0 + j - 1];
      s2 += VR2[r * 122 + c0 + j + 10] - VR2[r * 122 + c0 + j - 1];
      RV1[r * 112 + c0 + j] = s1; RV2[r * 112 + c0 + j] = s2;
    }
  }
  __syncthreads();

  // ---- d loop: pairs (d, d+1), both same sign (ranges exclude 0) ----
  float* CH0 = POOL;          // 26 x 64 cross sums for d
  float* CH1 = POOL + 1664;   // for d+1
  const int dstart = grp ? 1 : -24;
  const int gx = x0 + vx;
  const bool headLane = grp && (gx < 5);
  const bool tailLane = (!grp) && (gx > 474);
  float bnum[4], bden[4], bdd[4];
  #pragma unroll
  for (int k = 0; k < 4; k++) { bnum[k] = -1.f; bden[k] = 1.f; bdd[k] = 0.f; }

  for (int it = 0; it < 12; ++it) {
    const int d0 = dstart + 2 * it;
    if (hr < 26) {
      const int c0 = 8 * hg + d0 + 24;
      float rgv[19];
      #pragma unroll
      for (int j = 0; j < 19; j++) rgv[j] = RGs[hr * 125 + c0 + j];
      float ca[8], cb[8];
      float sa = 0.f, sb = 0.f;
      #pragma unroll
      for (int k = 0; k < 11; k++) { sa += lgc[k] * rgv[k]; sb += lgc[k] * rgv[k + 1]; }
      ca[0] = sa; cb[0] = sb;
      #pragma unroll
      for (int j = 1; j < 8; j++) {
        sa += lgc[j + 10] * rgv[j + 10] - lgc[j - 1] * rgv[j - 1];
        sb += lgc[j + 10] * rgv[j + 11] - lgc[j - 1] * rgv[j];
        ca[j] = sa; cb[j] = sb;
      }
      *(float4*)&CH0[hr * 64 + 8 * hg]     = make_float4(ca[0], ca[1], ca[2], ca[3]);
      *(float4*)&CH0[hr * 64 + 8 * hg + 4] = make_float4(ca[4], ca[5], ca[6], ca[7]);
      *(float4*)&CH1[hr * 64 + 8 * hg]     = make_float4(cb[0], cb[1], cb[2], cb[3]);
      *(float4*)&CH1[hr * 64 + 8 * hg + 4] = make_float4(cb[4], cb[5], cb[6], cb[7]);
    }
    __syncthreads();
    {
      float a0 = 0.f, a1 = 0.f;
      #pragma unroll
      for (int dy = 0; dy < 11; dy++) { a0 += CH0[(vys + dy) * 64 + vx]; a1 += CH1[(vys + dy) * 64 + vx]; }
      #pragma unroll
      for (int k = 0; k < 4; k++) {
        if (k) {
          a0 += CH0[(vys + k + 10) * 64 + vx] - CH0[(vys + k - 1) * 64 + vx];
          a1 += CH1[(vys + k + 10) * 64 + vx] - CH1[(vys + k - 1) * 64 + vx];
        }
        #pragma unroll
        for (int h = 0; h < 2; h++) {
          int d = d0 + h;
          float cs = h ? a1 : a0;
          float rs = RV1[(vys + k) * 112 + vx + d + 24];
          float r2 = RV2[(vys + k) * 112 + vx + d + 24];
          if (headLane) {            // d>0 here; mask taps u<0 (t in [gx-5+d, d-1])
            int a = max(gx - 5 + d, 0);
            int bI = d;              // = (d-1)+1, <=24
            rs -= P1[(vys + k) * 25 + bI] - P1[(vys + k) * 25 + a];
            r2 -= P2[(vys + k) * 25 + bI] - P2[(vys + k) * 25 + a];
          }
          if (tailLane) {            // d<0 here; mask taps u>=W2 (t in [480+d, gx+5+d])
            int a = 24 + d;          // (480+d)-456
            int bI = min(gx + 5 + d, 479) - 455;
            rs -= P1[(vys + k) * 25 + bI] - P1[(vys + k) * 25 + a];
            r2 -= P2[(vys + k) * 25 + bI] - P2[(vys + k) * 25 + a];
          }
          float rmv = rs * (1.f / 121.f);
          float r2v = r2 * (1.f / 121.f);
          float rstd = sqrtf(fmaxf(r2v - rmv * rmv, 1e-8f));
          float num = cs * (1.f / 121.f) - lmv[k] * rmv;
          float den = lsv[k] * rstd + 1e-8f;
          // num/den > bnum/bden  (dens > 0)
          if (num * bden[k] > bnum[k] * den) { bnum[k] = num; bden[k] = den; bdd[k] = (float)d; }
        }
      }
    }
    __syncthreads();
  }

  if (gx < W2) {
    float* bcp = grp ? bc1 : bc0;
    float* bdp = grp ? bd1 : bd0;
    #pragma unroll
    for (int k = 0; k < 4; k++) {
      size_t o = (size_t)b * (H2 * W2) + (size_t)(y0 + vys + k) * W2 + gx;
      bcp[o] = bnum[k] / bden[k];
      bdp[o] = bdd[k];
    }
  }
}

// ------- fused per-pixel kernel (merges the two d-groups) -------
__global__ __launch_bounds__(256) void k_pixel(const float* __restrict__ pred,
                                               const float* __restrict__ gt,
                                               const float* __restrict__ conf,
                                               const float* __restrict__ occ,
                                               const float* __restrict__ left,
                                               const float* __restrict__ right,
                                               const float* __restrict__ bc0,
                                               const float* __restrict__ bd0,
                                               const float* __restrict__ bc1,
                                               const float* __restrict__ bd1,
                                               float* __restrict__ partials) {
  int tid = blockIdx.x * 256 + threadIdx.x;
  float v[NSLOT];
  #pragma unroll
  for (int s = 0; s < NSLOT; s++) v[s] = 0.f;

  if (tid < NF) {
    int b = tid / (H * W);
    int rem = tid % (H * W);
    int y = rem / W, x = rem % W;
    const float* dispb = pred + (size_t)b * H * W;
    const float* lb = left  + (size_t)b * 3 * H * W;
    const float* rb = right + (size_t)b * 3 * H * W;

    {
      float g = gt[tid];
      float trust = (g > 2.0f) ? conf[tid] * occ[tid] : 0.f;
      v[0] = trust * fabsf(dispb[y * W + x] - g);
      v[1] = trust;
    }

    float ds = dispb[y * W + x];
    {
      float xs = (float)x - ds;
      bool valid = (xs > 0.f) && (xs < (float)(W - 1));

      float sl[3] = {0,0,0}, sw[3] = {0,0,0}, sl2[3] = {0,0,0},
            sw2[3] = {0,0,0}, slw[3] = {0,0,0};
      float cl[3] = {0,0,0}, cw[3] = {0,0,0};
      for (int ky = -1; ky <= 1; ky++) {
        int yy = y + ky; if (yy < 0 || yy >= H) continue;
        for (int kx = -1; kx <= 1; kx++) {
          int xx = x + kx; if (xx < 0 || xx >= W) continue;
          float dv = dispb[yy * W + xx];
          float xsv = (float)xx - dv;
          float xc = fminf(fmaxf(xsv, 0.f), (float)(W - 1));
          float x0f = floorf(xc);
          float w = xc - x0f;
          int x0i = (int)x0f;
          int x1i = min(x0i + 1, W - 1);
          #pragma unroll
          for (int c = 0; c < 3; c++) {
            float lv = lb[(size_t)(c * H + yy) * W + xx];
            const float* rc = rb + (size_t)(c * H + yy) * W;
            float wv = rc[x0i] * (1.f - w) + rc[x1i] * w;
            sl[c] += lv; sw[c] += wv;
            sl2[c] += lv * lv; sw2[c] += wv * wv; slw[c] += lv * wv;
            if (ky == 0 && kx == 0) { cl[c] = lv; cw[c] = wv; }
          }
        }
      }
      float ssm = 0.f, l1m = 0.f;
      #pragma unroll
      for (int c = 0; c < 3; c++) {
        float mx = sl[c] * (1.f / 9.f), my = sw[c] * (1.f / 9.f);
        float sx = fmaxf(sl2[c] * (1.f / 9.f) - mx * mx, 0.f);
        float sy = fmaxf(sw2[c] * (1.f / 9.f) - my * my, 0.f);
        float sxy = slw[c] * (1.f / 9.f) - mx * my;
        float n  = (2.f * mx * my + 1e-4f) * (2.f * sxy + 9e-4f);
        float dd = (mx * mx + my * my + 1e-4f) * (sx + sy + 9e-4f);
        float ss = (1.f - n / dd) * 0.5f;
        ss = fminf(fmaxf(ss, 0.f), 1.f);
        ssm += ss;
        l1m += fabsf(cl[c] - cw[c]);
      }
      ssm *= (1.f / 3.f); l1m *= (1.f / 3.f);
      float err = 0.85f * ssm + 0.15f * l1m;
      if (valid) { v[2] = err; v[3] = 1.f; }
    }

    {
      float p0 = ds;
      if (x < W - 1) {
        float ddx = fabsf(dispb[y * W + x + 1] - p0);
        float idx = 0.f;
        #pragma unroll
        for (int c = 0; c < 3; c++) {
          const float* lc = lb + (size_t)(c * H + y) * W;
          idx += fabsf(lc[x + 1] - lc[x]);
        }
        v[4] = ddx * __expf(-idx * (1.f / 3.f));
      }
      if (y < H - 1) {
        float ddy = fabsf(dispb[(y + 1) * W + x] - p0);
        float idy = 0.f;
        #pragma unroll
        for (int c = 0; c < 3; c++) {
          const float* lc = lb + (size_t)(c * H) * W;
          idy += fabsf(lc[(y + 1) * W + x] - lc[y * W + x]);
        }
        v[5] = ddy * __expf(-idy * (1.f / 3.f));
      }
    }

    {
      size_t hidx = (size_t)b * H2 * W2 + (size_t)(y >> 1) * W2 + (x >> 1);
      float c0v = bc0[hidx], c1v = bc1[hidx];
      float bcv, bdvv;
      if (c1v > c0v) { bcv = c1v; bdvv = bd1[hidx]; }
      else           { bcv = c0v; bdvv = bd0[hidx]; }
      if (bcv > 0.3f) {
        float nd = bdvv * 2.f;
        float p = ds;
        float sgn = (nd > 0.f) ? 1.f : ((nd < 0.f) ? -1.f : 0.f);
        v[6] = fmaxf(-p * sgn, 0.f);
        v[7] = bcv * fabsf(p - nd);
        v[8] = 1.f;
      }
    }
  }

  __shared__ float sm[4][NSLOT];
  int wave = threadIdx.x >> 6, lane = threadIdx.x & 63;
  #pragma unroll
  for (int s = 0; s < NSLOT; s++) {
    float r = waveSum(v[s]);
    if (lane == 0) sm[wave][s] = r;
  }
  __syncthreads();
  if (threadIdx.x < NSLOT) {
    float t = sm[0][threadIdx.x] + sm[1][threadIdx.x] +
              sm[2][threadIdx.x] + sm[3][threadIdx.x];
    partials[(size_t)threadIdx.x * NBLK + blockIdx.x] = t;
  }
}

// ---------------- final reduction + scalar composition ----------------
__global__ __launch_bounds__(256) void k_final(const float* __restrict__ P,
                                               float* __restrict__ out) {
  __shared__ float red[NSLOT][4];
  int lane = threadIdx.x & 63, wave = threadIdx.x >> 6;
  #pragma unroll
  for (int s = 0; s < NSLOT; s++) {
    float l = 0.f;
    for (int i = threadIdx.x; i < NBLK; i += 256) l += P[(size_t)s * NBLK + i];
    l = waveSum(l);
    if (lane == 0) red[s][wave] = l;
  }
  __syncthreads();
  if (threadIdx.x == 0) {
    float a[NSLOT];
    #pragma unroll
    for (int s = 0; s < NSLOT; s++) a[s] = red[s][0] + red[s][1] + red[s][2] + red[s][3];
    float gtl = a[0] / fmaxf(a[1], 1.f);
    float ph  = a[2] / fmaxf(a[3], 1.f);
    float n   = fmaxf(a[8], 1.f);
    float smv = 0.3f * (a[6] / n) + 0.7f * (a[7] / n);
    float smo = a[4] * (1.f / ((float)B * H * (W - 1)))
              + a[5] * (1.f / ((float)B * (H - 1) * W));
    out[0] = gtl + ph + 0.5f * smv + 0.1f * smo;
  }
}

extern "C" void kernel_launch(void* const* d_in, const int* in_sizes, int n_in,
                              void* d_out, int out_size, void* d_ws, size_t ws_size,
                              hipStream_t stream) {
  const float* pred  = (const float*)d_in[0];
  const float* gt    = (const float*)d_in[1];
  const float* conf  = (const float*)d_in[2];
  const float* occ   = (const float*)d_in[3];
  const float* left  = (const float*)d_in[4];
  const float* right = (const float*)d_in[5];
  float* out = (float*)d_out;

  float* ws = (float*)d_ws;
  float* lg  = ws;
  float* rg  = ws + (size_t)NH;
  float* bc0 = ws + 2 * (size_t)NH;
  float* bd0 = ws + 3 * (size_t)NH;
  float* bc1 = ws + 4 * (size_t)NH;
  float* bd1 = ws + 5 * (size_t)NH;
  float* partials = ws + 6 * (size_t)NH;   // NSLOT * NBLK floats

  k_down<<<(NH + 255) / 256, 256, 0, stream>>>(left, right, lg, rg);

  dim3 nccGrid(8, 17, 8);   // x-tiles, y-tiles, batch*2 d-groups
  k_ncc<<<nccGrid, 256, 0, stream>>>(lg, rg, bc0, bd0, bc1, bd1);

  k_pixel<<<NBLK, 256, 0, stream>>>(pred, gt, conf, occ, left, right,
                                    bc0, bd0, bc1, bd1, partials);

  k_final<<<1, 256, 0, stream>>>(partials, out);
}

// Round 4
// 312.367 us; speedup vs baseline: 13.0706x; 1.0844x over previous
//
#include <hip/hip_runtime.h>
#include <hip/hip_bf16.h>

// Problem constants (match reference setup_inputs / hyperparams)
constexpr int B  = 4;
constexpr int H  = 544;
constexpr int W  = 960;
constexpr int H2 = 272;   // half-res
constexpr int W2 = 480;
constexpr int NH = B * H2 * W2;     // 522240
constexpr int NF = B * H * W;       // 2088960
constexpr int NSLOT = 9;

// k_pixel tiling: 32x8 outputs per block, halo 1 -> 34x10 staged
constexpr int TPW = 32, TPH = 8;
constexpr int SW = TPW + 2, SH = TPH + 2;      // 34 x 10
constexpr int NSTAGE = SW * SH;                // 340
constexpr int GX = W / TPW;                    // 30
constexpr int GY = H / TPH;                    // 68
constexpr int NBLK = GX * GY * B;              // 8160

__device__ inline float waveSum(float v) {
  #pragma unroll
  for (int off = 32; off > 0; off >>= 1) v += __shfl_down(v, off, 64);
  return v;
}

// ---------------- downsample to half-res grayscale ----------------
__global__ __launch_bounds__(256) void k_down(const float* __restrict__ left,
                                              const float* __restrict__ right,
                                              float* __restrict__ lg,
                                              float* __restrict__ rg) {
  int tid = blockIdx.x * 256 + threadIdx.x;
  if (tid >= NH) return;
  int b = tid / (H2 * W2);
  int rem = tid % (H2 * W2);
  int y = rem / W2, x = rem % W2;
  const float* lb = left  + (size_t)b * 3 * H * W;
  const float* rb = right + (size_t)b * 3 * H * W;
  int y2 = 2 * y, x2 = 2 * x;
  float sl = 0.f, sr = 0.f;
  #pragma unroll
  for (int c = 0; c < 3; c++) {
    const float* lp = lb + (size_t)(c * H + y2) * W + x2;
    const float* rp = rb + (size_t)(c * H + y2) * W + x2;
    sl += lp[0] + lp[1] + lp[W] + lp[W + 1];
    sr += rp[0] + rp[1] + rp[W] + rp[W + 1];
  }
  lg[tid] = sl * (1.f / 12.f);
  rg[tid] = sr * (1.f / 12.f);
}

// ---------------- fused NCC disparity search ----------------
__global__ __launch_bounds__(256) void k_ncc(const float* __restrict__ lg,
                                             const float* __restrict__ rg,
                                             float* __restrict__ bc0,
                                             float* __restrict__ bd0,
                                             float* __restrict__ bc1,
                                             float* __restrict__ bd1) {
  const int z = blockIdx.z;
  const int b = z >> 1, grp = z & 1;
  const int x0 = blockIdx.x * 64;
  const int y0 = blockIdx.y * 16;
  const int tid = threadIdx.x;

  __shared__ float SM[13462];
  float* LGs = SM;            // 26 x 74
  float* RV1 = SM + 1924;     // 16 x 112
  float* RV2 = SM + 3716;
  float* POOL= SM + 5508;     // 3904
  float* P1  = SM + 9412;     // 16 x 25
  float* P2  = SM + 9812;
  float* RGs = SM + 10212;    // 26 x 125

  const float* lgb = lg + (size_t)b * (H2 * W2);
  const float* rgb = rg + (size_t)b * (H2 * W2);

  for (int e = tid; e < 26 * 74; e += 256) {
    int r = e / 74, c = e % 74;
    int gy = y0 - 5 + r, gxx = x0 - 5 + c;
    LGs[r * 74 + c] = (gy >= 0 && gy < H2 && gxx >= 0 && gxx < W2) ? lgb[gy * W2 + gxx] : 0.f;
  }
  for (int e = tid; e < 26 * 122; e += 256) {
    int r = e / 122, c = e % 122;
    int gy = y0 - 5 + r, gxx = x0 - 29 + c;
    RGs[r * 125 + c] = (gy >= 0 && gy < H2 && gxx >= 0 && gxx < W2) ? rgb[gy * W2 + gxx] : 0.f;
  }
  __syncthreads();

  const int hg = tid & 7, hr = tid >> 3;
  float lgc[18];
  float* LH1 = POOL;          // 26 x 64
  float* LH2 = POOL + 1664;
  if (hr < 26) {
    #pragma unroll
    for (int k = 0; k < 18; k++) lgc[k] = LGs[hr * 74 + 8 * hg + k];
    float w1[8], w2[8];
    float s1 = 0.f, s2 = 0.f;
    #pragma unroll
    for (int k = 0; k < 11; k++) { s1 += lgc[k]; s2 += lgc[k] * lgc[k]; }
    w1[0] = s1; w2[0] = s2;
    #pragma unroll
    for (int j = 1; j < 8; j++) {
      s1 += lgc[j + 10] - lgc[j - 1];
      s2 += lgc[j + 10] * lgc[j + 10] - lgc[j - 1] * lgc[j - 1];
      w1[j] = s1; w2[j] = s2;
    }
    *(float4*)&LH1[hr * 64 + 8 * hg]     = make_float4(w1[0], w1[1], w1[2], w1[3]);
    *(float4*)&LH1[hr * 64 + 8 * hg + 4] = make_float4(w1[4], w1[5], w1[6], w1[7]);
    *(float4*)&LH2[hr * 64 + 8 * hg]     = make_float4(w2[0], w2[1], w2[2], w2[3]);
    *(float4*)&LH2[hr * 64 + 8 * hg + 4] = make_float4(w2[4], w2[5], w2[6], w2[7]);
  }
  const bool headTile = (x0 == 0), tailTile = (x0 == 448);
  if (headTile || tailTile) {
    int cl0 = headTile ? 29 : 37;
    for (int e = tid; e < 16 * 24; e += 256) {
      int y = e / 24, i = e % 24;
      float v1 = 0.f, v2 = 0.f;
      #pragma unroll
      for (int dy = 0; dy < 11; dy++) {
        float v = RGs[(y + dy) * 125 + cl0 + i];
        v1 += v; v2 += v * v;
      }
      P1[y * 25 + i + 1] = v1;
      P2[y * 25 + i + 1] = v2;
    }
  }
  __syncthreads();

  if ((headTile || tailTile) && tid < 16) {
    int y = tid;
    float s1 = 0.f, s2 = 0.f;
    P1[y * 25] = 0.f; P2[y * 25] = 0.f;
    for (int k = 0; k < 24; k++) {
      s1 += P1[y * 25 + k + 1]; P1[y * 25 + k + 1] = s1;
      s2 += P2[y * 25 + k + 1]; P2[y * 25 + k + 1] = s2;
    }
  }
  const int vx = tid & 63;
  const int vys = (tid >> 6) * 4;
  float lmv[4], lsv[4];
  {
    float s1 = 0.f, s2 = 0.f;
    #pragma unroll
    for (int dy = 0; dy < 11; dy++) { s1 += LH1[(vys + dy) * 64 + vx]; s2 += LH2[(vys + dy) * 64 + vx]; }
    #pragma unroll
    for (int k = 0; k < 4; k++) {
      if (k) {
        s1 += LH1[(vys + k + 10) * 64 + vx] - LH1[(vys + k - 1) * 64 + vx];
        s2 += LH2[(vys + k + 10) * 64 + vx] - LH2[(vys + k - 1) * 64 + vx];
      }
      float m = s1 * (1.f / 121.f);
      lmv[k] = m;
      lsv[k] = sqrtf(fmaxf(s2 * (1.f / 121.f) - m * m, 1e-8f));
    }
  }
  __syncthreads();

  float* VR1 = POOL;          // 16 x 122
  float* VR2 = POOL + 1952;
  if (tid < 244) {
    int c = tid % 122;
    int r0 = (tid / 122) * 8;
    float s1 = 0.f, s2 = 0.f;
    #pragma unroll
    for (int dy = 0; dy < 11; dy++) {
      float v = RGs[(r0 + dy) * 125 + c];
      s1 += v; s2 += v * v;
    }
    VR1[r0 * 122 + c] = s1; VR2[r0 * 122 + c] = s2;
    #pragma unroll
    for (int k = 1; k < 8; k++) {
      float vin  = RGs[(r0 + k + 10) * 125 + c];
      float vout = RGs[(r0 + k - 1) * 125 + c];
      s1 += vin - vout;
      s2 += vin * vin - vout * vout;
      VR1[(r0 + k) * 122 + c] = s1; VR2[(r0 + k) * 122 + c] = s2;
    }
  }
  __syncthreads();

  {
    int r = tid >> 4, seg = tid & 15;
    int c0 = seg * 7;
    float s1 = 0.f, s2 = 0.f;
    #pragma unroll
    for (int m = 0; m < 11; m++) { s1 += VR1[r * 122 + c0 + m]; s2 += VR2[r * 122 + c0 + m]; }
    RV1[r * 112 + c0] = s1; RV2[r * 112 + c0] = s2;
    #pragma unroll
    for (int j = 1; j < 7; j++) {
      s1 += VR1[r * 122 + c0 + j + 10] - VR1[r * 122 + c0 + j - 1];
      s2 += VR2[r * 122 + c0 + j + 10] - VR2[r * 122 + c0 + j - 1];
      RV1[r * 112 + c0 + j] = s1; RV2[r * 112 + c0 + j] = s2;
    }
  }
  __syncthreads();

  float* CH0 = POOL;          // 26 x 64
  float* CH1 = POOL + 1664;
  const int dstart = grp ? 1 : -24;
  const int gx = x0 + vx;
  const bool headLane = grp && (gx < 5);
  const bool tailLane = (!grp) && (gx > 474);
  float bnum[4], bden[4], bdd[4];
  #pragma unroll
  for (int k = 0; k < 4; k++) { bnum[k] = -1.f; bden[k] = 1.f; bdd[k] = 0.f; }

  for (int it = 0; it < 12; ++it) {
    const int d0 = dstart + 2 * it;
    if (hr < 26) {
      const int c0 = 8 * hg + d0 + 24;
      float rgv[19];
      #pragma unroll
      for (int j = 0; j < 19; j++) rgv[j] = RGs[hr * 125 + c0 + j];
      float ca[8], cb[8];
      float sa = 0.f, sb = 0.f;
      #pragma unroll
      for (int k = 0; k < 11; k++) { sa += lgc[k] * rgv[k]; sb += lgc[k] * rgv[k + 1]; }
      ca[0] = sa; cb[0] = sb;
      #pragma unroll
      for (int j = 1; j < 8; j++) {
        sa += lgc[j + 10] * rgv[j + 10] - lgc[j - 1] * rgv[j - 1];
        sb += lgc[j + 10] * rgv[j + 11] - lgc[j - 1] * rgv[j];
        ca[j] = sa; cb[j] = sb;
      }
      *(float4*)&CH0[hr * 64 + 8 * hg]     = make_float4(ca[0], ca[1], ca[2], ca[3]);
      *(float4*)&CH0[hr * 64 + 8 * hg + 4] = make_float4(ca[4], ca[5], ca[6], ca[7]);
      *(float4*)&CH1[hr * 64 + 8 * hg]     = make_float4(cb[0], cb[1], cb[2], cb[3]);
      *(float4*)&CH1[hr * 64 + 8 * hg + 4] = make_float4(cb[4], cb[5], cb[6], cb[7]);
    }
    __syncthreads();
    {
      float a0 = 0.f, a1 = 0.f;
      #pragma unroll
      for (int dy = 0; dy < 11; dy++) { a0 += CH0[(vys + dy) * 64 + vx]; a1 += CH1[(vys + dy) * 64 + vx]; }
      #pragma unroll
      for (int k = 0; k < 4; k++) {
        if (k) {
          a0 += CH0[(vys + k + 10) * 64 + vx] - CH0[(vys + k - 1) * 64 + vx];
          a1 += CH1[(vys + k + 10) * 64 + vx] - CH1[(vys + k - 1) * 64 + vx];
        }
        #pragma unroll
        for (int h = 0; h < 2; h++) {
          int d = d0 + h;
          float cs = h ? a1 : a0;
          float rs = RV1[(vys + k) * 112 + vx + d + 24];
          float r2 = RV2[(vys + k) * 112 + vx + d + 24];
          if (headLane) {
            int a = max(gx - 5 + d, 0);
            int bI = d;
            rs -= P1[(vys + k) * 25 + bI] - P1[(vys + k) * 25 + a];
            r2 -= P2[(vys + k) * 25 + bI] - P2[(vys + k) * 25 + a];
          }
          if (tailLane) {
            int a = 24 + d;
            int bI = min(gx + 5 + d, 479) - 455;
            rs -= P1[(vys + k) * 25 + bI] - P1[(vys + k) * 25 + a];
            r2 -= P2[(vys + k) * 25 + bI] - P2[(vys + k) * 25 + a];
          }
          float rmv = rs * (1.f / 121.f);
          float r2v = r2 * (1.f / 121.f);
          float rstd = sqrtf(fmaxf(r2v - rmv * rmv, 1e-8f));
          float num = cs * (1.f / 121.f) - lmv[k] * rmv;
          float den = lsv[k] * rstd + 1e-8f;
          if (num * bden[k] > bnum[k] * den) { bnum[k] = num; bden[k] = den; bdd[k] = (float)d; }
        }
      }
    }
    __syncthreads();
  }

  if (gx < W2) {
    float* bcp = grp ? bc1 : bc0;
    float* bdp = grp ? bd1 : bd0;
    #pragma unroll
    for (int k = 0; k < 4; k++) {
      size_t o = (size_t)b * (H2 * W2) + (size_t)(y0 + vys + k) * W2 + gx;
      bcp[o] = bnum[k] / bden[k];
      bdp[o] = bdd[k];
    }
  }
}

// ------- fused per-pixel kernel, LDS-staged warp + neighborhoods -------
__global__ __launch_bounds__(256) void k_pixel(const float* __restrict__ pred,
                                               const float* __restrict__ gt,
                                               const float* __restrict__ conf,
                                               const float* __restrict__ occ,
                                               const float* __restrict__ left,
                                               const float* __restrict__ right,
                                               const float* __restrict__ bc0,
                                               const float* __restrict__ bd0,
                                               const float* __restrict__ bc1,
                                               const float* __restrict__ bd1,
                                               float* __restrict__ partials) {
  const int bx = blockIdx.x % GX;
  const int by = (blockIdx.x / GX) % GY;
  const int b  = blockIdx.x / (GX * GY);
  const int x0 = bx * TPW, y0 = by * TPH;
  const int tid = threadIdx.x;

  const float* dispb = pred + (size_t)b * H * W;
  const float* lb = left  + (size_t)b * 3 * H * W;
  const float* rb = right + (size_t)b * 3 * H * W;

  __shared__ float4 L4s[NSTAGE];   // (lv0, lv1, lv2, disp); zeros if OOB
  __shared__ float4 W4s[NSTAGE];   // (wv0, wv1, wv2, 0);    zeros if OOB

  // ---- stage 34x10 input pixels: left RGB + disp + warped-right RGB ----
  for (int e = tid; e < NSTAGE; e += 256) {
    int r = e / SW, c = e % SW;
    int yy = y0 - 1 + r, xx = x0 - 1 + c;
    float4 l4 = make_float4(0.f, 0.f, 0.f, 0.f);
    float4 w4 = make_float4(0.f, 0.f, 0.f, 0.f);
    if (yy >= 0 && yy < H && xx >= 0 && xx < W) {
      float dv = dispb[yy * W + xx];
      float xsv = (float)xx - dv;
      float xc = fminf(fmaxf(xsv, 0.f), (float)(W - 1));
      float x0f = floorf(xc);
      float w = xc - x0f;
      int x0i = (int)x0f;
      int x1i = min(x0i + 1, W - 1);
      const float* l0 = lb + (size_t)yy * W;
      const float* r0 = rb + (size_t)yy * W;
      l4.x = l0[xx];
      l4.y = l0[(size_t)H * W + xx];
      l4.z = l0[2 * (size_t)H * W + xx];
      l4.w = dv;
      w4.x = r0[x0i] * (1.f - w) + r0[x1i] * w;
      w4.y = r0[(size_t)H * W + x0i] * (1.f - w) + r0[(size_t)H * W + x1i] * w;
      w4.z = r0[2 * (size_t)H * W + x0i] * (1.f - w) + r0[2 * (size_t)H * W + x1i] * w;
    }
    L4s[e] = l4; W4s[e] = w4;
  }
  __syncthreads();

  float v[NSLOT];
  #pragma unroll
  for (int s = 0; s < NSLOT; s++) v[s] = 0.f;

  {
    const int tx = tid & 31, ty = tid >> 5;
    const int x = x0 + tx, y = y0 + ty;
    const size_t gidx = (size_t)b * H * W + (size_t)y * W + x;
    const int ci = (ty + 1) * SW + (tx + 1);

    // ---- 3x3 sums from LDS; capture center/right/down on the way ----
    float sl[3] = {0,0,0}, sw[3] = {0,0,0}, sl2[3] = {0,0,0},
          sw2[3] = {0,0,0}, slw[3] = {0,0,0};
    float4 cl4, cw4, rl4, dl4;
    #pragma unroll
    for (int dy = -1; dy <= 1; dy++) {
      #pragma unroll
      for (int dx = -1; dx <= 1; dx++) {
        int ni = ci + dy * SW + dx;
        float4 a = L4s[ni];
        float4 wv = W4s[ni];
        sl[0] += a.x;  sl2[0] += a.x * a.x;  sw[0] += wv.x;  sw2[0] += wv.x * wv.x;  slw[0] += a.x * wv.x;
        sl[1] += a.y;  sl2[1] += a.y * a.y;  sw[1] += wv.y;  sw2[1] += wv.y * wv.y;  slw[1] += a.y * wv.y;
        sl[2] += a.z;  sl2[2] += a.z * a.z;  sw[2] += wv.z;  sw2[2] += wv.z * wv.z;  slw[2] += a.z * wv.z;
        if (dy == 0 && dx == 0) { cl4 = a; cw4 = wv; }
        if (dy == 0 && dx == 1) rl4 = a;
        if (dy == 1 && dx == 0) dl4 = a;
      }
    }
    float ds = cl4.w;

    // ---- gt anchor ----
    {
      float g = gt[gidx];
      float trust = (g > 2.0f) ? conf[gidx] * occ[gidx] : 0.f;
      v[0] = trust * fabsf(ds - g);
      v[1] = trust;
    }

    // ---- photometric ----
    {
      float xs = (float)x - ds;
      bool valid = (xs > 0.f) && (xs < (float)(W - 1));
      float cl[3] = {cl4.x, cl4.y, cl4.z};
      float cw[3] = {cw4.x, cw4.y, cw4.z};
      float ssm = 0.f, l1m = 0.f;
      #pragma unroll
      for (int c = 0; c < 3; c++) {
        float mx = sl[c] * (1.f / 9.f), my = sw[c] * (1.f / 9.f);
        float sx = fmaxf(sl2[c] * (1.f / 9.f) - mx * mx, 0.f);
        float sy = fmaxf(sw2[c] * (1.f / 9.f) - my * my, 0.f);
        float sxy = slw[c] * (1.f / 9.f) - mx * my;
        float n  = (2.f * mx * my + 1e-4f) * (2.f * sxy + 9e-4f);
        float dd = (mx * mx + my * my + 1e-4f) * (sx + sy + 9e-4f);
        float ss = (1.f - n / dd) * 0.5f;
        ss = fminf(fmaxf(ss, 0.f), 1.f);
        ssm += ss;
        l1m += fabsf(cl[c] - cw[c]);
      }
      ssm *= (1.f / 3.f); l1m *= (1.f / 3.f);
      float err = 0.85f * ssm + 0.15f * l1m;
      if (valid) { v[2] = err; v[3] = 1.f; }
    }

    // ---- smoothness (right/down neighbors from LDS) ----
    if (x < W - 1) {
      float ddx = fabsf(rl4.w - ds);
      float idx = fabsf(rl4.x - cl4.x) + fabsf(rl4.y - cl4.y) + fabsf(rl4.z - cl4.z);
      v[4] = ddx * __expf(-idx * (1.f / 3.f));
    }
    if (y < H - 1) {
      float ddy = fabsf(dl4.w - ds);
      float idy = fabsf(dl4.x - cl4.x) + fabsf(dl4.y - cl4.y) + fabsf(dl4.z - cl4.z);
      v[5] = ddy * __expf(-idy * (1.f / 3.f));
    }

    // ---- sign / magnitude vs NCC pseudo-disparity ----
    {
      size_t hidx = (size_t)b * H2 * W2 + (size_t)(y >> 1) * W2 + (x >> 1);
      float c0v = bc0[hidx], c1v = bc1[hidx];
      float bcv, bdvv;
      if (c1v > c0v) { bcv = c1v; bdvv = bd1[hidx]; }
      else           { bcv = c0v; bdvv = bd0[hidx]; }
      if (bcv > 0.3f) {
        float nd = bdvv * 2.f;
        float sgn = (nd > 0.f) ? 1.f : ((nd < 0.f) ? -1.f : 0.f);
        v[6] = fmaxf(-ds * sgn, 0.f);
        v[7] = bcv * fabsf(ds - nd);
        v[8] = 1.f;
      }
    }
  }

  __shared__ float sm[4][NSLOT];
  int wave = threadIdx.x >> 6, lane = threadIdx.x & 63;
  #pragma unroll
  for (int s = 0; s < NSLOT; s++) {
    float r = waveSum(v[s]);
    if (lane == 0) sm[wave][s] = r;
  }
  __syncthreads();
  if (threadIdx.x < NSLOT) {
    float t = sm[0][threadIdx.x] + sm[1][threadIdx.x] +
              sm[2][threadIdx.x] + sm[3][threadIdx.x];
    partials[(size_t)threadIdx.x * NBLK + blockIdx.x] = t;
  }
}

// ---------------- final reduction + scalar composition ----------------
__global__ __launch_bounds__(256) void k_final(const float* __restrict__ P,
                                               float* __restrict__ out) {
  __shared__ float red[NSLOT][4];
  int lane = threadIdx.x & 63, wave = threadIdx.x >> 6;
  #pragma unroll
  for (int s = 0; s < NSLOT; s++) {
    float l = 0.f;
    for (int i = threadIdx.x; i < NBLK; i += 256) l += P[(size_t)s * NBLK + i];
    l = waveSum(l);
    if (lane == 0) red[s][wave] = l;
  }
  __syncthreads();
  if (threadIdx.x == 0) {
    float a[NSLOT];
    #pragma unroll
    for (int s = 0; s < NSLOT; s++) a[s] = red[s][0] + red[s][1] + red[s][2] + red[s][3];
    float gtl = a[0] / fmaxf(a[1], 1.f);
    float ph  = a[2] / fmaxf(a[3], 1.f);
    float n   = fmaxf(a[8], 1.f);
    float smv = 0.3f * (a[6] / n) + 0.7f * (a[7] / n);
    float smo = a[4] * (1.f / ((float)B * H * (W - 1)))
              + a[5] * (1.f / ((float)B * (H - 1) * W));
    out[0] = gtl + ph + 0.5f * smv + 0.1f * smo;
  }
}

extern "C" void kernel_launch(void* const* d_in, const int* in_sizes, int n_in,
                              void* d_out, int out_size, void* d_ws, size_t ws_size,
                              hipStream_t stream) {
  const float* pred  = (const float*)d_in[0];
  const float* gt    = (const float*)d_in[1];
  const float* conf  = (const float*)d_in[2];
  const float* occ   = (const float*)d_in[3];
  const float* left  = (const float*)d_in[4];
  const float* right = (const float*)d_in[5];
  float* out = (float*)d_out;

  float* ws = (float*)d_ws;
  float* lg  = ws;
  float* rg  = ws + (size_t)NH;
  float* bc0 = ws + 2 * (size_t)NH;
  float* bd0 = ws + 3 * (size_t)NH;
  float* bc1 = ws + 4 * (size_t)NH;
  float* bd1 = ws + 5 * (size_t)NH;
  float* partials = ws + 6 * (size_t)NH;   // NSLOT * NBLK floats

  k_down<<<(NH + 255) / 256, 256, 0, stream>>>(left, right, lg, rg);

  dim3 nccGrid(8, 17, 8);   // x-tiles, y-tiles, batch*2 d-groups
  k_ncc<<<nccGrid, 256, 0, stream>>>(lg, rg, bc0, bd0, bc1, bd1);

  k_pixel<<<NBLK, 256, 0, stream>>>(pred, gt, conf, occ, left, right,
                                    bc0, bd0, bc1, bd1, partials);

  k_final<<<1, 256, 0, stream>>>(partials, out);
}

// Round 5
// 289.100 us; speedup vs baseline: 14.1226x; 1.0805x over previous
//
#include <hip/hip_runtime.h>
#include <hip/hip_bf16.h>

// Problem constants (match reference setup_inputs / hyperparams)
constexpr int B  = 4;
constexpr int H  = 544;
constexpr int W  = 960;
constexpr int H2 = 272;   // half-res
constexpr int W2 = 480;
constexpr int NH = B * H2 * W2;     // 522240
constexpr int NF = B * H * W;       // 2088960

// pixel kernel tiling: 32x8 outputs per block, halo 1 -> 34x10 staged
constexpr int TPW = 32, TPH = 8;
constexpr int SW = TPW + 2, SH = TPH + 2;      // 34 x 10
constexpr int NSTAGE = SW * SH;                // 340
constexpr int GX = W / TPW;                    // 30
constexpr int GY = H / TPH;                    // 68
constexpr int NBLK  = GX * GY * B;             // 8160 (k_pix blocks)
constexpr int NBLK2 = (NH + 255) / 256;        // 2040 (k_sgm blocks)

__device__ inline float waveSum(float v) {
  #pragma unroll
  for (int off = 32; off > 0; off >>= 1) v += __shfl_down(v, off, 64);
  return v;
}

// ------- fused pixel kernel: gt + photometric + smoothness + lg/rg downsample -------
__global__ __launch_bounds__(256) void k_pix(const float* __restrict__ pred,
                                             const float* __restrict__ gt,
                                             const float* __restrict__ conf,
                                             const float* __restrict__ occ,
                                             const float* __restrict__ left,
                                             const float* __restrict__ right,
                                             float* __restrict__ lg,
                                             float* __restrict__ rg,
                                             float* __restrict__ partialsA) {
  const int bx = blockIdx.x % GX;
  const int by = (blockIdx.x / GX) % GY;
  const int b  = blockIdx.x / (GX * GY);
  const int x0 = bx * TPW, y0 = by * TPH;
  const int tid = threadIdx.x;

  const float* dispb = pred + (size_t)b * H * W;
  const float* lb = left  + (size_t)b * 3 * H * W;
  const float* rb = right + (size_t)b * 3 * H * W;

  __shared__ float4 L4s[NSTAGE];   // (lv0, lv1, lv2, disp); zeros if OOB
  __shared__ float4 W4s[NSTAGE];   // (wv0, wv1, wv2, 0);    zeros if OOB

  // ---- stage 34x10 input pixels: left RGB + disp + warped-right RGB ----
  for (int e = tid; e < NSTAGE; e += 256) {
    int r = e / SW, c = e % SW;
    int yy = y0 - 1 + r, xx = x0 - 1 + c;
    float4 l4 = make_float4(0.f, 0.f, 0.f, 0.f);
    float4 w4 = make_float4(0.f, 0.f, 0.f, 0.f);
    if (yy >= 0 && yy < H && xx >= 0 && xx < W) {
      float dv = dispb[yy * W + xx];
      float xsv = (float)xx - dv;
      float xc = fminf(fmaxf(xsv, 0.f), (float)(W - 1));
      float x0f = floorf(xc);
      float w = xc - x0f;
      int x0i = (int)x0f;
      int x1i = min(x0i + 1, W - 1);
      const float* l0 = lb + (size_t)yy * W;
      const float* r0 = rb + (size_t)yy * W;
      l4.x = l0[xx];
      l4.y = l0[(size_t)H * W + xx];
      l4.z = l0[2 * (size_t)H * W + xx];
      l4.w = dv;
      w4.x = r0[x0i] * (1.f - w) + r0[x1i] * w;
      w4.y = r0[(size_t)H * W + x0i] * (1.f - w) + r0[(size_t)H * W + x1i] * w;
      w4.z = r0[2 * (size_t)H * W + x0i] * (1.f - w) + r0[2 * (size_t)H * W + x1i] * w;
    }
    L4s[e] = l4; W4s[e] = w4;
  }
  __syncthreads();

  // ---- lg/rg emission (threads 0..63): 16x4 half-res pixels of this tile ----
  if (tid < 64) {
    int hx = tid & 15, hy = tid >> 4;
    int y2g = (y0 >> 1) + hy, x2g = (x0 >> 1) + hx;
    // staged indices of the 2x2 full-res block
    int i00 = (2 * hy + 1) * SW + (2 * hx + 1);
    float4 a00 = L4s[i00], a01 = L4s[i00 + 1], a10 = L4s[i00 + SW], a11 = L4s[i00 + SW + 1];
    float sl = 0.f;
    sl += a00.x + a01.x + a10.x + a11.x;
    sl += a00.y + a01.y + a10.y + a11.y;
    sl += a00.z + a01.z + a10.z + a11.z;
    float sr = 0.f;
    int yy2 = y0 + 2 * hy, xx2 = x0 + 2 * hx;
    #pragma unroll
    for (int c = 0; c < 3; c++) {
      const float* rp = rb + (size_t)(c * H + yy2) * W + xx2;
      sr += rp[0] + rp[1] + rp[W] + rp[W + 1];
    }
    size_t ho = (size_t)b * (H2 * W2) + (size_t)y2g * W2 + x2g;
    lg[ho] = sl * (1.f / 12.f);
    rg[ho] = sr * (1.f / 12.f);
  }

  float v[6];
  #pragma unroll
  for (int s = 0; s < 6; s++) v[s] = 0.f;

  {
    const int tx = tid & 31, ty = tid >> 5;
    const int x = x0 + tx, y = y0 + ty;
    const size_t gidx = (size_t)b * H * W + (size_t)y * W + x;
    const int ci = (ty + 1) * SW + (tx + 1);

    float sl[3] = {0,0,0}, sw[3] = {0,0,0}, sl2[3] = {0,0,0},
          sw2[3] = {0,0,0}, slw[3] = {0,0,0};
    float4 cl4, cw4, rl4, dl4;
    #pragma unroll
    for (int dy = -1; dy <= 1; dy++) {
      #pragma unroll
      for (int dx = -1; dx <= 1; dx++) {
        int ni = ci + dy * SW + dx;
        float4 a = L4s[ni];
        float4 wv = W4s[ni];
        sl[0] += a.x;  sl2[0] += a.x * a.x;  sw[0] += wv.x;  sw2[0] += wv.x * wv.x;  slw[0] += a.x * wv.x;
        sl[1] += a.y;  sl2[1] += a.y * a.y;  sw[1] += wv.y;  sw2[1] += wv.y * wv.y;  slw[1] += a.y * wv.y;
        sl[2] += a.z;  sl2[2] += a.z * a.z;  sw[2] += wv.z;  sw2[2] += wv.z * wv.z;  slw[2] += a.z * wv.z;
        if (dy == 0 && dx == 0) { cl4 = a; cw4 = wv; }
        if (dy == 0 && dx == 1) rl4 = a;
        if (dy == 1 && dx == 0) dl4 = a;
      }
    }
    float ds = cl4.w;

    // ---- gt anchor ----
    {
      float g = gt[gidx];
      float trust = (g > 2.0f) ? conf[gidx] * occ[gidx] : 0.f;
      v[0] = trust * fabsf(ds - g);
      v[1] = trust;
    }

    // ---- photometric ----
    {
      float xs = (float)x - ds;
      bool valid = (xs > 0.f) && (xs < (float)(W - 1));
      float cl[3] = {cl4.x, cl4.y, cl4.z};
      float cw[3] = {cw4.x, cw4.y, cw4.z};
      float ssm = 0.f, l1m = 0.f;
      #pragma unroll
      for (int c = 0; c < 3; c++) {
        float mx = sl[c] * (1.f / 9.f), my = sw[c] * (1.f / 9.f);
        float sx = fmaxf(sl2[c] * (1.f / 9.f) - mx * mx, 0.f);
        float sy = fmaxf(sw2[c] * (1.f / 9.f) - my * my, 0.f);
        float sxy = slw[c] * (1.f / 9.f) - mx * my;
        float n  = (2.f * mx * my + 1e-4f) * (2.f * sxy + 9e-4f);
        float dd = (mx * mx + my * my + 1e-4f) * (sx + sy + 9e-4f);
        float ss = (1.f - n / dd) * 0.5f;
        ss = fminf(fmaxf(ss, 0.f), 1.f);
        ssm += ss;
        l1m += fabsf(cl[c] - cw[c]);
      }
      ssm *= (1.f / 3.f); l1m *= (1.f / 3.f);
      float err = 0.85f * ssm + 0.15f * l1m;
      if (valid) { v[2] = err; v[3] = 1.f; }
    }

    // ---- smoothness ----
    if (x < W - 1) {
      float ddx = fabsf(rl4.w - ds);
      float idx = fabsf(rl4.x - cl4.x) + fabsf(rl4.y - cl4.y) + fabsf(rl4.z - cl4.z);
      v[4] = ddx * __expf(-idx * (1.f / 3.f));
    }
    if (y < H - 1) {
      float ddy = fabsf(dl4.w - ds);
      float idy = fabsf(dl4.x - cl4.x) + fabsf(dl4.y - cl4.y) + fabsf(dl4.z - cl4.z);
      v[5] = ddy * __expf(-idy * (1.f / 3.f));
    }
  }

  __shared__ float sm[4][6];
  int wave = threadIdx.x >> 6, lane = threadIdx.x & 63;
  #pragma unroll
  for (int s = 0; s < 6; s++) {
    float r = waveSum(v[s]);
    if (lane == 0) sm[wave][s] = r;
  }
  __syncthreads();
  if (threadIdx.x < 6) {
    float t = sm[0][threadIdx.x] + sm[1][threadIdx.x] +
              sm[2][threadIdx.x] + sm[3][threadIdx.x];
    partialsA[(size_t)threadIdx.x * NBLK + blockIdx.x] = t;
  }
}

// ---------------- fused NCC disparity search ----------------
// LDS layout (floats), total 13462:
//   LGs @0 26x74 | RV1 @1924 16x112 | RV2 @3716 | POOL @5508 (3904)
//   P1 @9412 16x25 | P2 @9812 | RGs @10212 26x125
// LH/CH in POOL use row-stride 68: (68*hr+8*hg)%32 = 4(hr+2hg)%32 spreads
// 64 lanes over 8 bank-quads = the b128 write floor (stride 64 gave 16/quad).
__global__ __launch_bounds__(256) void k_ncc(const float* __restrict__ lg,
                                             const float* __restrict__ rg,
                                             float* __restrict__ bc0,
                                             float* __restrict__ bd0,
                                             float* __restrict__ bc1,
                                             float* __restrict__ bd1) {
  const int z = blockIdx.z;
  const int b = z >> 1, grp = z & 1;
  const int x0 = blockIdx.x * 64;
  const int y0 = blockIdx.y * 16;
  const int tid = threadIdx.x;

  __shared__ __align__(16) float SM[13462];
  float* LGs = SM;            // 26 x 74
  float* RV1 = SM + 1924;     // 16 x 112
  float* RV2 = SM + 3716;
  float* POOL= SM + 5508;     // 3904
  float* P1  = SM + 9412;     // 16 x 25
  float* P2  = SM + 9812;
  float* RGs = SM + 10212;    // 26 x 125

  const float* lgb = lg + (size_t)b * (H2 * W2);
  const float* rgb = rg + (size_t)b * (H2 * W2);

  for (int e = tid; e < 26 * 74; e += 256) {
    int r = e / 74, c = e % 74;
    int gy = y0 - 5 + r, gxx = x0 - 5 + c;
    LGs[r * 74 + c] = (gy >= 0 && gy < H2 && gxx >= 0 && gxx < W2) ? lgb[gy * W2 + gxx] : 0.f;
  }
  for (int e = tid; e < 26 * 122; e += 256) {
    int r = e / 122, c = e % 122;
    int gy = y0 - 5 + r, gxx = x0 - 29 + c;
    RGs[r * 125 + c] = (gy >= 0 && gy < H2 && gxx >= 0 && gxx < W2) ? rgb[gy * W2 + gxx] : 0.f;
  }
  __syncthreads();

  const int hg = tid & 7, hr = tid >> 3;
  float lgc[18];
  float* LH1 = POOL;          // 26 x 68 (64 used)
  float* LH2 = POOL + 1768;
  if (hr < 26) {
    #pragma unroll
    for (int k = 0; k < 18; k++) lgc[k] = LGs[hr * 74 + 8 * hg + k];
    float w1[8], w2[8];
    float s1 = 0.f, s2 = 0.f;
    #pragma unroll
    for (int k = 0; k < 11; k++) { s1 += lgc[k]; s2 += lgc[k] * lgc[k]; }
    w1[0] = s1; w2[0] = s2;
    #pragma unroll
    for (int j = 1; j < 8; j++) {
      s1 += lgc[j + 10] - lgc[j - 1];
      s2 += lgc[j + 10] * lgc[j + 10] - lgc[j - 1] * lgc[j - 1];
      w1[j] = s1; w2[j] = s2;
    }
    *(float4*)&LH1[hr * 68 + 8 * hg]     = make_float4(w1[0], w1[1], w1[2], w1[3]);
    *(float4*)&LH1[hr * 68 + 8 * hg + 4] = make_float4(w1[4], w1[5], w1[6], w1[7]);
    *(float4*)&LH2[hr * 68 + 8 * hg]     = make_float4(w2[0], w2[1], w2[2], w2[3]);
    *(float4*)&LH2[hr * 68 + 8 * hg + 4] = make_float4(w2[4], w2[5], w2[6], w2[7]);
  }
  const bool headTile = (x0 == 0), tailTile = (x0 == 448);
  if (headTile || tailTile) {
    int cl0 = headTile ? 29 : 37;
    for (int e = tid; e < 16 * 24; e += 256) {
      int y = e / 24, i = e % 24;
      float v1 = 0.f, v2 = 0.f;
      #pragma unroll
      for (int dy = 0; dy < 11; dy++) {
        float v = RGs[(y + dy) * 125 + cl0 + i];
        v1 += v; v2 += v * v;
      }
      P1[y * 25 + i + 1] = v1;
      P2[y * 25 + i + 1] = v2;
    }
  }
  __syncthreads();

  if ((headTile || tailTile) && tid < 16) {
    int y = tid;
    float s1 = 0.f, s2 = 0.f;
    P1[y * 25] = 0.f; P2[y * 25] = 0.f;
    for (int k = 0; k < 24; k++) {
      s1 += P1[y * 25 + k + 1]; P1[y * 25 + k + 1] = s1;
      s2 += P2[y * 25 + k + 1]; P2[y * 25 + k + 1] = s2;
    }
  }
  const int vx = tid & 63;
  const int vys = (tid >> 6) * 4;
  float lmv[4], lsv[4];
  {
    float s1 = 0.f, s2 = 0.f;
    #pragma unroll
    for (int dy = 0; dy < 11; dy++) { s1 += LH1[(vys + dy) * 68 + vx]; s2 += LH2[(vys + dy) * 68 + vx]; }
    #pragma unroll
    for (int k = 0; k < 4; k++) {
      if (k) {
        s1 += LH1[(vys + k + 10) * 68 + vx] - LH1[(vys + k - 1) * 68 + vx];
        s2 += LH2[(vys + k + 10) * 68 + vx] - LH2[(vys + k - 1) * 68 + vx];
      }
      float m = s1 * (1.f / 121.f);
      lmv[k] = m;
      lsv[k] = sqrtf(fmaxf(s2 * (1.f / 121.f) - m * m, 1e-8f));
    }
  }
  __syncthreads();

  float* VR1 = POOL;          // 16 x 122
  float* VR2 = POOL + 1952;
  if (tid < 244) {
    int c = tid % 122;
    int r0 = (tid / 122) * 8;
    float s1 = 0.f, s2 = 0.f;
    #pragma unroll
    for (int dy = 0; dy < 11; dy++) {
      float v = RGs[(r0 + dy) * 125 + c];
      s1 += v; s2 += v * v;
    }
    VR1[r0 * 122 + c] = s1; VR2[r0 * 122 + c] = s2;
    #pragma unroll
    for (int k = 1; k < 8; k++) {
      float vin  = RGs[(r0 + k + 10) * 125 + c];
      float vout = RGs[(r0 + k - 1) * 125 + c];
      s1 += vin - vout;
      s2 += vin * vin - vout * vout;
      VR1[(r0 + k) * 122 + c] = s1; VR2[(r0 + k) * 122 + c] = s2;
    }
  }
  __syncthreads();

  {
    int r = tid >> 4, seg = tid & 15;
    int c0 = seg * 7;
    float s1 = 0.f, s2 = 0.f;
    #pragma unroll
    for (int m = 0; m < 11; m++) { s1 += VR1[r * 122 + c0 + m]; s2 += VR2[r * 122 + c0 + m]; }
    RV1[r * 112 + c0] = s1; RV2[r * 112 + c0] = s2;
    #pragma unroll
    for (int j = 1; j < 7; j++) {
      s1 += VR1[r * 122 + c0 + j + 10] - VR1[r * 122 + c0 + j - 1];
      s2 += VR2[r * 122 + c0 + j + 10] - VR2[r * 122 + c0 + j - 1];
      RV1[r * 112 + c0 + j] = s1; RV2[r * 112 + c0 + j] = s2;
    }
  }
  __syncthreads();

  float* CH0 = POOL;          // 26 x 68 (64 used)
  float* CH1 = POOL + 1768;
  const int dstart = grp ? 1 : -24;
  const int gx = x0 + vx;
  const bool headLane = grp && (gx < 5);
  const bool tailLane = (!grp) && (gx > 474);
  float bnum[4], bden[4], bdd[4];
  #pragma unroll
  for (int k = 0; k < 4; k++) { bnum[k] = -1.f; bden[k] = 1.f; bdd[k] = 0.f; }

  for (int it = 0; it < 12; ++it) {
    const int d0 = dstart + 2 * it;
    if (hr < 26) {
      const int c0 = 8 * hg + d0 + 24;
      float rgv[19];
      #pragma unroll
      for (int j = 0; j < 19; j++) rgv[j] = RGs[hr * 125 + c0 + j];
      float ca[8], cb[8];
      float sa = 0.f, sb = 0.f;
      #pragma unroll
      for (int k = 0; k < 11; k++) { sa += lgc[k] * rgv[k]; sb += lgc[k] * rgv[k + 1]; }
      ca[0] = sa; cb[0] = sb;
      #pragma unroll
      for (int j = 1; j < 8; j++) {
        sa += lgc[j + 10] * rgv[j + 10] - lgc[j - 1] * rgv[j - 1];
        sb += lgc[j + 10] * rgv[j + 11] - lgc[j - 1] * rgv[j];
        ca[j] = sa; cb[j] = sb;
      }
      *(float4*)&CH0[hr * 68 + 8 * hg]     = make_float4(ca[0], ca[1], ca[2], ca[3]);
      *(float4*)&CH0[hr * 68 + 8 * hg + 4] = make_float4(ca[4], ca[5], ca[6], ca[7]);
      *(float4*)&CH1[hr * 68 + 8 * hg]     = make_float4(cb[0], cb[1], cb[2], cb[3]);
      *(float4*)&CH1[hr * 68 + 8 * hg + 4] = make_float4(cb[4], cb[5], cb[6], cb[7]);
    }
    __syncthreads();
    {
      float a0 = 0.f, a1 = 0.f;
      #pragma unroll
      for (int dy = 0; dy < 11; dy++) { a0 += CH0[(vys + dy) * 68 + vx]; a1 += CH1[(vys + dy) * 68 + vx]; }
      #pragma unroll
      for (int k = 0; k < 4; k++) {
        if (k) {
          a0 += CH0[(vys + k + 10) * 68 + vx] - CH0[(vys + k - 1) * 68 + vx];
          a1 += CH1[(vys + k + 10) * 68 + vx] - CH1[(vys + k - 1) * 68 + vx];
        }
        #pragma unroll
        for (int h = 0; h < 2; h++) {
          int d = d0 + h;
          float cs = h ? a1 : a0;
          float rs = RV1[(vys + k) * 112 + vx + d + 24];
          float r2 = RV2[(vys + k) * 112 + vx + d + 24];
          if (headLane) {
            int a = max(gx - 5 + d, 0);
            int bI = d;
            rs -= P1[(vys + k) * 25 + bI] - P1[(vys + k) * 25 + a];
            r2 -= P2[(vys + k) * 25 + bI] - P2[(vys + k) * 25 + a];
          }
          if (tailLane) {
            int a = 24 + d;
            int bI = min(gx + 5 + d, 479) - 455;
            rs -= P1[(vys + k) * 25 + bI] - P1[(vys + k) * 25 + a];
            r2 -= P2[(vys + k) * 25 + bI] - P2[(vys + k) * 25 + a];
          }
          float rmv = rs * (1.f / 121.f);
          float r2v = r2 * (1.f / 121.f);
          float rstd = sqrtf(fmaxf(r2v - rmv * rmv, 1e-8f));
          float num = cs * (1.f / 121.f) - lmv[k] * rmv;
          float den = lsv[k] * rstd + 1e-8f;
          if (num * bden[k] > bnum[k] * den) { bnum[k] = num; bden[k] = den; bdd[k] = (float)d; }
        }
      }
    }
    __syncthreads();
  }

  if (gx < W2) {
    float* bcp = grp ? bc1 : bc0;
    float* bdp = grp ? bd1 : bd0;
    #pragma unroll
    for (int k = 0; k < 4; k++) {
      size_t o = (size_t)b * (H2 * W2) + (size_t)(y0 + vys + k) * W2 + gx;
      bcp[o] = bnum[k] / bden[k];
      bdp[o] = bdd[k];
    }
  }
}

// ------- sign/magnitude: one thread per half-res pixel, 4 preds each -------
__global__ __launch_bounds__(256) void k_sgm(const float* __restrict__ pred,
                                             const float* __restrict__ bc0,
                                             const float* __restrict__ bd0,
                                             const float* __restrict__ bc1,
                                             const float* __restrict__ bd1,
                                             float* __restrict__ partialsB) {
  int tid = blockIdx.x * 256 + threadIdx.x;
  float v6 = 0.f, v7 = 0.f, v8 = 0.f;
  if (tid < NH) {
    int b = tid / (H2 * W2);
    int rem = tid % (H2 * W2);
    int y2 = rem / W2, x2 = rem % W2;
    float c0v = bc0[tid], c1v = bc1[tid];
    float bcv, bdvv;
    if (c1v > c0v) { bcv = c1v; bdvv = bd1[tid]; }
    else           { bcv = c0v; bdvv = bd0[tid]; }
    if (bcv > 0.3f) {
      float nd = bdvv * 2.f;
      float sgn = (nd > 0.f) ? 1.f : ((nd < 0.f) ? -1.f : 0.f);
      const float* pb = pred + (size_t)b * H * W;
      #pragma unroll
      for (int dy = 0; dy < 2; dy++) {
        #pragma unroll
        for (int dx = 0; dx < 2; dx++) {
          float p = pb[(size_t)(2 * y2 + dy) * W + 2 * x2 + dx];
          v6 += fmaxf(-p * sgn, 0.f);
          v7 += bcv * fabsf(p - nd);
        }
      }
      v8 = 4.f;
    }
  }
  __shared__ float sm[4][3];
  int wave = threadIdx.x >> 6, lane = threadIdx.x & 63;
  float r;
  r = waveSum(v6); if (lane == 0) sm[wave][0] = r;
  r = waveSum(v7); if (lane == 0) sm[wave][1] = r;
  r = waveSum(v8); if (lane == 0) sm[wave][2] = r;
  __syncthreads();
  if (threadIdx.x < 3) {
    float t = sm[0][threadIdx.x] + sm[1][threadIdx.x] +
              sm[2][threadIdx.x] + sm[3][threadIdx.x];
    partialsB[(size_t)threadIdx.x * NBLK2 + blockIdx.x] = t;
  }
}

// ---------------- final reduction + scalar composition ----------------
// slots: 0 gt_num 1 gt_den 2 ph_num 3 ph_den 4 s_dx 5 s_dy (A, NBLK)
//        6 s_sign 7 s_mag 8 s_act (B, NBLK2)
__global__ __launch_bounds__(256) void k_final(const float* __restrict__ PA,
                                               const float* __restrict__ PB,
                                               float* __restrict__ out) {
  __shared__ float red[9][4];
  int lane = threadIdx.x & 63, wave = threadIdx.x >> 6;
  #pragma unroll
  for (int s = 0; s < 6; s++) {
    float l = 0.f;
    for (int i = threadIdx.x; i < NBLK; i += 256) l += PA[(size_t)s * NBLK + i];
    l = waveSum(l);
    if (lane == 0) red[s][wave] = l;
  }
  #pragma unroll
  for (int s = 0; s < 3; s++) {
    float l = 0.f;
    for (int i = threadIdx.x; i < NBLK2; i += 256) l += PB[(size_t)s * NBLK2 + i];
    l = waveSum(l);
    if (lane == 0) red[6 + s][wave] = l;
  }
  __syncthreads();
  if (threadIdx.x == 0) {
    float a[9];
    #pragma unroll
    for (int s = 0; s < 9; s++) a[s] = red[s][0] + red[s][1] + red[s][2] + red[s][3];
    float gtl = a[0] / fmaxf(a[1], 1.f);
    float ph  = a[2] / fmaxf(a[3], 1.f);
    float n   = fmaxf(a[8], 1.f);
    float smv = 0.3f * (a[6] / n) + 0.7f * (a[7] / n);
    float smo = a[4] * (1.f / ((float)B * H * (W - 1)))
              + a[5] * (1.f / ((float)B * (H - 1) * W));
    out[0] = gtl + ph + 0.5f * smv + 0.1f * smo;
  }
}

extern "C" void kernel_launch(void* const* d_in, const int* in_sizes, int n_in,
                              void* d_out, int out_size, void* d_ws, size_t ws_size,
                              hipStream_t stream) {
  const float* pred  = (const float*)d_in[0];
  const float* gt    = (const float*)d_in[1];
  const float* conf  = (const float*)d_in[2];
  const float* occ   = (const float*)d_in[3];
  const float* left  = (const float*)d_in[4];
  const float* right = (const float*)d_in[5];
  float* out = (float*)d_out;

  float* ws = (float*)d_ws;
  float* lg  = ws;
  float* rg  = ws + (size_t)NH;
  float* bc0 = ws + 2 * (size_t)NH;
  float* bd0 = ws + 3 * (size_t)NH;
  float* bc1 = ws + 4 * (size_t)NH;
  float* bd1 = ws + 5 * (size_t)NH;
  float* partialsA = ws + 6 * (size_t)NH;            // 6 * NBLK floats
  float* partialsB = partialsA + 6 * (size_t)NBLK;   // 3 * NBLK2 floats

  k_pix<<<NBLK, 256, 0, stream>>>(pred, gt, conf, occ, left, right,
                                  lg, rg, partialsA);

  dim3 nccGrid(8, 17, 8);   // x-tiles, y-tiles, batch*2 d-groups
  k_ncc<<<nccGrid, 256, 0, stream>>>(lg, rg, bc0, bd0, bc1, bd1);

  k_sgm<<<NBLK2, 256, 0, stream>>>(pred, bc0, bd0, bc1, bd1, partialsB);

  k_final<<<1, 256, 0, stream>>>(partialsA, partialsB, out);
}

// Round 6
// 285.404 us; speedup vs baseline: 14.3055x; 1.0130x over previous
//
#include <hip/hip_runtime.h>
#include <hip/hip_bf16.h>

// Problem constants (match reference setup_inputs / hyperparams)
constexpr int B  = 4;
constexpr int H  = 544;
constexpr int W  = 960;
constexpr int H2 = 272;   // half-res
constexpr int W2 = 480;
constexpr int NH = B * H2 * W2;     // 522240
constexpr int NF = B * H * W;       // 2088960

// pixel kernel tiling: 32x8 outputs per block, halo 1 -> 34x10 staged
constexpr int TPW = 32, TPH = 8;
constexpr int SW = TPW + 2, SH = TPH + 2;      // 34 x 10
constexpr int NSTAGE = SW * SH;                // 340
constexpr int GX = W / TPW;                    // 30
constexpr int GY = H / TPH;                    // 68
constexpr int NBLK  = GX * GY * B;             // 8160 (k_pix blocks)
constexpr int NBLK2 = (NH + 255) / 256;        // 2040 (k_sgm blocks)

__device__ inline float waveSum(float v) {
  #pragma unroll
  for (int off = 32; off > 0; off >>= 1) v += __shfl_down(v, off, 64);
  return v;
}

// ------- fused pixel kernel: gt + photometric + smoothness + lg/rg downsample -------
__global__ __launch_bounds__(256) void k_pix(const float* __restrict__ pred,
                                             const float* __restrict__ gt,
                                             const float* __restrict__ conf,
                                             const float* __restrict__ occ,
                                             const float* __restrict__ left,
                                             const float* __restrict__ right,
                                             float* __restrict__ lg,
                                             float* __restrict__ rg,
                                             float* __restrict__ partialsA) {
  const int bx = blockIdx.x % GX;
  const int by = (blockIdx.x / GX) % GY;
  const int b  = blockIdx.x / (GX * GY);
  const int x0 = bx * TPW, y0 = by * TPH;
  const int tid = threadIdx.x;

  const float* dispb = pred + (size_t)b * H * W;
  const float* lb = left  + (size_t)b * 3 * H * W;
  const float* rb = right + (size_t)b * 3 * H * W;

  __shared__ float4 L4s[NSTAGE];   // (lv0, lv1, lv2, disp); zeros if OOB
  __shared__ float4 W4s[NSTAGE];   // (wv0, wv1, wv2, 0);    zeros if OOB

  for (int e = tid; e < NSTAGE; e += 256) {
    int r = e / SW, c = e % SW;
    int yy = y0 - 1 + r, xx = x0 - 1 + c;
    float4 l4 = make_float4(0.f, 0.f, 0.f, 0.f);
    float4 w4 = make_float4(0.f, 0.f, 0.f, 0.f);
    if (yy >= 0 && yy < H && xx >= 0 && xx < W) {
      float dv = dispb[yy * W + xx];
      float xsv = (float)xx - dv;
      float xc = fminf(fmaxf(xsv, 0.f), (float)(W - 1));
      float x0f = floorf(xc);
      float w = xc - x0f;
      int x0i = (int)x0f;
      int x1i = min(x0i + 1, W - 1);
      const float* l0 = lb + (size_t)yy * W;
      const float* r0 = rb + (size_t)yy * W;
      l4.x = l0[xx];
      l4.y = l0[(size_t)H * W + xx];
      l4.z = l0[2 * (size_t)H * W + xx];
      l4.w = dv;
      w4.x = r0[x0i] * (1.f - w) + r0[x1i] * w;
      w4.y = r0[(size_t)H * W + x0i] * (1.f - w) + r0[(size_t)H * W + x1i] * w;
      w4.z = r0[2 * (size_t)H * W + x0i] * (1.f - w) + r0[2 * (size_t)H * W + x1i] * w;
    }
    L4s[e] = l4; W4s[e] = w4;
  }
  __syncthreads();

  // ---- lg/rg emission (threads 0..63): 16x4 half-res pixels of this tile ----
  if (tid < 64) {
    int hx = tid & 15, hy = tid >> 4;
    int y2g = (y0 >> 1) + hy, x2g = (x0 >> 1) + hx;
    int i00 = (2 * hy + 1) * SW + (2 * hx + 1);
    float4 a00 = L4s[i00], a01 = L4s[i00 + 1], a10 = L4s[i00 + SW], a11 = L4s[i00 + SW + 1];
    float sl = 0.f;
    sl += a00.x + a01.x + a10.x + a11.x;
    sl += a00.y + a01.y + a10.y + a11.y;
    sl += a00.z + a01.z + a10.z + a11.z;
    float sr = 0.f;
    int yy2 = y0 + 2 * hy, xx2 = x0 + 2 * hx;
    #pragma unroll
    for (int c = 0; c < 3; c++) {
      const float* rp = rb + (size_t)(c * H + yy2) * W + xx2;
      sr += rp[0] + rp[1] + rp[W] + rp[W + 1];
    }
    size_t ho = (size_t)b * (H2 * W2) + (size_t)y2g * W2 + x2g;
    lg[ho] = sl * (1.f / 12.f);
    rg[ho] = sr * (1.f / 12.f);
  }

  float v[6];
  #pragma unroll
  for (int s = 0; s < 6; s++) v[s] = 0.f;

  {
    const int tx = tid & 31, ty = tid >> 5;
    const int x = x0 + tx, y = y0 + ty;
    const size_t gidx = (size_t)b * H * W + (size_t)y * W + x;
    const int ci = (ty + 1) * SW + (tx + 1);

    float sl[3] = {0,0,0}, sw[3] = {0,0,0}, sl2[3] = {0,0,0},
          sw2[3] = {0,0,0}, slw[3] = {0,0,0};
    float4 cl4, cw4, rl4, dl4;
    #pragma unroll
    for (int dy = -1; dy <= 1; dy++) {
      #pragma unroll
      for (int dx = -1; dx <= 1; dx++) {
        int ni = ci + dy * SW + dx;
        float4 a = L4s[ni];
        float4 wv = W4s[ni];
        sl[0] += a.x;  sl2[0] += a.x * a.x;  sw[0] += wv.x;  sw2[0] += wv.x * wv.x;  slw[0] += a.x * wv.x;
        sl[1] += a.y;  sl2[1] += a.y * a.y;  sw[1] += wv.y;  sw2[1] += wv.y * wv.y;  slw[1] += a.y * wv.y;
        sl[2] += a.z;  sl2[2] += a.z * a.z;  sw[2] += wv.z;  sw2[2] += wv.z * wv.z;  slw[2] += a.z * wv.z;
        if (dy == 0 && dx == 0) { cl4 = a; cw4 = wv; }
        if (dy == 0 && dx == 1) rl4 = a;
        if (dy == 1 && dx == 0) dl4 = a;
      }
    }
    float ds = cl4.w;

    // ---- gt anchor ----
    {
      float g = gt[gidx];
      float trust = (g > 2.0f) ? conf[gidx] * occ[gidx] : 0.f;
      v[0] = trust * fabsf(ds - g);
      v[1] = trust;
    }

    // ---- photometric ----
    {
      float xs = (float)x - ds;
      bool valid = (xs > 0.f) && (xs < (float)(W - 1));
      float cl[3] = {cl4.x, cl4.y, cl4.z};
      float cw[3] = {cw4.x, cw4.y, cw4.z};
      float ssm = 0.f, l1m = 0.f;
      #pragma unroll
      for (int c = 0; c < 3; c++) {
        float mx = sl[c] * (1.f / 9.f), my = sw[c] * (1.f / 9.f);
        float sx = fmaxf(sl2[c] * (1.f / 9.f) - mx * mx, 0.f);
        float sy = fmaxf(sw2[c] * (1.f / 9.f) - my * my, 0.f);
        float sxy = slw[c] * (1.f / 9.f) - mx * my;
        float n  = (2.f * mx * my + 1e-4f) * (2.f * sxy + 9e-4f);
        float dd = (mx * mx + my * my + 1e-4f) * (sx + sy + 9e-4f);
        float ss = (1.f - n / dd) * 0.5f;
        ss = fminf(fmaxf(ss, 0.f), 1.f);
        ssm += ss;
        l1m += fabsf(cl[c] - cw[c]);
      }
      ssm *= (1.f / 3.f); l1m *= (1.f / 3.f);
      float err = 0.85f * ssm + 0.15f * l1m;
      if (valid) { v[2] = err; v[3] = 1.f; }
    }

    // ---- smoothness ----
    if (x < W - 1) {
      float ddx = fabsf(rl4.w - ds);
      float idx = fabsf(rl4.x - cl4.x) + fabsf(rl4.y - cl4.y) + fabsf(rl4.z - cl4.z);
      v[4] = ddx * __expf(-idx * (1.f / 3.f));
    }
    if (y < H - 1) {
      float ddy = fabsf(dl4.w - ds);
      float idy = fabsf(dl4.x - cl4.x) + fabsf(dl4.y - cl4.y) + fabsf(dl4.z - cl4.z);
      v[5] = ddy * __expf(-idy * (1.f / 3.f));
    }
  }

  __shared__ float sm[4][6];
  int wave = threadIdx.x >> 6, lane = threadIdx.x & 63;
  #pragma unroll
  for (int s = 0; s < 6; s++) {
    float r = waveSum(v[s]);
    if (lane == 0) sm[wave][s] = r;
  }
  __syncthreads();
  if (threadIdx.x < 6) {
    float t = sm[0][threadIdx.x] + sm[1][threadIdx.x] +
              sm[2][threadIdx.x] + sm[3][threadIdx.x];
    partialsA[(size_t)threadIdx.x * NBLK + blockIdx.x] = t;
  }
}

// ---------------- fused NCC disparity search, 4 d-groups ----------------
// grp g covers 12 d's: g0 [-24..-13], g1 [-12..-1], g2 [1..12], g3 [13..24].
// LDS 8770 floats = 35080 B -> 4 blocks/CU:
//   region A @0: LGs 26x74 (1924, dead after LH pass) overlaid by RV1/RV2 (2x16x76)
//   RGs @2432: 26x85 | POOL @4642: 3328 (LH pair / VR pair / CH pair, stride 64)
//   P1 @7970, P2 @8370: 16x25 border prefix sums
__global__ __launch_bounds__(256) void k_ncc(const float* __restrict__ lg,
                                             const float* __restrict__ rg,
                                             float* __restrict__ bcA,
                                             float* __restrict__ bdA) {
  const int z = blockIdx.z;
  const int b = z >> 2, grp = z & 3;
  const int dmin = (grp == 0) ? -24 : ((grp == 1) ? -12 : ((grp == 2) ? 1 : 13));
  const int x0 = blockIdx.x * 64;
  const int y0 = blockIdx.y * 16;
  const int tid = threadIdx.x;

  __shared__ __align__(16) float SM[8770];
  float* LGs = SM;             // 26 x 74
  float* RV1 = SM;             // 16 x 76 (overlays LGs after it's dead)
  float* RV2 = SM + 1216;
  float* RGs = SM + 2432;      // 26 x 85
  float* POOL = SM + 4642;     // 3328
  float* P1 = SM + 7970;       // 16 x 25
  float* P2 = SM + 8370;

  const float* lgb = lg + (size_t)b * (H2 * W2);
  const float* rgb = rg + (size_t)b * (H2 * W2);

  for (int e = tid; e < 26 * 74; e += 256) {
    int r = e / 74, c = e % 74;
    int gy = y0 - 5 + r, gxx = x0 - 5 + c;
    LGs[e] = (gy >= 0 && gy < H2 && gxx >= 0 && gxx < W2) ? lgb[gy * W2 + gxx] : 0.f;
  }
  const int col0RG = x0 - 5 + dmin;
  for (int e = tid; e < 26 * 85; e += 256) {
    int r = e / 85, c = e % 85;
    int gy = y0 - 5 + r, gxx = col0RG + c;
    RGs[e] = (gy >= 0 && gy < H2 && gxx >= 0 && gxx < W2) ? rgb[gy * W2 + gxx] : 0.f;
  }
  __syncthreads();

  // ---- LH pass (horizontal 11-sums of lg, lg^2) + lgc register cache ----
  const int hg = tid & 7, hr = tid >> 3;
  float lgc[18];
  float* LH1 = POOL;           // 26 x 64
  float* LH2 = POOL + 1664;
  if (hr < 26) {
    #pragma unroll
    for (int k = 0; k < 18; k++) lgc[k] = LGs[hr * 74 + 8 * hg + k];
    float w1[8], w2[8];
    float s1 = 0.f, s2 = 0.f;
    #pragma unroll
    for (int k = 0; k < 11; k++) { s1 += lgc[k]; s2 += lgc[k] * lgc[k]; }
    w1[0] = s1; w2[0] = s2;
    #pragma unroll
    for (int j = 1; j < 8; j++) {
      s1 += lgc[j + 10] - lgc[j - 1];
      s2 += lgc[j + 10] * lgc[j + 10] - lgc[j - 1] * lgc[j - 1];
      w1[j] = s1; w2[j] = s2;
    }
    *(float4*)&LH1[hr * 64 + 8 * hg]     = make_float4(w1[0], w1[1], w1[2], w1[3]);
    *(float4*)&LH1[hr * 64 + 8 * hg + 4] = make_float4(w1[4], w1[5], w1[6], w1[7]);
    *(float4*)&LH2[hr * 64 + 8 * hg]     = make_float4(w2[0], w2[1], w2[2], w2[3]);
    *(float4*)&LH2[hr * 64 + 8 * hg + 4] = make_float4(w2[4], w2[5], w2[6], w2[7]);
  }
  // ---- border column sums (head: global cols 0..23; tail: 456..479) ----
  const bool headT = (grp >= 2) && (x0 == 0);
  const bool tailT = (grp < 2) && (x0 == 448);
  if (headT || tailT) {
    int gcol0 = headT ? 0 : 456;
    for (int e = tid; e < 16 * 24; e += 256) {
      int y = e / 24, i = e % 24;
      int lc = gcol0 + i - col0RG;
      float v1 = 0.f, v2 = 0.f;
      if (lc >= 0 && lc < 85) {
        #pragma unroll
        for (int dy = 0; dy < 11; dy++) {
          float v = RGs[(y + dy) * 85 + lc];
          v1 += v; v2 += v * v;
        }
      }
      P1[y * 25 + i + 1] = v1;
      P2[y * 25 + i + 1] = v2;
    }
  }
  __syncthreads();

  if ((headT || tailT) && tid < 16) {
    int y = tid;
    float s1 = 0.f, s2 = 0.f;
    P1[y * 25] = 0.f; P2[y * 25] = 0.f;
    for (int k = 0; k < 24; k++) {
      s1 += P1[y * 25 + k + 1]; P1[y * 25 + k + 1] = s1;
      s2 += P2[y * 25 + k + 1]; P2[y * 25 + k + 1] = s2;
    }
  }
  const int vx = tid & 63;
  const int vys = (tid >> 6) * 4;
  float lmv[4], lsv[4];
  {
    float s1 = 0.f, s2 = 0.f;
    #pragma unroll
    for (int dy = 0; dy < 11; dy++) { s1 += LH1[(vys + dy) * 64 + vx]; s2 += LH2[(vys + dy) * 64 + vx]; }
    #pragma unroll
    for (int k = 0; k < 4; k++) {
      if (k) {
        s1 += LH1[(vys + k + 10) * 64 + vx] - LH1[(vys + k - 1) * 64 + vx];
        s2 += LH2[(vys + k + 10) * 64 + vx] - LH2[(vys + k - 1) * 64 + vx];
      }
      float m = s1 * (1.f / 121.f);
      lmv[k] = m;
      lsv[k] = sqrtf(fmaxf(s2 * (1.f / 121.f) - m * m, 1e-8f));
    }
  }
  __syncthreads();

  // ---- VR pass: vertical 11-sums of rg, rg^2 (POOL, overwrites LH) ----
  float* VR1 = POOL;           // 16 x 85
  float* VR2 = POOL + 1360;
  if (tid < 170) {
    int c = tid % 85;
    int r0 = (tid / 85) * 8;
    float s1 = 0.f, s2 = 0.f;
    #pragma unroll
    for (int dy = 0; dy < 11; dy++) {
      float v = RGs[(r0 + dy) * 85 + c];
      s1 += v; s2 += v * v;
    }
    VR1[r0 * 85 + c] = s1; VR2[r0 * 85 + c] = s2;
    #pragma unroll
    for (int k = 1; k < 8; k++) {
      float vin  = RGs[(r0 + k + 10) * 85 + c];
      float vout = RGs[(r0 + k - 1) * 85 + c];
      s1 += vin - vout;
      s2 += vin * vin - vout * vout;
      VR1[(r0 + k) * 85 + c] = s1; VR2[(r0 + k) * 85 + c] = s2;
    }
  }
  __syncthreads();

  // ---- RV pass: horizontal 11-sums of VR -> raw 121-sums, width 75 ----
  // (writes overlay the dead LGs region)
  {
    int r = tid >> 4, seg = tid & 15;
    int c0 = seg * 5;
    if (c0 < 75) {
      float s1 = 0.f, s2 = 0.f;
      #pragma unroll
      for (int m = 0; m < 11; m++) { s1 += VR1[r * 85 + c0 + m]; s2 += VR2[r * 85 + c0 + m]; }
      RV1[r * 76 + c0] = s1; RV2[r * 76 + c0] = s2;
      #pragma unroll
      for (int j = 1; j < 5; j++) {
        s1 += VR1[r * 85 + c0 + j + 10] - VR1[r * 85 + c0 + j - 1];
        s2 += VR2[r * 85 + c0 + j + 10] - VR2[r * 85 + c0 + j - 1];
        RV1[r * 76 + c0 + j] = s1; RV2[r * 76 + c0 + j] = s2;
      }
    }
  }
  __syncthreads();

  // ---- d loop: 6 pairs (d, d+1) within this group's 12 d's ----
  float* CH0 = POOL;           // 26 x 64
  float* CH1 = POOL + 1664;
  const int gx = x0 + vx;
  const bool headL = (grp >= 2) && (gx < 5);
  const bool tailL = (grp < 2) && (gx > 474);
  float bnum[4], bden[4], bdd[4];
  #pragma unroll
  for (int k = 0; k < 4; k++) { bnum[k] = -1.f; bden[k] = 1.f; bdd[k] = 0.f; }

  for (int it = 0; it < 6; ++it) {
    const int d0 = dmin + 2 * it;
    if (hr < 26) {
      const int c0 = 8 * hg + 2 * it;
      float rgv[19];
      #pragma unroll
      for (int j = 0; j < 19; j++) rgv[j] = RGs[hr * 85 + c0 + j];
      float ca[8], cb[8];
      float sa = 0.f, sb = 0.f;
      #pragma unroll
      for (int k = 0; k < 11; k++) { sa += lgc[k] * rgv[k]; sb += lgc[k] * rgv[k + 1]; }
      ca[0] = sa; cb[0] = sb;
      #pragma unroll
      for (int j = 1; j < 8; j++) {
        sa += lgc[j + 10] * rgv[j + 10] - lgc[j - 1] * rgv[j - 1];
        sb += lgc[j + 10] * rgv[j + 11] - lgc[j - 1] * rgv[j];
        ca[j] = sa; cb[j] = sb;
      }
      *(float4*)&CH0[hr * 64 + 8 * hg]     = make_float4(ca[0], ca[1], ca[2], ca[3]);
      *(float4*)&CH0[hr * 64 + 8 * hg + 4] = make_float4(ca[4], ca[5], ca[6], ca[7]);
      *(float4*)&CH1[hr * 64 + 8 * hg]     = make_float4(cb[0], cb[1], cb[2], cb[3]);
      *(float4*)&CH1[hr * 64 + 8 * hg + 4] = make_float4(cb[4], cb[5], cb[6], cb[7]);
    }
    __syncthreads();
    {
      float a0 = 0.f, a1 = 0.f;
      #pragma unroll
      for (int dy = 0; dy < 11; dy++) { a0 += CH0[(vys + dy) * 64 + vx]; a1 += CH1[(vys + dy) * 64 + vx]; }
      #pragma unroll
      for (int k = 0; k < 4; k++) {
        if (k) {
          a0 += CH0[(vys + k + 10) * 64 + vx] - CH0[(vys + k - 1) * 64 + vx];
          a1 += CH1[(vys + k + 10) * 64 + vx] - CH1[(vys + k - 1) * 64 + vx];
        }
        #pragma unroll
        for (int h = 0; h < 2; h++) {
          int d = d0 + h;
          float cs = h ? a1 : a0;
          int rvi = vx + 2 * it + h;
          float rs = RV1[(vys + k) * 76 + rvi];
          float r2 = RV2[(vys + k) * 76 + rvi];
          if (headL) {             // d>0: drop taps t<0 -> rg cols [gx-5+d, d-1]
            int a = max(gx - 5 + d, 0);
            int bI = d;
            rs -= P1[(vys + k) * 25 + bI] - P1[(vys + k) * 25 + a];
            r2 -= P2[(vys + k) * 25 + bI] - P2[(vys + k) * 25 + a];
          }
          if (tailL) {             // d<0: drop taps t>=W2 -> rg cols [480+d, gx+5+d]
            int a = 24 + d;
            int bI = min(gx + 5 + d, 479) - 455;
            rs -= P1[(vys + k) * 25 + bI] - P1[(vys + k) * 25 + a];
            r2 -= P2[(vys + k) * 25 + bI] - P2[(vys + k) * 25 + a];
          }
          float rmv = rs * (1.f / 121.f);
          float r2v = r2 * (1.f / 121.f);
          float rstd = sqrtf(fmaxf(r2v - rmv * rmv, 1e-8f));
          float num = cs * (1.f / 121.f) - lmv[k] * rmv;
          float den = lsv[k] * rstd + 1e-8f;
          if (num * bden[k] > bnum[k] * den) { bnum[k] = num; bden[k] = den; bdd[k] = (float)d; }
        }
      }
    }
    __syncthreads();
  }

  if (gx < W2) {
    float* bcp = bcA + (size_t)grp * NH + (size_t)b * (H2 * W2);
    float* bdp = bdA + (size_t)grp * NH + (size_t)b * (H2 * W2);
    #pragma unroll
    for (int k = 0; k < 4; k++) {
      size_t o = (size_t)(y0 + vys + k) * W2 + gx;
      bcp[o] = bnum[k] / bden[k];
      bdp[o] = bdd[k];
    }
  }
}

// ------- sign/magnitude: merge 4 d-groups (ascending, strict >), 4 preds each -------
__global__ __launch_bounds__(256) void k_sgm(const float* __restrict__ pred,
                                             const float* __restrict__ bcA,
                                             const float* __restrict__ bdA,
                                             float* __restrict__ partialsB) {
  int tid = blockIdx.x * 256 + threadIdx.x;
  float v6 = 0.f, v7 = 0.f, v8 = 0.f;
  if (tid < NH) {
    int b = tid / (H2 * W2);
    int rem = tid % (H2 * W2);
    int y2 = rem / W2, x2 = rem % W2;
    float bcv = bcA[tid];
    float bdv = bdA[tid];
    #pragma unroll
    for (int g = 1; g < 4; g++) {
      float c = bcA[(size_t)g * NH + tid];
      if (c > bcv) { bcv = c; bdv = bdA[(size_t)g * NH + tid]; }
    }
    if (bcv > 0.3f) {
      float nd = bdv * 2.f;
      float sgn = (nd > 0.f) ? 1.f : ((nd < 0.f) ? -1.f : 0.f);
      const float* pb = pred + (size_t)b * H * W;
      #pragma unroll
      for (int dy = 0; dy < 2; dy++) {
        #pragma unroll
        for (int dx = 0; dx < 2; dx++) {
          float p = pb[(size_t)(2 * y2 + dy) * W + 2 * x2 + dx];
          v6 += fmaxf(-p * sgn, 0.f);
          v7 += bcv * fabsf(p - nd);
        }
      }
      v8 = 4.f;
    }
  }
  __shared__ float sm[4][3];
  int wave = threadIdx.x >> 6, lane = threadIdx.x & 63;
  float r;
  r = waveSum(v6); if (lane == 0) sm[wave][0] = r;
  r = waveSum(v7); if (lane == 0) sm[wave][1] = r;
  r = waveSum(v8); if (lane == 0) sm[wave][2] = r;
  __syncthreads();
  if (threadIdx.x < 3) {
    float t = sm[0][threadIdx.x] + sm[1][threadIdx.x] +
              sm[2][threadIdx.x] + sm[3][threadIdx.x];
    partialsB[(size_t)threadIdx.x * NBLK2 + blockIdx.x] = t;
  }
}

// ---------------- final reduction + scalar composition ----------------
__global__ __launch_bounds__(256) void k_final(const float* __restrict__ PA,
                                               const float* __restrict__ PB,
                                               float* __restrict__ out) {
  __shared__ float red[9][4];
  int lane = threadIdx.x & 63, wave = threadIdx.x >> 6;
  #pragma unroll
  for (int s = 0; s < 6; s++) {
    float l = 0.f;
    for (int i = threadIdx.x; i < NBLK; i += 256) l += PA[(size_t)s * NBLK + i];
    l = waveSum(l);
    if (lane == 0) red[s][wave] = l;
  }
  #pragma unroll
  for (int s = 0; s < 3; s++) {
    float l = 0.f;
    for (int i = threadIdx.x; i < NBLK2; i += 256) l += PB[(size_t)s * NBLK2 + i];
    l = waveSum(l);
    if (lane == 0) red[6 + s][wave] = l;
  }
  __syncthreads();
  if (threadIdx.x == 0) {
    float a[9];
    #pragma unroll
    for (int s = 0; s < 9; s++) a[s] = red[s][0] + red[s][1] + red[s][2] + red[s][3];
    float gtl = a[0] / fmaxf(a[1], 1.f);
    float ph  = a[2] / fmaxf(a[3], 1.f);
    float n   = fmaxf(a[8], 1.f);
    float smv = 0.3f * (a[6] / n) + 0.7f * (a[7] / n);
    float smo = a[4] * (1.f / ((float)B * H * (W - 1)))
              + a[5] * (1.f / ((float)B * (H - 1) * W));
    out[0] = gtl + ph + 0.5f * smv + 0.1f * smo;
  }
}

extern "C" void kernel_launch(void* const* d_in, const int* in_sizes, int n_in,
                              void* d_out, int out_size, void* d_ws, size_t ws_size,
                              hipStream_t stream) {
  const float* pred  = (const float*)d_in[0];
  const float* gt    = (const float*)d_in[1];
  const float* conf  = (const float*)d_in[2];
  const float* occ   = (const float*)d_in[3];
  const float* left  = (const float*)d_in[4];
  const float* right = (const float*)d_in[5];
  float* out = (float*)d_out;

  float* ws = (float*)d_ws;
  float* lg  = ws;
  float* rg  = ws + (size_t)NH;
  float* bcA = ws + 2 * (size_t)NH;                  // 4 * NH
  float* bdA = ws + 6 * (size_t)NH;                  // 4 * NH
  float* partialsA = ws + 10 * (size_t)NH;           // 6 * NBLK
  float* partialsB = partialsA + 6 * (size_t)NBLK;   // 3 * NBLK2

  k_pix<<<NBLK, 256, 0, stream>>>(pred, gt, conf, occ, left, right,
                                  lg, rg, partialsA);

  dim3 nccGrid(8, 17, 16);   // x-tiles, y-tiles, batch*4 d-groups
  k_ncc<<<nccGrid, 256, 0, stream>>>(lg, rg, bcA, bdA);

  k_sgm<<<NBLK2, 256, 0, stream>>>(pred, bcA, bdA, partialsB);

  k_final<<<1, 256, 0, stream>>>(partialsA, partialsB, out);
}

// Round 7
// 282.837 us; speedup vs baseline: 14.4353x; 1.0091x over previous
//
#include <hip/hip_runtime.h>
#include <hip/hip_bf16.h>

// Problem constants (match reference setup_inputs / hyperparams)
constexpr int B  = 4;
constexpr int H  = 544;
constexpr int W  = 960;
constexpr int H2 = 272;   // half-res
constexpr int W2 = 480;
constexpr int NH = B * H2 * W2;     // 522240
constexpr int NF = B * H * W;       // 2088960

// pixel kernel tiling: 32x8 outputs per block, halo 1 -> 34x10 staged
constexpr int TPW = 32, TPH = 8;
constexpr int SW = TPW + 2, SH = TPH + 2;      // 34 x 10
constexpr int NSTAGE = SW * SH;                // 340
constexpr int GX = W / TPW;                    // 30
constexpr int GY = H / TPH;                    // 68
constexpr int NBLK  = GX * GY * B;             // 8160 (k_pix blocks)
constexpr int NBLK2 = (NH + 255) / 256;        // 2040 (k_sgm blocks)

__device__ inline float waveSum(float v) {
  #pragma unroll
  for (int off = 32; off > 0; off >>= 1) v += __shfl_down(v, off, 64);
  return v;
}

// ------- fused pixel kernel: gt + photometric + smoothness + lg/rg downsample -------
__global__ __launch_bounds__(256) void k_pix(const float* __restrict__ pred,
                                             const float* __restrict__ gt,
                                             const float* __restrict__ conf,
                                             const float* __restrict__ occ,
                                             const float* __restrict__ left,
                                             const float* __restrict__ right,
                                             float* __restrict__ lg,
                                             float* __restrict__ rg,
                                             float* __restrict__ partialsA) {
  const int bx = blockIdx.x % GX;
  const int by = (blockIdx.x / GX) % GY;
  const int b  = blockIdx.x / (GX * GY);
  const int x0 = bx * TPW, y0 = by * TPH;
  const int tid = threadIdx.x;

  const float* dispb = pred + (size_t)b * H * W;
  const float* lb = left  + (size_t)b * 3 * H * W;
  const float* rb = right + (size_t)b * 3 * H * W;

  __shared__ float4 L4s[NSTAGE];   // (lv0, lv1, lv2, disp); zeros if OOB
  __shared__ float4 W4s[NSTAGE];   // (wv0, wv1, wv2, 0);    zeros if OOB

  for (int e = tid; e < NSTAGE; e += 256) {
    int r = e / SW, c = e % SW;
    int yy = y0 - 1 + r, xx = x0 - 1 + c;
    float4 l4 = make_float4(0.f, 0.f, 0.f, 0.f);
    float4 w4 = make_float4(0.f, 0.f, 0.f, 0.f);
    if (yy >= 0 && yy < H && xx >= 0 && xx < W) {
      float dv = dispb[yy * W + xx];
      float xsv = (float)xx - dv;
      float xc = fminf(fmaxf(xsv, 0.f), (float)(W - 1));
      float x0f = floorf(xc);
      float w = xc - x0f;
      int x0i = (int)x0f;
      int x1i = min(x0i + 1, W - 1);
      const float* l0 = lb + (size_t)yy * W;
      const float* r0 = rb + (size_t)yy * W;
      l4.x = l0[xx];
      l4.y = l0[(size_t)H * W + xx];
      l4.z = l0[2 * (size_t)H * W + xx];
      l4.w = dv;
      w4.x = r0[x0i] * (1.f - w) + r0[x1i] * w;
      w4.y = r0[(size_t)H * W + x0i] * (1.f - w) + r0[(size_t)H * W + x1i] * w;
      w4.z = r0[2 * (size_t)H * W + x0i] * (1.f - w) + r0[2 * (size_t)H * W + x1i] * w;
    }
    L4s[e] = l4; W4s[e] = w4;
  }
  __syncthreads();

  // ---- lg/rg emission (threads 0..63): 16x4 half-res pixels of this tile ----
  if (tid < 64) {
    int hx = tid & 15, hy = tid >> 4;
    int y2g = (y0 >> 1) + hy, x2g = (x0 >> 1) + hx;
    int i00 = (2 * hy + 1) * SW + (2 * hx + 1);
    float4 a00 = L4s[i00], a01 = L4s[i00 + 1], a10 = L4s[i00 + SW], a11 = L4s[i00 + SW + 1];
    float sl = 0.f;
    sl += a00.x + a01.x + a10.x + a11.x;
    sl += a00.y + a01.y + a10.y + a11.y;
    sl += a00.z + a01.z + a10.z + a11.z;
    float sr = 0.f;
    int yy2 = y0 + 2 * hy, xx2 = x0 + 2 * hx;
    #pragma unroll
    for (int c = 0; c < 3; c++) {
      const float* rp = rb + (size_t)(c * H + yy2) * W + xx2;
      sr += rp[0] + rp[1] + rp[W] + rp[W + 1];
    }
    size_t ho = (size_t)b * (H2 * W2) + (size_t)y2g * W2 + x2g;
    lg[ho] = sl * (1.f / 12.f);
    rg[ho] = sr * (1.f / 12.f);
  }

  float v[6];
  #pragma unroll
  for (int s = 0; s < 6; s++) v[s] = 0.f;

  {
    const int tx = tid & 31, ty = tid >> 5;
    const int x = x0 + tx, y = y0 + ty;
    const size_t gidx = (size_t)b * H * W + (size_t)y * W + x;
    const int ci = (ty + 1) * SW + (tx + 1);

    float sl[3] = {0,0,0}, sw[3] = {0,0,0}, sl2[3] = {0,0,0},
          sw2[3] = {0,0,0}, slw[3] = {0,0,0};
    float4 cl4, cw4, rl4, dl4;
    #pragma unroll
    for (int dy = -1; dy <= 1; dy++) {
      #pragma unroll
      for (int dx = -1; dx <= 1; dx++) {
        int ni = ci + dy * SW + dx;
        float4 a = L4s[ni];
        float4 wv = W4s[ni];
        sl[0] += a.x;  sl2[0] += a.x * a.x;  sw[0] += wv.x;  sw2[0] += wv.x * wv.x;  slw[0] += a.x * wv.x;
        sl[1] += a.y;  sl2[1] += a.y * a.y;  sw[1] += wv.y;  sw2[1] += wv.y * wv.y;  slw[1] += a.y * wv.y;
        sl[2] += a.z;  sl2[2] += a.z * a.z;  sw[2] += wv.z;  sw2[2] += wv.z * wv.z;  slw[2] += a.z * wv.z;
        if (dy == 0 && dx == 0) { cl4 = a; cw4 = wv; }
        if (dy == 0 && dx == 1) rl4 = a;
        if (dy == 1 && dx == 0) dl4 = a;
      }
    }
    float ds = cl4.w;

    // ---- gt anchor ----
    {
      float g = gt[gidx];
      float trust = (g > 2.0f) ? conf[gidx] * occ[gidx] : 0.f;
      v[0] = trust * fabsf(ds - g);
      v[1] = trust;
    }

    // ---- photometric ----
    {
      float xs = (float)x - ds;
      bool valid = (xs > 0.f) && (xs < (float)(W - 1));
      float cl[3] = {cl4.x, cl4.y, cl4.z};
      float cw[3] = {cw4.x, cw4.y, cw4.z};
      float ssm = 0.f, l1m = 0.f;
      #pragma unroll
      for (int c = 0; c < 3; c++) {
        float mx = sl[c] * (1.f / 9.f), my = sw[c] * (1.f / 9.f);
        float sx = fmaxf(sl2[c] * (1.f / 9.f) - mx * mx, 0.f);
        float sy = fmaxf(sw2[c] * (1.f / 9.f) - my * my, 0.f);
        float sxy = slw[c] * (1.f / 9.f) - mx * my;
        float n  = (2.f * mx * my + 1e-4f) * (2.f * sxy + 9e-4f);
        float dd = (mx * mx + my * my + 1e-4f) * (sx + sy + 9e-4f);
        float ss = (1.f - n / dd) * 0.5f;
        ss = fminf(fmaxf(ss, 0.f), 1.f);
        ssm += ss;
        l1m += fabsf(cl[c] - cw[c]);
      }
      ssm *= (1.f / 3.f); l1m *= (1.f / 3.f);
      float err = 0.85f * ssm + 0.15f * l1m;
      if (valid) { v[2] = err; v[3] = 1.f; }
    }

    // ---- smoothness ----
    if (x < W - 1) {
      float ddx = fabsf(rl4.w - ds);
      float idx = fabsf(rl4.x - cl4.x) + fabsf(rl4.y - cl4.y) + fabsf(rl4.z - cl4.z);
      v[4] = ddx * __expf(-idx * (1.f / 3.f));
    }
    if (y < H - 1) {
      float ddy = fabsf(dl4.w - ds);
      float idy = fabsf(dl4.x - cl4.x) + fabsf(dl4.y - cl4.y) + fabsf(dl4.z - cl4.z);
      v[5] = ddy * __expf(-idy * (1.f / 3.f));
    }
  }

  __shared__ float sm[4][6];
  int wave = threadIdx.x >> 6, lane = threadIdx.x & 63;
  #pragma unroll
  for (int s = 0; s < 6; s++) {
    float r = waveSum(v[s]);
    if (lane == 0) sm[wave][s] = r;
  }
  __syncthreads();
  if (threadIdx.x < 6) {
    float t = sm[0][threadIdx.x] + sm[1][threadIdx.x] +
              sm[2][threadIdx.x] + sm[3][threadIdx.x];
    partialsA[(size_t)threadIdx.x * NBLK + blockIdx.x] = t;
  }
}

// ---------------- fused NCC disparity search, 4 d-groups ----------------
// grp g covers 12 d's: g0 [-24..-13], g1 [-12..-1], g2 [1..12], g3 [13..24].
// LDS 8770 floats = 35080 B -> 4 blocks/CU:
//   region A @0: LGs 26x74 (1924, dead after LH pass) overlaid by
//                RMS float2[16][76] (rm, rstd per (row, u)) -> 2432 floats
//   RGs @2432: 26x85 | POOL @4642: 3328 (LH pair / VR pair / CH pair)
//   P1 @7970, P2 @8370: 16x25 border prefix sums
// Inner d-loop works in the x121-scaled domain (cs raw 121-sums, lm/ls
// pre-scaled): ratio compares and final bnum/bden are scale-invariant.
__global__ __launch_bounds__(256) void k_ncc(const float* __restrict__ lg,
                                             const float* __restrict__ rg,
                                             float* __restrict__ bcA,
                                             float* __restrict__ bdA) {
  const int z = blockIdx.z;
  const int b = z >> 2, grp = z & 3;
  const int dmin = (grp == 0) ? -24 : ((grp == 1) ? -12 : ((grp == 2) ? 1 : 13));
  const int x0 = blockIdx.x * 64;
  const int y0 = blockIdx.y * 16;
  const int tid = threadIdx.x;

  __shared__ __align__(16) float SM[8770];
  float* LGs = SM;             // 26 x 74
  float* RMS = SM;             // 16 x 76 float2 (overlays dead LGs+pad)
  float* RGs = SM + 2432;      // 26 x 85
  float* POOL = SM + 4642;     // 3328
  float* P1 = SM + 7970;       // 16 x 25
  float* P2 = SM + 8370;

  const float* lgb = lg + (size_t)b * (H2 * W2);
  const float* rgb = rg + (size_t)b * (H2 * W2);

  for (int e = tid; e < 26 * 74; e += 256) {
    int r = e / 74, c = e % 74;
    int gy = y0 - 5 + r, gxx = x0 - 5 + c;
    LGs[e] = (gy >= 0 && gy < H2 && gxx >= 0 && gxx < W2) ? lgb[gy * W2 + gxx] : 0.f;
  }
  const int col0RG = x0 - 5 + dmin;
  for (int e = tid; e < 26 * 85; e += 256) {
    int r = e / 85, c = e % 85;
    int gy = y0 - 5 + r, gxx = col0RG + c;
    RGs[e] = (gy >= 0 && gy < H2 && gxx >= 0 && gxx < W2) ? rgb[gy * W2 + gxx] : 0.f;
  }
  __syncthreads();

  // ---- LH pass (horizontal 11-sums of lg, lg^2) + lgc register cache ----
  const int hg = tid & 7, hr = tid >> 3;
  float lgc[18];
  float* LH1 = POOL;           // 26 x 64
  float* LH2 = POOL + 1664;
  if (hr < 26) {
    #pragma unroll
    for (int k = 0; k < 18; k++) lgc[k] = LGs[hr * 74 + 8 * hg + k];
    float w1[8], w2[8];
    float s1 = 0.f, s2 = 0.f;
    #pragma unroll
    for (int k = 0; k < 11; k++) { s1 += lgc[k]; s2 += lgc[k] * lgc[k]; }
    w1[0] = s1; w2[0] = s2;
    #pragma unroll
    for (int j = 1; j < 8; j++) {
      s1 += lgc[j + 10] - lgc[j - 1];
      s2 += lgc[j + 10] * lgc[j + 10] - lgc[j - 1] * lgc[j - 1];
      w1[j] = s1; w2[j] = s2;
    }
    *(float4*)&LH1[hr * 64 + 8 * hg]     = make_float4(w1[0], w1[1], w1[2], w1[3]);
    *(float4*)&LH1[hr * 64 + 8 * hg + 4] = make_float4(w1[4], w1[5], w1[6], w1[7]);
    *(float4*)&LH2[hr * 64 + 8 * hg]     = make_float4(w2[0], w2[1], w2[2], w2[3]);
    *(float4*)&LH2[hr * 64 + 8 * hg + 4] = make_float4(w2[4], w2[5], w2[6], w2[7]);
  }
  // ---- border column sums (head: global cols 0..23; tail: 456..479) ----
  const bool headT = (grp >= 2) && (x0 == 0);
  const bool tailT = (grp < 2) && (x0 == 448);
  if (headT || tailT) {
    int gcol0 = headT ? 0 : 456;
    for (int e = tid; e < 16 * 24; e += 256) {
      int y = e / 24, i = e % 24;
      int lc = gcol0 + i - col0RG;
      float v1 = 0.f, v2 = 0.f;
      if (lc >= 0 && lc < 85) {
        #pragma unroll
        for (int dy = 0; dy < 11; dy++) {
          float v = RGs[(y + dy) * 85 + lc];
          v1 += v; v2 += v * v;
        }
      }
      P1[y * 25 + i + 1] = v1;
      P2[y * 25 + i + 1] = v2;
    }
  }
  __syncthreads();

  if ((headT || tailT) && tid < 16) {
    int y = tid;
    float s1 = 0.f, s2 = 0.f;
    P1[y * 25] = 0.f; P2[y * 25] = 0.f;
    for (int k = 0; k < 24; k++) {
      s1 += P1[y * 25 + k + 1]; P1[y * 25 + k + 1] = s1;
      s2 += P2[y * 25 + k + 1]; P2[y * 25 + k + 1] = s2;
    }
  }
  const int vx = tid & 63;
  const int vys = (tid >> 6) * 4;
  float lmS[4], lsS[4];   // 121-scaled left mean / std
  {
    float s1 = 0.f, s2 = 0.f;
    #pragma unroll
    for (int dy = 0; dy < 11; dy++) { s1 += LH1[(vys + dy) * 64 + vx]; s2 += LH2[(vys + dy) * 64 + vx]; }
    #pragma unroll
    for (int k = 0; k < 4; k++) {
      if (k) {
        s1 += LH1[(vys + k + 10) * 64 + vx] - LH1[(vys + k - 1) * 64 + vx];
        s2 += LH2[(vys + k + 10) * 64 + vx] - LH2[(vys + k - 1) * 64 + vx];
      }
      float m = s1 * (1.f / 121.f);
      float s = sqrtf(fmaxf(s2 * (1.f / 121.f) - m * m, 1e-8f));
      lmS[k] = m * 121.f;
      lsS[k] = s * 121.f;
    }
  }
  __syncthreads();

  // ---- VR pass: vertical 11-sums of rg, rg^2 (POOL, overwrites LH) ----
  float* VR1 = POOL;           // 16 x 85
  float* VR2 = POOL + 1360;
  if (tid < 170) {
    int c = tid % 85;
    int r0 = (tid / 85) * 8;
    float s1 = 0.f, s2 = 0.f;
    #pragma unroll
    for (int dy = 0; dy < 11; dy++) {
      float v = RGs[(r0 + dy) * 85 + c];
      s1 += v; s2 += v * v;
    }
    VR1[r0 * 85 + c] = s1; VR2[r0 * 85 + c] = s2;
    #pragma unroll
    for (int k = 1; k < 8; k++) {
      float vin  = RGs[(r0 + k + 10) * 85 + c];
      float vout = RGs[(r0 + k - 1) * 85 + c];
      s1 += vin - vout;
      s2 += vin * vin - vout * vout;
      VR1[(r0 + k) * 85 + c] = s1; VR2[(r0 + k) * 85 + c] = s2;
    }
  }
  __syncthreads();

  // ---- RV pass fused with moment transform -> RMS float2 (rm, rstd) ----
  {
    int r = tid >> 4, seg = tid & 15;
    int c0 = seg * 5;
    if (c0 < 75) {
      float s1 = 0.f, s2 = 0.f;
      #pragma unroll
      for (int m = 0; m < 11; m++) { s1 += VR1[r * 85 + c0 + m]; s2 += VR2[r * 85 + c0 + m]; }
      #pragma unroll
      for (int j = 0; j < 5; j++) {
        if (j) {
          s1 += VR1[r * 85 + c0 + j + 10] - VR1[r * 85 + c0 + j - 1];
          s2 += VR2[r * 85 + c0 + j + 10] - VR2[r * 85 + c0 + j - 1];
        }
        float rm = s1 * (1.f / 121.f);
        float rstd = sqrtf(fmaxf(s2 * (1.f / 121.f) - rm * rm, 1e-8f));
        *(float2*)&RMS[r * 152 + 2 * (c0 + j)] = make_float2(rm, rstd);
      }
    }
  }
  __syncthreads();

  // ---- d loop: 6 pairs (d, d+1) within this group's 12 d's ----
  float* CH0 = POOL;           // 26 x 64
  float* CH1 = POOL + 1664;
  const int gx = x0 + vx;
  const bool headL = (grp >= 2) && (gx < 5);
  const bool tailL = (grp < 2) && (gx > 474);
  const bool edgeL = headL || tailL;
  float bnum[4], bden[4], bdd[4];
  #pragma unroll
  for (int k = 0; k < 4; k++) { bnum[k] = -1.f; bden[k] = 1.f; bdd[k] = 0.f; }

  for (int it = 0; it < 6; ++it) {
    const int d0 = dmin + 2 * it;
    if (hr < 26) {
      const int c0 = 8 * hg + 2 * it;
      float rgv[19];
      #pragma unroll
      for (int j = 0; j < 19; j++) rgv[j] = RGs[hr * 85 + c0 + j];
      float ca[8], cb[8];
      float sa = 0.f, sb = 0.f;
      #pragma unroll
      for (int k = 0; k < 11; k++) { sa += lgc[k] * rgv[k]; sb += lgc[k] * rgv[k + 1]; }
      ca[0] = sa; cb[0] = sb;
      #pragma unroll
      for (int j = 1; j < 8; j++) {
        sa += lgc[j + 10] * rgv[j + 10] - lgc[j - 1] * rgv[j - 1];
        sb += lgc[j + 10] * rgv[j + 11] - lgc[j - 1] * rgv[j];
        ca[j] = sa; cb[j] = sb;
      }
      *(float4*)&CH0[hr * 64 + 8 * hg]     = make_float4(ca[0], ca[1], ca[2], ca[3]);
      *(float4*)&CH0[hr * 64 + 8 * hg + 4] = make_float4(ca[4], ca[5], ca[6], ca[7]);
      *(float4*)&CH1[hr * 64 + 8 * hg]     = make_float4(cb[0], cb[1], cb[2], cb[3]);
      *(float4*)&CH1[hr * 64 + 8 * hg + 4] = make_float4(cb[4], cb[5], cb[6], cb[7]);
    }
    __syncthreads();
    {
      float a0 = 0.f, a1 = 0.f;
      #pragma unroll
      for (int dy = 0; dy < 11; dy++) { a0 += CH0[(vys + dy) * 64 + vx]; a1 += CH1[(vys + dy) * 64 + vx]; }
      #pragma unroll
      for (int k = 0; k < 4; k++) {
        if (k) {
          a0 += CH0[(vys + k + 10) * 64 + vx] - CH0[(vys + k - 1) * 64 + vx];
          a1 += CH1[(vys + k + 10) * 64 + vx] - CH1[(vys + k - 1) * 64 + vx];
        }
        #pragma unroll
        for (int h = 0; h < 2; h++) {
          int d = d0 + h;
          float cs = h ? a1 : a0;                  // raw 121-sum of lg*rg_shift
          int rvi = vx + 2 * it + h;
          float2 ms = *(const float2*)&RMS[(vys + k) * 152 + 2 * rvi];
          float rm = ms.x, rstd = ms.y;
          if (edgeL) {
            // reconstruct raw sums, subtract out-of-image border taps, redo moments
            float rs = rm * 121.f;
            float r2 = (rstd * rstd + rm * rm) * 121.f;
            int a, bI;
            if (headL) { a = max(gx - 5 + d, 0); bI = d; }
            else       { a = 24 + d; bI = min(gx + 5 + d, 479) - 455; }
            rs -= P1[(vys + k) * 25 + bI] - P1[(vys + k) * 25 + a];
            r2 -= P2[(vys + k) * 25 + bI] - P2[(vys + k) * 25 + a];
            rm = rs * (1.f / 121.f);
            rstd = sqrtf(fmaxf(r2 * (1.f / 121.f) - rm * rm, 1e-8f));
          }
          float num = __builtin_fmaf(-lmS[k], rm, cs);
          float den = __builtin_fmaf(lsS[k], rstd, 1.21e-6f);
          if (num * bden[k] > bnum[k] * den) { bnum[k] = num; bden[k] = den; bdd[k] = (float)d; }
        }
      }
    }
    __syncthreads();
  }

  if (gx < W2) {
    float* bcp = bcA + (size_t)grp * NH + (size_t)b * (H2 * W2);
    float* bdp = bdA + (size_t)grp * NH + (size_t)b * (H2 * W2);
    #pragma unroll
    for (int k = 0; k < 4; k++) {
      size_t o = (size_t)(y0 + vys + k) * W2 + gx;
      bcp[o] = bnum[k] / bden[k];
      bdp[o] = bdd[k];
    }
  }
}

// ------- sign/magnitude: merge 4 d-groups (ascending, strict >), 4 preds each -------
__global__ __launch_bounds__(256) void k_sgm(const float* __restrict__ pred,
                                             const float* __restrict__ bcA,
                                             const float* __restrict__ bdA,
                                             float* __restrict__ partialsB) {
  int tid = blockIdx.x * 256 + threadIdx.x;
  float v6 = 0.f, v7 = 0.f, v8 = 0.f;
  if (tid < NH) {
    int b = tid / (H2 * W2);
    int rem = tid % (H2 * W2);
    int y2 = rem / W2, x2 = rem % W2;
    float bcv = bcA[tid];
    float bdv = bdA[tid];
    #pragma unroll
    for (int g = 1; g < 4; g++) {
      float c = bcA[(size_t)g * NH + tid];
      if (c > bcv) { bcv = c; bdv = bdA[(size_t)g * NH + tid]; }
    }
    if (bcv > 0.3f) {
      float nd = bdv * 2.f;
      float sgn = (nd > 0.f) ? 1.f : ((nd < 0.f) ? -1.f : 0.f);
      const float* pb = pred + (size_t)b * H * W;
      #pragma unroll
      for (int dy = 0; dy < 2; dy++) {
        #pragma unroll
        for (int dx = 0; dx < 2; dx++) {
          float p = pb[(size_t)(2 * y2 + dy) * W + 2 * x2 + dx];
          v6 += fmaxf(-p * sgn, 0.f);
          v7 += bcv * fabsf(p - nd);
        }
      }
      v8 = 4.f;
    }
  }
  __shared__ float sm[4][3];
  int wave = threadIdx.x >> 6, lane = threadIdx.x & 63;
  float r;
  r = waveSum(v6); if (lane == 0) sm[wave][0] = r;
  r = waveSum(v7); if (lane == 0) sm[wave][1] = r;
  r = waveSum(v8); if (lane == 0) sm[wave][2] = r;
  __syncthreads();
  if (threadIdx.x < 3) {
    float t = sm[0][threadIdx.x] + sm[1][threadIdx.x] +
              sm[2][threadIdx.x] + sm[3][threadIdx.x];
    partialsB[(size_t)threadIdx.x * NBLK2 + blockIdx.x] = t;
  }
}

// ---------------- final reduction + scalar composition ----------------
__global__ __launch_bounds__(256) void k_final(const float* __restrict__ PA,
                                               const float* __restrict__ PB,
                                               float* __restrict__ out) {
  __shared__ float red[9][4];
  int lane = threadIdx.x & 63, wave = threadIdx.x >> 6;
  #pragma unroll
  for (int s = 0; s < 6; s++) {
    float l = 0.f;
    for (int i = threadIdx.x; i < NBLK; i += 256) l += PA[(size_t)s * NBLK + i];
    l = waveSum(l);
    if (lane == 0) red[s][wave] = l;
  }
  #pragma unroll
  for (int s = 0; s < 3; s++) {
    float l = 0.f;
    for (int i = threadIdx.x; i < NBLK2; i += 256) l += PB[(size_t)s * NBLK2 + i];
    l = waveSum(l);
    if (lane == 0) red[6 + s][wave] = l;
  }
  __syncthreads();
  if (threadIdx.x == 0) {
    float a[9];
    #pragma unroll
    for (int s = 0; s < 9; s++) a[s] = red[s][0] + red[s][1] + red[s][2] + red[s][3];
    float gtl = a[0] / fmaxf(a[1], 1.f);
    float ph  = a[2] / fmaxf(a[3], 1.f);
    float n   = fmaxf(a[8], 1.f);
    float smv = 0.3f * (a[6] / n) + 0.7f * (a[7] / n);
    float smo = a[4] * (1.f / ((float)B * H * (W - 1)))
              + a[5] * (1.f / ((float)B * (H - 1) * W));
    out[0] = gtl + ph + 0.5f * smv + 0.1f * smo;
  }
}

extern "C" void kernel_launch(void* const* d_in, const int* in_sizes, int n_in,
                              void* d_out, int out_size, void* d_ws, size_t ws_size,
                              hipStream_t stream) {
  const float* pred  = (const float*)d_in[0];
  const float* gt    = (const float*)d_in[1];
  const float* conf  = (const float*)d_in[2];
  const float* occ   = (const float*)d_in[3];
  const float* left  = (const float*)d_in[4];
  const float* right = (const float*)d_in[5];
  float* out = (float*)d_out;

  float* ws = (float*)d_ws;
  float* lg  = ws;
  float* rg  = ws + (size_t)NH;
  float* bcA = ws + 2 * (size_t)NH;                  // 4 * NH
  float* bdA = ws + 6 * (size_t)NH;                  // 4 * NH
  float* partialsA = ws + 10 * (size_t)NH;           // 6 * NBLK
  float* partialsB = partialsA + 6 * (size_t)NBLK;   // 3 * NBLK2

  k_pix<<<NBLK, 256, 0, stream>>>(pred, gt, conf, occ, left, right,
                                  lg, rg, partialsA);

  dim3 nccGrid(8, 17, 16);   // x-tiles, y-tiles, batch*4 d-groups
  k_ncc<<<nccGrid, 256, 0, stream>>>(lg, rg, bcA, bdA);

  k_sgm<<<NBLK2, 256, 0, stream>>>(pred, bcA, bdA, partialsB);

  k_final<<<1, 256, 0, stream>>>(partialsA, partialsB, out);
}

// Round 9
// 280.156 us; speedup vs baseline: 14.5734x; 1.0096x over previous
//
#include <hip/hip_runtime.h>
#include <hip/hip_bf16.h>

// Problem constants (match reference setup_inputs / hyperparams)
constexpr int B  = 4;
constexpr int H  = 544;
constexpr int W  = 960;
constexpr int H2 = 272;   // half-res
constexpr int W2 = 480;
constexpr int NH = B * H2 * W2;     // 522240
constexpr int NF = B * H * W;       // 2088960

// pixel kernel tiling: 32x8 outputs per block, halo 1 -> 34x10 staged
constexpr int TPW = 32, TPH = 8;
constexpr int SW = TPW + 2, SH = TPH + 2;      // 34 x 10
constexpr int NSTAGE = SW * SH;                // 340
constexpr int GX = W / TPW;                    // 30
constexpr int GY = H / TPH;                    // 68
constexpr int NBLK  = GX * GY * B;             // 8160 (k_pix blocks)
constexpr int NBLK2 = (NH + 255) / 256;        // 2040 (k_sgm blocks)

__device__ inline float waveSum(float v) {
  #pragma unroll
  for (int off = 32; off > 0; off >>= 1) v += __shfl_down(v, off, 64);
  return v;
}

// ------- fused pixel kernel: gt + photometric + smoothness + lg/rg downsample -------
__global__ __launch_bounds__(256) void k_pix(const float* __restrict__ pred,
                                             const float* __restrict__ gt,
                                             const float* __restrict__ conf,
                                             const float* __restrict__ occ,
                                             const float* __restrict__ left,
                                             const float* __restrict__ right,
                                             float* __restrict__ lg,
                                             float* __restrict__ rg,
                                             float* __restrict__ partialsA) {
  const int bx = blockIdx.x % GX;
  const int by = (blockIdx.x / GX) % GY;
  const int b  = blockIdx.x / (GX * GY);
  const int x0 = bx * TPW, y0 = by * TPH;
  const int tid = threadIdx.x;

  const float* dispb = pred + (size_t)b * H * W;
  const float* lb = left  + (size_t)b * 3 * H * W;
  const float* rb = right + (size_t)b * 3 * H * W;

  __shared__ float4 L4s[NSTAGE];   // (lv0, lv1, lv2, disp); zeros if OOB
  __shared__ float4 W4s[NSTAGE];   // (wv0, wv1, wv2, 0);    zeros if OOB

  for (int e = tid; e < NSTAGE; e += 256) {
    int r = e / SW, c = e % SW;
    int yy = y0 - 1 + r, xx = x0 - 1 + c;
    float4 l4 = make_float4(0.f, 0.f, 0.f, 0.f);
    float4 w4 = make_float4(0.f, 0.f, 0.f, 0.f);
    if (yy >= 0 && yy < H && xx >= 0 && xx < W) {
      float dv = dispb[yy * W + xx];
      float xsv = (float)xx - dv;
      float xc = fminf(fmaxf(xsv, 0.f), (float)(W - 1));
      float x0f = floorf(xc);
      float w = xc - x0f;
      int x0i = (int)x0f;
      int x1i = min(x0i + 1, W - 1);
      const float* l0 = lb + (size_t)yy * W;
      const float* r0 = rb + (size_t)yy * W;
      l4.x = l0[xx];
      l4.y = l0[(size_t)H * W + xx];
      l4.z = l0[2 * (size_t)H * W + xx];
      l4.w = dv;
      w4.x = r0[x0i] * (1.f - w) + r0[x1i] * w;
      w4.y = r0[(size_t)H * W + x0i] * (1.f - w) + r0[(size_t)H * W + x1i] * w;
      w4.z = r0[2 * (size_t)H * W + x0i] * (1.f - w) + r0[2 * (size_t)H * W + x1i] * w;
    }
    L4s[e] = l4; W4s[e] = w4;
  }
  __syncthreads();

  // ---- lg/rg emission (threads 0..63): 16x4 half-res pixels of this tile ----
  if (tid < 64) {
    int hx = tid & 15, hy = tid >> 4;
    int y2g = (y0 >> 1) + hy, x2g = (x0 >> 1) + hx;
    int i00 = (2 * hy + 1) * SW + (2 * hx + 1);
    float4 a00 = L4s[i00], a01 = L4s[i00 + 1], a10 = L4s[i00 + SW], a11 = L4s[i00 + SW + 1];
    float sl = 0.f;
    sl += a00.x + a01.x + a10.x + a11.x;
    sl += a00.y + a01.y + a10.y + a11.y;
    sl += a00.z + a01.z + a10.z + a11.z;
    float sr = 0.f;
    int yy2 = y0 + 2 * hy, xx2 = x0 + 2 * hx;
    #pragma unroll
    for (int c = 0; c < 3; c++) {
      const float* rp = rb + (size_t)(c * H + yy2) * W + xx2;
      sr += rp[0] + rp[1] + rp[W] + rp[W + 1];
    }
    size_t ho = (size_t)b * (H2 * W2) + (size_t)y2g * W2 + x2g;
    lg[ho] = sl * (1.f / 12.f);
    rg[ho] = sr * (1.f / 12.f);
  }

  float v[6];
  #pragma unroll
  for (int s = 0; s < 6; s++) v[s] = 0.f;

  {
    const int tx = tid & 31, ty = tid >> 5;
    const int x = x0 + tx, y = y0 + ty;
    const size_t gidx = (size_t)b * H * W + (size_t)y * W + x;
    const int ci = (ty + 1) * SW + (tx + 1);

    float sl[3] = {0,0,0}, sw[3] = {0,0,0}, sl2[3] = {0,0,0},
          sw2[3] = {0,0,0}, slw[3] = {0,0,0};
    float4 cl4, cw4, rl4, dl4;
    #pragma unroll
    for (int dy = -1; dy <= 1; dy++) {
      #pragma unroll
      for (int dx = -1; dx <= 1; dx++) {
        int ni = ci + dy * SW + dx;
        float4 a = L4s[ni];
        float4 wv = W4s[ni];
        sl[0] += a.x;  sl2[0] += a.x * a.x;  sw[0] += wv.x;  sw2[0] += wv.x * wv.x;  slw[0] += a.x * wv.x;
        sl[1] += a.y;  sl2[1] += a.y * a.y;  sw[1] += wv.y;  sw2[1] += wv.y * wv.y;  slw[1] += a.y * wv.y;
        sl[2] += a.z;  sl2[2] += a.z * a.z;  sw[2] += wv.z;  sw2[2] += wv.z * wv.z;  slw[2] += a.z * wv.z;
        if (dy == 0 && dx == 0) { cl4 = a; cw4 = wv; }
        if (dy == 0 && dx == 1) rl4 = a;
        if (dy == 1 && dx == 0) dl4 = a;
      }
    }
    float ds = cl4.w;

    // ---- gt anchor ----
    {
      float g = gt[gidx];
      float trust = (g > 2.0f) ? conf[gidx] * occ[gidx] : 0.f;
      v[0] = trust * fabsf(ds - g);
      v[1] = trust;
    }

    // ---- photometric ----
    {
      float xs = (float)x - ds;
      bool valid = (xs > 0.f) && (xs < (float)(W - 1));
      float cl[3] = {cl4.x, cl4.y, cl4.z};
      float cw[3] = {cw4.x, cw4.y, cw4.z};
      float ssm = 0.f, l1m = 0.f;
      #pragma unroll
      for (int c = 0; c < 3; c++) {
        float mx = sl[c] * (1.f / 9.f), my = sw[c] * (1.f / 9.f);
        float sx = fmaxf(sl2[c] * (1.f / 9.f) - mx * mx, 0.f);
        float sy = fmaxf(sw2[c] * (1.f / 9.f) - my * my, 0.f);
        float sxy = slw[c] * (1.f / 9.f) - mx * my;
        float n  = (2.f * mx * my + 1e-4f) * (2.f * sxy + 9e-4f);
        float dd = (mx * mx + my * my + 1e-4f) * (sx + sy + 9e-4f);
        float ss = (1.f - n / dd) * 0.5f;
        ss = fminf(fmaxf(ss, 0.f), 1.f);
        ssm += ss;
        l1m += fabsf(cl[c] - cw[c]);
      }
      ssm *= (1.f / 3.f); l1m *= (1.f / 3.f);
      float err = 0.85f * ssm + 0.15f * l1m;
      if (valid) { v[2] = err; v[3] = 1.f; }
    }

    // ---- smoothness ----
    if (x < W - 1) {
      float ddx = fabsf(rl4.w - ds);
      float idx = fabsf(rl4.x - cl4.x) + fabsf(rl4.y - cl4.y) + fabsf(rl4.z - cl4.z);
      v[4] = ddx * __expf(-idx * (1.f / 3.f));
    }
    if (y < H - 1) {
      float ddy = fabsf(dl4.w - ds);
      float idy = fabsf(dl4.x - cl4.x) + fabsf(dl4.y - cl4.y) + fabsf(dl4.z - cl4.z);
      v[5] = ddy * __expf(-idy * (1.f / 3.f));
    }
  }

  __shared__ float sm[4][6];
  int wave = threadIdx.x >> 6, lane = threadIdx.x & 63;
  #pragma unroll
  for (int s = 0; s < 6; s++) {
    float r = waveSum(v[s]);
    if (lane == 0) sm[wave][s] = r;
  }
  __syncthreads();
  if (threadIdx.x < 6) {
    float t = sm[0][threadIdx.x] + sm[1][threadIdx.x] +
              sm[2][threadIdx.x] + sm[3][threadIdx.x];
    partialsA[(size_t)threadIdx.x * NBLK + blockIdx.x] = t;
  }
}

// ---------------- fused NCC disparity search, 4 d-groups ----------------
// grp g covers 12 d's: g0 [-24..-13], g1 [-12..-1], g2 [1..12], g3 [13..24].
// LDS 8772 floats = 35088 B -> 4 blocks/CU:
//   @0:    LGs 26x74 (dead after LH) overlaid by RMS float2[16][76] (2432)
//   @2432: RGs 26x85 (2210) + 2 pad
//   @4644: POOL 3328 = interleaved float2 [26][64] (LH pair, then CH pair;
//          VR scratch between). 16B-aligned base.
//   @7972: P1 16x25 | @8372: P2
// d-loop: horizontal phase by 208 threads; vertical phase by waves 0-1 only,
// 8 rows/thread (sliding window amortization: 18 b64 reads / 8 rows / 2 d).
__global__ __launch_bounds__(256) void k_ncc(const float* __restrict__ lg,
                                             const float* __restrict__ rg,
                                             float* __restrict__ bcA,
                                             float* __restrict__ bdA) {
  const int z = blockIdx.z;
  const int b = z >> 2, grp = z & 3;
  const int dmin = (grp == 0) ? -24 : ((grp == 1) ? -12 : ((grp == 2) ? 1 : 13));
  const int x0 = blockIdx.x * 64;
  const int y0 = blockIdx.y * 16;
  const int tid = threadIdx.x;

  __shared__ __align__(16) float SM[8772];
  float* LGs = SM;             // 26 x 74
  float* RMS = SM;             // float2[16][76] row-major (overlays dead LGs)
  float* RGs = SM + 2432;      // 26 x 85
  float* POOL = SM + 4644;     // 3328 (16B aligned)
  float* P1 = SM + 7972;       // 16 x 25
  float* P2 = SM + 8372;

  const float* lgb = lg + (size_t)b * (H2 * W2);
  const float* rgb = rg + (size_t)b * (H2 * W2);

  for (int e = tid; e < 26 * 74; e += 256) {
    int r = e / 74, c = e % 74;
    int gy = y0 - 5 + r, gxx = x0 - 5 + c;
    LGs[e] = (gy >= 0 && gy < H2 && gxx >= 0 && gxx < W2) ? lgb[gy * W2 + gxx] : 0.f;
  }
  const int col0RG = x0 - 5 + dmin;
  for (int e = tid; e < 26 * 85; e += 256) {
    int r = e / 85, c = e % 85;
    int gy = y0 - 5 + r, gxx = col0RG + c;
    RGs[e] = (gy >= 0 && gy < H2 && gxx >= 0 && gxx < W2) ? rgb[gy * W2 + gxx] : 0.f;
  }
  __syncthreads();

  // ---- LH pass: horizontal 11-sums of lg, lg^2 -> interleaved float2 ----
  const int hg = tid & 7, hr = tid >> 3;
  float lgc[18];
  if (hr < 26) {
    #pragma unroll
    for (int k = 0; k < 18; k++) lgc[k] = LGs[hr * 74 + 8 * hg + k];
    float w1[8], w2[8];
    float s1 = 0.f, s2 = 0.f;
    #pragma unroll
    for (int k = 0; k < 11; k++) { s1 += lgc[k]; s2 += lgc[k] * lgc[k]; }
    w1[0] = s1; w2[0] = s2;
    #pragma unroll
    for (int j = 1; j < 8; j++) {
      s1 += lgc[j + 10] - lgc[j - 1];
      s2 += lgc[j + 10] * lgc[j + 10] - lgc[j - 1] * lgc[j - 1];
      w1[j] = s1; w2[j] = s2;
    }
    float* dst = &POOL[hr * 128 + 16 * hg];
    *(float4*)(dst)      = make_float4(w1[0], w2[0], w1[1], w2[1]);
    *(float4*)(dst + 4)  = make_float4(w1[2], w2[2], w1[3], w2[3]);
    *(float4*)(dst + 8)  = make_float4(w1[4], w2[4], w1[5], w2[5]);
    *(float4*)(dst + 12) = make_float4(w1[6], w2[6], w1[7], w2[7]);
  }
  // ---- border column sums (head: global cols 0..23; tail: 456..479) ----
  const bool headT = (grp >= 2) && (x0 == 0);
  const bool tailT = (grp < 2) && (x0 == 448);
  if (headT || tailT) {
    int gcol0 = headT ? 0 : 456;
    for (int e = tid; e < 16 * 24; e += 256) {
      int y = e / 24, i = e % 24;
      int lc = gcol0 + i - col0RG;
      float v1 = 0.f, v2 = 0.f;
      if (lc >= 0 && lc < 85) {
        #pragma unroll
        for (int dy = 0; dy < 11; dy++) {
          float v = RGs[(y + dy) * 85 + lc];
          v1 += v; v2 += v * v;
        }
      }
      P1[y * 25 + i + 1] = v1;
      P2[y * 25 + i + 1] = v2;
    }
  }
  __syncthreads();

  if ((headT || tailT) && tid < 16) {
    int y = tid;
    float s1 = 0.f, s2 = 0.f;
    P1[y * 25] = 0.f; P2[y * 25] = 0.f;
    for (int k = 0; k < 24; k++) {
      s1 += P1[y * 25 + k + 1]; P1[y * 25 + k + 1] = s1;
      s2 += P2[y * 25 + k + 1]; P2[y * 25 + k + 1] = s2;
    }
  }
  const int vx = tid & 63;
  const int w  = tid >> 6;
  const int r0 = (w & 1) * 8;          // rows for vertical work (waves 0,1)
  float lmS[8], lsS[8];                // 121-scaled left mean / std (w<2)
  if (w < 2) {
    float s1 = 0.f, s2 = 0.f;
    #pragma unroll
    for (int dy = 0; dy < 11; dy++) {
      float2 t = *(const float2*)&POOL[(r0 + dy) * 128 + 2 * vx];
      s1 += t.x; s2 += t.y;
    }
    #pragma unroll
    for (int k = 0; k < 8; k++) {
      if (k) {
        float2 tin  = *(const float2*)&POOL[(r0 + k + 10) * 128 + 2 * vx];
        float2 tout = *(const float2*)&POOL[(r0 + k - 1) * 128 + 2 * vx];
        s1 += tin.x - tout.x;
        s2 += tin.y - tout.y;
      }
      float m = s1 * (1.f / 121.f);
      float s = sqrtf(fmaxf(s2 * (1.f / 121.f) - m * m, 1e-8f));
      lmS[k] = m * 121.f;
      lsS[k] = s * 121.f;
    }
  }
  __syncthreads();

  // ---- VR pass: vertical 11-sums of rg, rg^2 (POOL scratch) ----
  float* VR1 = POOL;           // 16 x 85
  float* VR2 = POOL + 1360;
  if (tid < 170) {
    int c = tid % 85;
    int rr0 = (tid / 85) * 8;
    float s1 = 0.f, s2 = 0.f;
    #pragma unroll
    for (int dy = 0; dy < 11; dy++) {
      float v = RGs[(rr0 + dy) * 85 + c];
      s1 += v; s2 += v * v;
    }
    VR1[rr0 * 85 + c] = s1; VR2[rr0 * 85 + c] = s2;
    #pragma unroll
    for (int k = 1; k < 8; k++) {
      float vin  = RGs[(rr0 + k + 10) * 85 + c];
      float vout = RGs[(rr0 + k - 1) * 85 + c];
      s1 += vin - vout;
      s2 += vin * vin - vout * vout;
      VR1[(rr0 + k) * 85 + c] = s1; VR2[(rr0 + k) * 85 + c] = s2;
    }
  }
  __syncthreads();

  // ---- RV pass fused with moment transform -> RMS float2 (rm, rstd) ----
  {
    int r = tid >> 4, seg = tid & 15;
    int c0 = seg * 5;
    if (c0 < 75) {
      float s1 = 0.f, s2 = 0.f;
      #pragma unroll
      for (int m = 0; m < 11; m++) { s1 += VR1[r * 85 + c0 + m]; s2 += VR2[r * 85 + c0 + m]; }
      #pragma unroll
      for (int j = 0; j < 5; j++) {
        if (j) {
          s1 += VR1[r * 85 + c0 + j + 10] - VR1[r * 85 + c0 + j - 1];
          s2 += VR2[r * 85 + c0 + j + 10] - VR2[r * 85 + c0 + j - 1];
        }
        float rm = s1 * (1.f / 121.f);
        float rstd = sqrtf(fmaxf(s2 * (1.f / 121.f) - rm * rm, 1e-8f));
        *(float2*)&RMS[r * 152 + 2 * (c0 + j)] = make_float2(rm, rstd);
      }
    }
  }
  __syncthreads();

  // ---- d loop: 6 pairs (d, d+1) within this group's 12 d's ----
  const int gx = x0 + vx;
  const bool headL = (grp >= 2) && (gx < 5);
  const bool tailL = (grp < 2) && (gx > 474);
  const bool edgeL = headL || tailL;
  float bnum[8], bden[8], bdd[8];
  #pragma unroll
  for (int k = 0; k < 8; k++) { bnum[k] = -1.f; bden[k] = 1.f; bdd[k] = 0.f; }

  for (int it = 0; it < 6; ++it) {
    const int d0 = dmin + 2 * it;
    if (hr < 26) {
      const int c0 = 8 * hg + 2 * it;
      float rgv[19];
      #pragma unroll
      for (int j = 0; j < 19; j++) rgv[j] = RGs[hr * 85 + c0 + j];
      float ca[8], cb[8];
      float sa = 0.f, sb = 0.f;
      #pragma unroll
      for (int k = 0; k < 11; k++) { sa += lgc[k] * rgv[k]; sb += lgc[k] * rgv[k + 1]; }
      ca[0] = sa; cb[0] = sb;
      #pragma unroll
      for (int j = 1; j < 8; j++) {
        sa += lgc[j + 10] * rgv[j + 10] - lgc[j - 1] * rgv[j - 1];
        sb += lgc[j + 10] * rgv[j + 11] - lgc[j - 1] * rgv[j];
        ca[j] = sa; cb[j] = sb;
      }
      float* dst = &POOL[hr * 128 + 16 * hg];
      *(float4*)(dst)      = make_float4(ca[0], cb[0], ca[1], cb[1]);
      *(float4*)(dst + 4)  = make_float4(ca[2], cb[2], ca[3], cb[3]);
      *(float4*)(dst + 8)  = make_float4(ca[4], cb[4], ca[5], cb[5]);
      *(float4*)(dst + 12) = make_float4(ca[6], cb[6], ca[7], cb[7]);
    }
    __syncthreads();
    if (w < 2) {
      float sa = 0.f, sb = 0.f;
      #pragma unroll
      for (int dy = 0; dy < 11; dy++) {
        float2 t = *(const float2*)&POOL[(r0 + dy) * 128 + 2 * vx];
        sa += t.x; sb += t.y;
      }
      #pragma unroll
      for (int k = 0; k < 8; k++) {
        if (k) {
          float2 tin  = *(const float2*)&POOL[(r0 + k + 10) * 128 + 2 * vx];
          float2 tout = *(const float2*)&POOL[(r0 + k - 1) * 128 + 2 * vx];
          sa += tin.x - tout.x;
          sb += tin.y - tout.y;
        }
        #pragma unroll
        for (int h = 0; h < 2; h++) {
          int d = d0 + h;
          float cs = h ? sb : sa;            // raw 121-sum of lg*rg_shift
          int rvi = vx + 2 * it + h;
          float2 ms = *(const float2*)&RMS[(r0 + k) * 152 + 2 * rvi];
          float rm = ms.x, rstd = ms.y;
          if (edgeL) {
            float rs = rm * 121.f;
            float r2 = (rstd * rstd + rm * rm) * 121.f;
            int a, bI;
            if (headL) { a = max(gx - 5 + d, 0); bI = d; }
            else       { a = 24 + d; bI = min(gx + 5 + d, 479) - 455; }
            rs -= P1[(r0 + k) * 25 + bI] - P1[(r0 + k) * 25 + a];
            r2 -= P2[(r0 + k) * 25 + bI] - P2[(r0 + k) * 25 + a];
            rm = rs * (1.f / 121.f);
            rstd = sqrtf(fmaxf(r2 * (1.f / 121.f) - rm * rm, 1e-8f));
          }
          float num = __builtin_fmaf(-lmS[k], rm, cs);
          float den = __builtin_fmaf(lsS[k], rstd, 1.21e-6f);
          if (num * bden[k] > bnum[k] * den) { bnum[k] = num; bden[k] = den; bdd[k] = (float)d; }
        }
      }
    }
    __syncthreads();
  }

  if (w < 2 && gx < W2) {
    float* bcp = bcA + (size_t)grp * NH + (size_t)b * (H2 * W2);
    float* bdp = bdA + (size_t)grp * NH + (size_t)b * (H2 * W2);
    #pragma unroll
    for (int k = 0; k < 8; k++) {
      size_t o = (size_t)(y0 + r0 + k) * W2 + gx;
      bcp[o] = bnum[k] / bden[k];
      bdp[o] = bdd[k];
    }
  }
}

// ------- sign/magnitude: merge 4 d-groups (ascending, strict >), 4 preds each -------
__global__ __launch_bounds__(256) void k_sgm(const float* __restrict__ pred,
                                             const float* __restrict__ bcA,
                                             const float* __restrict__ bdA,
                                             float* __restrict__ partialsB) {
  int tid = blockIdx.x * 256 + threadIdx.x;
  float v6 = 0.f, v7 = 0.f, v8 = 0.f;
  if (tid < NH) {
    int b = tid / (H2 * W2);
    int rem = tid % (H2 * W2);
    int y2 = rem / W2, x2 = rem % W2;
    float bcv = bcA[tid];
    float bdv = bdA[tid];
    #pragma unroll
    for (int g = 1; g < 4; g++) {
      float c = bcA[(size_t)g * NH + tid];
      if (c > bcv) { bcv = c; bdv = bdA[(size_t)g * NH + tid]; }
    }
    if (bcv > 0.3f) {
      float nd = bdv * 2.f;
      float sgn = (nd > 0.f) ? 1.f : ((nd < 0.f) ? -1.f : 0.f);
      const float* pb = pred + (size_t)b * H * W;
      #pragma unroll
      for (int dy = 0; dy < 2; dy++) {
        #pragma unroll
        for (int dx = 0; dx < 2; dx++) {
          float p = pb[(size_t)(2 * y2 + dy) * W + 2 * x2 + dx];
          v6 += fmaxf(-p * sgn, 0.f);
          v7 += bcv * fabsf(p - nd);
        }
      }
      v8 = 4.f;
    }
  }
  __shared__ float sm[4][3];
  int wave = threadIdx.x >> 6, lane = threadIdx.x & 63;
  float r;
  r = waveSum(v6); if (lane == 0) sm[wave][0] = r;
  r = waveSum(v7); if (lane == 0) sm[wave][1] = r;
  r = waveSum(v8); if (lane == 0) sm[wave][2] = r;
  __syncthreads();
  if (threadIdx.x < 3) {
    float t = sm[0][threadIdx.x] + sm[1][threadIdx.x] +
              sm[2][threadIdx.x] + sm[3][threadIdx.x];
    partialsB[(size_t)threadIdx.x * NBLK2 + blockIdx.x] = t;
  }
}

// ---------------- final reduction + scalar composition (1024 threads) ----------------
__global__ __launch_bounds__(1024) void k_final(const float* __restrict__ PA,
                                                const float* __restrict__ PB,
                                                float* __restrict__ out) {
  __shared__ float red[9][16];
  int lane = threadIdx.x & 63, wave = threadIdx.x >> 6;
  #pragma unroll
  for (int s = 0; s < 6; s++) {
    float l = 0.f;
    for (int i = threadIdx.x; i < NBLK; i += 1024) l += PA[(size_t)s * NBLK + i];
    l = waveSum(l);
    if (lane == 0) red[s][wave] = l;
  }
  #pragma unroll
  for (int s = 0; s < 3; s++) {
    float l = 0.f;
    for (int i = threadIdx.x; i < NBLK2; i += 1024) l += PB[(size_t)s * NBLK2 + i];
    l = waveSum(l);
    if (lane == 0) red[6 + s][wave] = l;
  }
  __syncthreads();
  if (threadIdx.x == 0) {
    float a[9];
    #pragma unroll
    for (int s = 0; s < 9; s++) {
      float t = 0.f;
      #pragma unroll
      for (int q = 0; q < 16; q++) t += red[s][q];
      a[s] = t;
    }
    float gtl = a[0] / fmaxf(a[1], 1.f);
    float ph  = a[2] / fmaxf(a[3], 1.f);
    float n   = fmaxf(a[8], 1.f);
    float smv = 0.3f * (a[6] / n) + 0.7f * (a[7] / n);
    float smo = a[4] * (1.f / ((float)B * H * (W - 1)))
              + a[5] * (1.f / ((float)B * (H - 1) * W));
    out[0] = gtl + ph + 0.5f * smv + 0.1f * smo;
  }
}

extern "C" void kernel_launch(void* const* d_in, const int* in_sizes, int n_in,
                              void* d_out, int out_size, void* d_ws, size_t ws_size,
                              hipStream_t stream) {
  const float* pred  = (const float*)d_in[0];
  const float* gt    = (const float*)d_in[1];
  const float* conf  = (const float*)d_in[2];
  const float* occ   = (const float*)d_in[3];
  const float* left  = (const float*)d_in[4];
  const float* right = (const float*)d_in[5];
  float* out = (float*)d_out;

  float* ws = (float*)d_ws;
  float* lg  = ws;
  float* rg  = ws + (size_t)NH;
  float* bcA = ws + 2 * (size_t)NH;                  // 4 * NH
  float* bdA = ws + 6 * (size_t)NH;                  // 4 * NH
  float* partialsA = ws + 10 * (size_t)NH;           // 6 * NBLK
  float* partialsB = partialsA + 6 * (size_t)NBLK;   // 3 * NBLK2

  k_pix<<<NBLK, 256, 0, stream>>>(pred, gt, conf, occ, left, right,
                                  lg, rg, partialsA);

  dim3 nccGrid(8, 17, 16);   // x-tiles, y-tiles, batch*4 d-groups
  k_ncc<<<nccGrid, 256, 0, stream>>>(lg, rg, bcA, bdA);

  k_sgm<<<NBLK2, 256, 0, stream>>>(pred, bcA, bdA, partialsB);

  k_final<<<1, 1024, 0, stream>>>(partialsA, partialsB, out);
}

// Round 10
// 242.851 us; speedup vs baseline: 16.8121x; 1.1536x over previous
//
#include <hip/hip_runtime.h>
#include <hip/hip_bf16.h>

// Problem constants (match reference setup_inputs / hyperparams)
constexpr int B  = 4;
constexpr int H  = 544;
constexpr int W  = 960;
constexpr int H2 = 272;   // half-res
constexpr int W2 = 480;
constexpr int NH = B * H2 * W2;     // 522240
constexpr int NF = B * H * W;       // 2088960

// pixel kernel tiling: 32x8 outputs per block, halo 1 -> 34x10 staged
constexpr int TPW = 32, TPH = 8;
constexpr int SW = TPW + 2, SH = TPH + 2;      // 34 x 10
constexpr int NSTAGE = SW * SH;                // 340
constexpr int GX = W / TPW;                    // 30
constexpr int GY = H / TPH;                    // 68
constexpr int NBLK  = GX * GY * B;             // 8160 (k_pix blocks)
constexpr int NBLK2 = (NH + 255) / 256;        // 2040 (k_sgm blocks)

__device__ inline float waveSum(float v) {
  #pragma unroll
  for (int off = 32; off > 0; off >>= 1) v += __shfl_down(v, off, 64);
  return v;
}

// ------- fused pixel kernel: gt + photometric + smoothness + lg/rg downsample -------
__global__ __launch_bounds__(256) void k_pix(const float* __restrict__ pred,
                                             const float* __restrict__ gt,
                                             const float* __restrict__ conf,
                                             const float* __restrict__ occ,
                                             const float* __restrict__ left,
                                             const float* __restrict__ right,
                                             float* __restrict__ lg,
                                             float* __restrict__ rg,
                                             float* __restrict__ partialsA) {
  const int bx = blockIdx.x % GX;
  const int by = (blockIdx.x / GX) % GY;
  const int b  = blockIdx.x / (GX * GY);
  const int x0 = bx * TPW, y0 = by * TPH;
  const int tid = threadIdx.x;

  const float* dispb = pred + (size_t)b * H * W;
  const float* lb = left  + (size_t)b * 3 * H * W;
  const float* rb = right + (size_t)b * 3 * H * W;

  __shared__ float4 L4s[NSTAGE];   // (lv0, lv1, lv2, disp); zeros if OOB
  __shared__ float4 W4s[NSTAGE];   // (wv0, wv1, wv2, 0);    zeros if OOB

  for (int e = tid; e < NSTAGE; e += 256) {
    int r = e / SW, c = e % SW;
    int yy = y0 - 1 + r, xx = x0 - 1 + c;
    float4 l4 = make_float4(0.f, 0.f, 0.f, 0.f);
    float4 w4 = make_float4(0.f, 0.f, 0.f, 0.f);
    if (yy >= 0 && yy < H && xx >= 0 && xx < W) {
      float dv = dispb[yy * W + xx];
      float xsv = (float)xx - dv;
      float xc = fminf(fmaxf(xsv, 0.f), (float)(W - 1));
      float x0f = floorf(xc);
      float w = xc - x0f;
      int x0i = (int)x0f;
      int x1i = min(x0i + 1, W - 1);
      const float* l0 = lb + (size_t)yy * W;
      const float* r0 = rb + (size_t)yy * W;
      l4.x = l0[xx];
      l4.y = l0[(size_t)H * W + xx];
      l4.z = l0[2 * (size_t)H * W + xx];
      l4.w = dv;
      w4.x = r0[x0i] * (1.f - w) + r0[x1i] * w;
      w4.y = r0[(size_t)H * W + x0i] * (1.f - w) + r0[(size_t)H * W + x1i] * w;
      w4.z = r0[2 * (size_t)H * W + x0i] * (1.f - w) + r0[2 * (size_t)H * W + x1i] * w;
    }
    L4s[e] = l4; W4s[e] = w4;
  }
  __syncthreads();

  // ---- lg/rg emission (threads 0..63): 16x4 half-res pixels of this tile ----
  if (tid < 64) {
    int hx = tid & 15, hy = tid >> 4;
    int y2g = (y0 >> 1) + hy, x2g = (x0 >> 1) + hx;
    int i00 = (2 * hy + 1) * SW + (2 * hx + 1);
    float4 a00 = L4s[i00], a01 = L4s[i00 + 1], a10 = L4s[i00 + SW], a11 = L4s[i00 + SW + 1];
    float sl = 0.f;
    sl += a00.x + a01.x + a10.x + a11.x;
    sl += a00.y + a01.y + a10.y + a11.y;
    sl += a00.z + a01.z + a10.z + a11.z;
    float sr = 0.f;
    int yy2 = y0 + 2 * hy, xx2 = x0 + 2 * hx;
    #pragma unroll
    for (int c = 0; c < 3; c++) {
      const float* rp = rb + (size_t)(c * H + yy2) * W + xx2;
      sr += rp[0] + rp[1] + rp[W] + rp[W + 1];
    }
    size_t ho = (size_t)b * (H2 * W2) + (size_t)y2g * W2 + x2g;
    lg[ho] = sl * (1.f / 12.f);
    rg[ho] = sr * (1.f / 12.f);
  }

  float v[6];
  #pragma unroll
  for (int s = 0; s < 6; s++) v[s] = 0.f;

  {
    const int tx = tid & 31, ty = tid >> 5;
    const int x = x0 + tx, y = y0 + ty;
    const size_t gidx = (size_t)b * H * W + (size_t)y * W + x;
    const int ci = (ty + 1) * SW + (tx + 1);

    float sl[3] = {0,0,0}, sw[3] = {0,0,0}, sl2[3] = {0,0,0},
          sw2[3] = {0,0,0}, slw[3] = {0,0,0};
    float4 cl4, cw4, rl4, dl4;
    #pragma unroll
    for (int dy = -1; dy <= 1; dy++) {
      #pragma unroll
      for (int dx = -1; dx <= 1; dx++) {
        int ni = ci + dy * SW + dx;
        float4 a = L4s[ni];
        float4 wv = W4s[ni];
        sl[0] += a.x;  sl2[0] += a.x * a.x;  sw[0] += wv.x;  sw2[0] += wv.x * wv.x;  slw[0] += a.x * wv.x;
        sl[1] += a.y;  sl2[1] += a.y * a.y;  sw[1] += wv.y;  sw2[1] += wv.y * wv.y;  slw[1] += a.y * wv.y;
        sl[2] += a.z;  sl2[2] += a.z * a.z;  sw[2] += wv.z;  sw2[2] += wv.z * wv.z;  slw[2] += a.z * wv.z;
        if (dy == 0 && dx == 0) { cl4 = a; cw4 = wv; }
        if (dy == 0 && dx == 1) rl4 = a;
        if (dy == 1 && dx == 0) dl4 = a;
      }
    }
    float ds = cl4.w;

    // ---- gt anchor ----
    {
      float g = gt[gidx];
      float trust = (g > 2.0f) ? conf[gidx] * occ[gidx] : 0.f;
      v[0] = trust * fabsf(ds - g);
      v[1] = trust;
    }

    // ---- photometric ----
    {
      float xs = (float)x - ds;
      bool valid = (xs > 0.f) && (xs < (float)(W - 1));
      float cl[3] = {cl4.x, cl4.y, cl4.z};
      float cw[3] = {cw4.x, cw4.y, cw4.z};
      float ssm = 0.f, l1m = 0.f;
      #pragma unroll
      for (int c = 0; c < 3; c++) {
        float mx = sl[c] * (1.f / 9.f), my = sw[c] * (1.f / 9.f);
        float sx = fmaxf(sl2[c] * (1.f / 9.f) - mx * mx, 0.f);
        float sy = fmaxf(sw2[c] * (1.f / 9.f) - my * my, 0.f);
        float sxy = slw[c] * (1.f / 9.f) - mx * my;
        float n  = (2.f * mx * my + 1e-4f) * (2.f * sxy + 9e-4f);
        float dd = (mx * mx + my * my + 1e-4f) * (sx + sy + 9e-4f);
        float ss = (1.f - n / dd) * 0.5f;
        ss = fminf(fmaxf(ss, 0.f), 1.f);
        ssm += ss;
        l1m += fabsf(cl[c] - cw[c]);
      }
      ssm *= (1.f / 3.f); l1m *= (1.f / 3.f);
      float err = 0.85f * ssm + 0.15f * l1m;
      if (valid) { v[2] = err; v[3] = 1.f; }
    }

    // ---- smoothness ----
    if (x < W - 1) {
      float ddx = fabsf(rl4.w - ds);
      float idx = fabsf(rl4.x - cl4.x) + fabsf(rl4.y - cl4.y) + fabsf(rl4.z - cl4.z);
      v[4] = ddx * __expf(-idx * (1.f / 3.f));
    }
    if (y < H - 1) {
      float ddy = fabsf(dl4.w - ds);
      float idy = fabsf(dl4.x - cl4.x) + fabsf(dl4.y - cl4.y) + fabsf(dl4.z - cl4.z);
      v[5] = ddy * __expf(-idy * (1.f / 3.f));
    }
  }

  __shared__ float sm[4][6];
  int wave = threadIdx.x >> 6, lane = threadIdx.x & 63;
  #pragma unroll
  for (int s = 0; s < 6; s++) {
    float r = waveSum(v[s]);
    if (lane == 0) sm[wave][s] = r;
  }
  __syncthreads();
  if (threadIdx.x < 6) {
    float t = sm[0][threadIdx.x] + sm[1][threadIdx.x] +
              sm[2][threadIdx.x] + sm[3][threadIdx.x];
    partialsA[(size_t)threadIdx.x * NBLK + blockIdx.x] = t;
  }
}

// ---------------- fused NCC disparity search, 4 d-groups (R7 version) ----------------
// grp g covers 12 d's: g0 [-24..-13], g1 [-12..-1], g2 [1..12], g3 [13..24].
// LDS 8770 floats = 35080 B -> 4 blocks/CU:
//   @0:    LGs 26x74 (dead after LH) overlaid by RMS float2[16][76] (2432)
//   @2432: RGs 26x85 | @4642: POOL 3328 (LH pair / VR pair / CH pair, stride 64)
//   @7970: P1 16x25 | @8370: P2
// NOTE (R9 lesson): keep CH/LH as two separate stride-64 arrays and the
// vertical phase at 4 rows/thread across ALL 4 waves. The interleaved-float2
// + 8-row variant raised VGPR 60->96 and real bank conflicts 2.1M->7.7M,
// regressing 79->115 us.
__global__ __launch_bounds__(256) void k_ncc(const float* __restrict__ lg,
                                             const float* __restrict__ rg,
                                             float* __restrict__ bcA,
                                             float* __restrict__ bdA) {
  const int z = blockIdx.z;
  const int b = z >> 2, grp = z & 3;
  const int dmin = (grp == 0) ? -24 : ((grp == 1) ? -12 : ((grp == 2) ? 1 : 13));
  const int x0 = blockIdx.x * 64;
  const int y0 = blockIdx.y * 16;
  const int tid = threadIdx.x;

  __shared__ __align__(16) float SM[8770];
  float* LGs = SM;             // 26 x 74
  float* RMS = SM;             // float2[16][76] row-major (overlays dead LGs)
  float* RGs = SM + 2432;      // 26 x 85
  float* POOL = SM + 4642;     // 3328
  float* P1 = SM + 7970;       // 16 x 25
  float* P2 = SM + 8370;

  const float* lgb = lg + (size_t)b * (H2 * W2);
  const float* rgb = rg + (size_t)b * (H2 * W2);

  for (int e = tid; e < 26 * 74; e += 256) {
    int r = e / 74, c = e % 74;
    int gy = y0 - 5 + r, gxx = x0 - 5 + c;
    LGs[e] = (gy >= 0 && gy < H2 && gxx >= 0 && gxx < W2) ? lgb[gy * W2 + gxx] : 0.f;
  }
  const int col0RG = x0 - 5 + dmin;
  for (int e = tid; e < 26 * 85; e += 256) {
    int r = e / 85, c = e % 85;
    int gy = y0 - 5 + r, gxx = col0RG + c;
    RGs[e] = (gy >= 0 && gy < H2 && gxx >= 0 && gxx < W2) ? rgb[gy * W2 + gxx] : 0.f;
  }
  __syncthreads();

  // ---- LH pass (horizontal 11-sums of lg, lg^2) + lgc register cache ----
  const int hg = tid & 7, hr = tid >> 3;
  float lgc[18];
  float* LH1 = POOL;           // 26 x 64
  float* LH2 = POOL + 1664;
  if (hr < 26) {
    #pragma unroll
    for (int k = 0; k < 18; k++) lgc[k] = LGs[hr * 74 + 8 * hg + k];
    float w1[8], w2[8];
    float s1 = 0.f, s2 = 0.f;
    #pragma unroll
    for (int k = 0; k < 11; k++) { s1 += lgc[k]; s2 += lgc[k] * lgc[k]; }
    w1[0] = s1; w2[0] = s2;
    #pragma unroll
    for (int j = 1; j < 8; j++) {
      s1 += lgc[j + 10] - lgc[j - 1];
      s2 += lgc[j + 10] * lgc[j + 10] - lgc[j - 1] * lgc[j - 1];
      w1[j] = s1; w2[j] = s2;
    }
    *(float4*)&LH1[hr * 64 + 8 * hg]     = make_float4(w1[0], w1[1], w1[2], w1[3]);
    *(float4*)&LH1[hr * 64 + 8 * hg + 4] = make_float4(w1[4], w1[5], w1[6], w1[7]);
    *(float4*)&LH2[hr * 64 + 8 * hg]     = make_float4(w2[0], w2[1], w2[2], w2[3]);
    *(float4*)&LH2[hr * 64 + 8 * hg + 4] = make_float4(w2[4], w2[5], w2[6], w2[7]);
  }
  // ---- border column sums (head: global cols 0..23; tail: 456..479) ----
  const bool headT = (grp >= 2) && (x0 == 0);
  const bool tailT = (grp < 2) && (x0 == 448);
  if (headT || tailT) {
    int gcol0 = headT ? 0 : 456;
    for (int e = tid; e < 16 * 24; e += 256) {
      int y = e / 24, i = e % 24;
      int lc = gcol0 + i - col0RG;
      float v1 = 0.f, v2 = 0.f;
      if (lc >= 0 && lc < 85) {
        #pragma unroll
        for (int dy = 0; dy < 11; dy++) {
          float v = RGs[(y + dy) * 85 + lc];
          v1 += v; v2 += v * v;
        }
      }
      P1[y * 25 + i + 1] = v1;
      P2[y * 25 + i + 1] = v2;
    }
  }
  __syncthreads();

  if ((headT || tailT) && tid < 16) {
    int y = tid;
    float s1 = 0.f, s2 = 0.f;
    P1[y * 25] = 0.f; P2[y * 25] = 0.f;
    for (int k = 0; k < 24; k++) {
      s1 += P1[y * 25 + k + 1]; P1[y * 25 + k + 1] = s1;
      s2 += P2[y * 25 + k + 1]; P2[y * 25 + k + 1] = s2;
    }
  }
  const int vx = tid & 63;
  const int vys = (tid >> 6) * 4;
  float lmS[4], lsS[4];   // 121-scaled left mean / std
  {
    float s1 = 0.f, s2 = 0.f;
    #pragma unroll
    for (int dy = 0; dy < 11; dy++) { s1 += LH1[(vys + dy) * 64 + vx]; s2 += LH2[(vys + dy) * 64 + vx]; }
    #pragma unroll
    for (int k = 0; k < 4; k++) {
      if (k) {
        s1 += LH1[(vys + k + 10) * 64 + vx] - LH1[(vys + k - 1) * 64 + vx];
        s2 += LH2[(vys + k + 10) * 64 + vx] - LH2[(vys + k - 1) * 64 + vx];
      }
      float m = s1 * (1.f / 121.f);
      float s = sqrtf(fmaxf(s2 * (1.f / 121.f) - m * m, 1e-8f));
      lmS[k] = m * 121.f;
      lsS[k] = s * 121.f;
    }
  }
  __syncthreads();

  // ---- VR pass: vertical 11-sums of rg, rg^2 (POOL, overwrites LH) ----
  float* VR1 = POOL;           // 16 x 85
  float* VR2 = POOL + 1360;
  if (tid < 170) {
    int c = tid % 85;
    int rr0 = (tid / 85) * 8;
    float s1 = 0.f, s2 = 0.f;
    #pragma unroll
    for (int dy = 0; dy < 11; dy++) {
      float v = RGs[(rr0 + dy) * 85 + c];
      s1 += v; s2 += v * v;
    }
    VR1[rr0 * 85 + c] = s1; VR2[rr0 * 85 + c] = s2;
    #pragma unroll
    for (int k = 1; k < 8; k++) {
      float vin  = RGs[(rr0 + k + 10) * 85 + c];
      float vout = RGs[(rr0 + k - 1) * 85 + c];
      s1 += vin - vout;
      s2 += vin * vin - vout * vout;
      VR1[(rr0 + k) * 85 + c] = s1; VR2[(rr0 + k) * 85 + c] = s2;
    }
  }
  __syncthreads();

  // ---- RV pass fused with moment transform -> RMS float2 (rm, rstd) ----
  {
    int r = tid >> 4, seg = tid & 15;
    int c0 = seg * 5;
    if (c0 < 75) {
      float s1 = 0.f, s2 = 0.f;
      #pragma unroll
      for (int m = 0; m < 11; m++) { s1 += VR1[r * 85 + c0 + m]; s2 += VR2[r * 85 + c0 + m]; }
      #pragma unroll
      for (int j = 0; j < 5; j++) {
        if (j) {
          s1 += VR1[r * 85 + c0 + j + 10] - VR1[r * 85 + c0 + j - 1];
          s2 += VR2[r * 85 + c0 + j + 10] - VR2[r * 85 + c0 + j - 1];
        }
        float rm = s1 * (1.f / 121.f);
        float rstd = sqrtf(fmaxf(s2 * (1.f / 121.f) - rm * rm, 1e-8f));
        *(float2*)&RMS[r * 152 + 2 * (c0 + j)] = make_float2(rm, rstd);
      }
    }
  }
  __syncthreads();

  // ---- d loop: 6 pairs (d, d+1) within this group's 12 d's ----
  float* CH0 = POOL;           // 26 x 64
  float* CH1 = POOL + 1664;
  const int gx = x0 + vx;
  const bool headL = (grp >= 2) && (gx < 5);
  const bool tailL = (grp < 2) && (gx > 474);
  const bool edgeL = headL || tailL;
  float bnum[4], bden[4], bdd[4];
  #pragma unroll
  for (int k = 0; k < 4; k++) { bnum[k] = -1.f; bden[k] = 1.f; bdd[k] = 0.f; }

  for (int it = 0; it < 6; ++it) {
    const int d0 = dmin + 2 * it;
    if (hr < 26) {
      const int c0 = 8 * hg + 2 * it;
      float rgv[19];
      #pragma unroll
      for (int j = 0; j < 19; j++) rgv[j] = RGs[hr * 85 + c0 + j];
      float ca[8], cb[8];
      float sa = 0.f, sb = 0.f;
      #pragma unroll
      for (int k = 0; k < 11; k++) { sa += lgc[k] * rgv[k]; sb += lgc[k] * rgv[k + 1]; }
      ca[0] = sa; cb[0] = sb;
      #pragma unroll
      for (int j = 1; j < 8; j++) {
        sa += lgc[j + 10] * rgv[j + 10] - lgc[j - 1] * rgv[j - 1];
        sb += lgc[j + 10] * rgv[j + 11] - lgc[j - 1] * rgv[j];
        ca[j] = sa; cb[j] = sb;
      }
      *(float4*)&CH0[hr * 64 + 8 * hg]     = make_float4(ca[0], ca[1], ca[2], ca[3]);
      *(float4*)&CH0[hr * 64 + 8 * hg + 4] = make_float4(ca[4], ca[5], ca[6], ca[7]);
      *(float4*)&CH1[hr * 64 + 8 * hg]     = make_float4(cb[0], cb[1], cb[2], cb[3]);
      *(float4*)&CH1[hr * 64 + 8 * hg + 4] = make_float4(cb[4], cb[5], cb[6], cb[7]);
    }
    __syncthreads();
    {
      float a0 = 0.f, a1 = 0.f;
      #pragma unroll
      for (int dy = 0; dy < 11; dy++) { a0 += CH0[(vys + dy) * 64 + vx]; a1 += CH1[(vys + dy) * 64 + vx]; }
      #pragma unroll
      for (int k = 0; k < 4; k++) {
        if (k) {
          a0 += CH0[(vys + k + 10) * 64 + vx] - CH0[(vys + k - 1) * 64 + vx];
          a1 += CH1[(vys + k + 10) * 64 + vx] - CH1[(vys + k - 1) * 64 + vx];
        }
        #pragma unroll
        for (int h = 0; h < 2; h++) {
          int d = d0 + h;
          float cs = h ? a1 : a0;            // raw 121-sum of lg*rg_shift
          int rvi = vx + 2 * it + h;
          float2 ms = *(const float2*)&RMS[(vys + k) * 152 + 2 * rvi];
          float rm = ms.x, rstd = ms.y;
          if (edgeL) {
            float rs = rm * 121.f;
            float r2 = (rstd * rstd + rm * rm) * 121.f;
            int a, bI;
            if (headL) { a = max(gx - 5 + d, 0); bI = d; }
            else       { a = 24 + d; bI = min(gx + 5 + d, 479) - 455; }
            rs -= P1[(vys + k) * 25 + bI] - P1[(vys + k) * 25 + a];
            r2 -= P2[(vys + k) * 25 + bI] - P2[(vys + k) * 25 + a];
            rm = rs * (1.f / 121.f);
            rstd = sqrtf(fmaxf(r2 * (1.f / 121.f) - rm * rm, 1e-8f));
          }
          float num = __builtin_fmaf(-lmS[k], rm, cs);
          float den = __builtin_fmaf(lsS[k], rstd, 1.21e-6f);
          if (num * bden[k] > bnum[k] * den) { bnum[k] = num; bden[k] = den; bdd[k] = (float)d; }
        }
      }
    }
    __syncthreads();
  }

  if (gx < W2) {
    float* bcp = bcA + (size_t)grp * NH + (size_t)b * (H2 * W2);
    float* bdp = bdA + (size_t)grp * NH + (size_t)b * (H2 * W2);
    #pragma unroll
    for (int k = 0; k < 4; k++) {
      size_t o = (size_t)(y0 + vys + k) * W2 + gx;
      bcp[o] = bnum[k] / bden[k];
      bdp[o] = bdd[k];
    }
  }
}

// ------- sign/magnitude: merge 4 d-groups (ascending, strict >), 4 preds each -------
__global__ __launch_bounds__(256) void k_sgm(const float* __restrict__ pred,
                                             const float* __restrict__ bcA,
                                             const float* __restrict__ bdA,
                                             float* __restrict__ partialsB) {
  int tid = blockIdx.x * 256 + threadIdx.x;
  float v6 = 0.f, v7 = 0.f, v8 = 0.f;
  if (tid < NH) {
    int b = tid / (H2 * W2);
    int rem = tid % (H2 * W2);
    int y2 = rem / W2, x2 = rem % W2;
    float bcv = bcA[tid];
    float bdv = bdA[tid];
    #pragma unroll
    for (int g = 1; g < 4; g++) {
      float c = bcA[(size_t)g * NH + tid];
      if (c > bcv) { bcv = c; bdv = bdA[(size_t)g * NH + tid]; }
    }
    if (bcv > 0.3f) {
      float nd = bdv * 2.f;
      float sgn = (nd > 0.f) ? 1.f : ((nd < 0.f) ? -1.f : 0.f);
      const float* pb = pred + (size_t)b * H * W;
      #pragma unroll
      for (int dy = 0; dy < 2; dy++) {
        #pragma unroll
        for (int dx = 0; dx < 2; dx++) {
          float p = pb[(size_t)(2 * y2 + dy) * W + 2 * x2 + dx];
          v6 += fmaxf(-p * sgn, 0.f);
          v7 += bcv * fabsf(p - nd);
        }
      }
      v8 = 4.f;
    }
  }
  __shared__ float sm[4][3];
  int wave = threadIdx.x >> 6, lane = threadIdx.x & 63;
  float r;
  r = waveSum(v6); if (lane == 0) sm[wave][0] = r;
  r = waveSum(v7); if (lane == 0) sm[wave][1] = r;
  r = waveSum(v8); if (lane == 0) sm[wave][2] = r;
  __syncthreads();
  if (threadIdx.x < 3) {
    float t = sm[0][threadIdx.x] + sm[1][threadIdx.x] +
              sm[2][threadIdx.x] + sm[3][threadIdx.x];
    partialsB[(size_t)threadIdx.x * NBLK2 + blockIdx.x] = t;
  }
}

// ---------------- final reduction + scalar composition (1024 threads) ----------------
__global__ __launch_bounds__(1024) void k_final(const float* __restrict__ PA,
                                                const float* __restrict__ PB,
                                                float* __restrict__ out) {
  __shared__ float red[9][16];
  int lane = threadIdx.x & 63, wave = threadIdx.x >> 6;
  #pragma unroll
  for (int s = 0; s < 6; s++) {
    float l = 0.f;
    for (int i = threadIdx.x; i < NBLK; i += 1024) l += PA[(size_t)s * NBLK + i];
    l = waveSum(l);
    if (lane == 0) red[s][wave] = l;
  }
  #pragma unroll
  for (int s = 0; s < 3; s++) {
    float l = 0.f;
    for (int i = threadIdx.x; i < NBLK2; i += 1024) l += PB[(size_t)s * NBLK2 + i];
    l = waveSum(l);
    if (lane == 0) red[6 + s][wave] = l;
  }
  __syncthreads();
  if (threadIdx.x == 0) {
    float a[9];
    #pragma unroll
    for (int s = 0; s < 9; s++) {
      float t = 0.f;
      #pragma unroll
      for (int q = 0; q < 16; q++) t += red[s][q];
      a[s] = t;
    }
    float gtl = a[0] / fmaxf(a[1], 1.f);
    float ph  = a[2] / fmaxf(a[3], 1.f);
    float n   = fmaxf(a[8], 1.f);
    float smv = 0.3f * (a[6] / n) + 0.7f * (a[7] / n);
    float smo = a[4] * (1.f / ((float)B * H * (W - 1)))
              + a[5] * (1.f / ((float)B * (H - 1) * W));
    out[0] = gtl + ph + 0.5f * smv + 0.1f * smo;
  }
}

extern "C" void kernel_launch(void* const* d_in, const int* in_sizes, int n_in,
                              void* d_out, int out_size, void* d_ws, size_t ws_size,
                              hipStream_t stream) {
  const float* pred  = (const float*)d_in[0];
  const float* gt    = (const float*)d_in[1];
  const float* conf  = (const float*)d_in[2];
  const float* occ   = (const float*)d_in[3];
  const float* left  = (const float*)d_in[4];
  const float* right = (const float*)d_in[5];
  float* out = (float*)d_out;

  float* ws = (float*)d_ws;
  float* lg  = ws;
  float* rg  = ws + (size_t)NH;
  float* bcA = ws + 2 * (size_t)NH;                  // 4 * NH
  float* bdA = ws + 6 * (size_t)NH;                  // 4 * NH
  float* partialsA = ws + 10 * (size_t)NH;           // 6 * NBLK
  float* partialsB = partialsA + 6 * (size_t)NBLK;   // 3 * NBLK2

  k_pix<<<NBLK, 256, 0, stream>>>(pred, gt, conf, occ, left, right,
                                  lg, rg, partialsA);

  dim3 nccGrid(8, 17, 16);   // x-tiles, y-tiles, batch*4 d-groups
  k_ncc<<<nccGrid, 256, 0, stream>>>(lg, rg, bcA, bdA);

  k_sgm<<<NBLK2, 256, 0, stream>>>(pred, bcA, bdA, partialsB);

  k_final<<<1, 1024, 0, stream>>>(partialsA, partialsB, out);
}